// Round 10
// baseline (769.705 us; speedup 1.0000x reference)
//
#include <hip/hip_runtime.h>
#include <hip/hip_bf16.h>

typedef __hip_bfloat16 bf16;
typedef unsigned int uint32;
typedef __attribute__((ext_vector_type(8))) short short8;   // 8 bf16 (4 VGPRs)
typedef __attribute__((ext_vector_type(4))) float f32x4;
typedef __attribute__((ext_vector_type(2))) float f32x2;
typedef __attribute__((ext_vector_type(4))) uint32 u32x4;   // clang vector: ok for nontemporal

#define N_ITEMS_C 50000
#define N_USERS_C 20000
#define N_NODES_C 70000
#define NNZ_C 800000
#define NSESS 1024
#define LP 49
#define NTOK (NSESS * LP)   // 50176
#define NBK 137             // coarse buckets: row >> 9

__device__ __forceinline__ float bflo(uint32 u) { return __uint_as_float(u << 16); }
__device__ __forceinline__ float bfhi(uint32 u) { return __uint_as_float(u & 0xffff0000u); }
// hi bf16 with low-16 garbage bits: relative error <= 2^-17, far below bf16 rounding.
__device__ __forceinline__ float bfhi_fast(uint32 u) { return __uint_as_float(u); }
__device__ __forceinline__ uint32 packbf(float a, float b) {
    return (uint32)__bfloat16_as_ushort(__float2bfloat16(a)) |
           ((uint32)__bfloat16_as_ushort(__float2bfloat16(b)) << 16);
}

// ---------------- init: hab = bf16(concat(id_emb, user_emb)), 16B/lane ----------------
__global__ void init_hab_kernel(const float4* __restrict__ idp, const float4* __restrict__ usp,
                                uint32* __restrict__ hab) {
    int i = blockIdx.x * 256 + threadIdx.x;           // quad index, 2,240,000 total
    float4 w = (i < 1600000) ? idp[i] : usp[i - 1600000];
    uint2 o = make_uint2(packbf(w.x, w.y), packbf(w.z, w.w));
    *(uint2*)&hab[(size_t)i * 2] = o;
}

// ================= CSR build: coarse-bucket sort with coalesced writes =================
// A1: per-block LDS hist over 137 buckets -> global bhist
__global__ __launch_bounds__(256) void bucket_hist_kernel(
    const int* __restrict__ rel_rows, int* __restrict__ bhist)
{
    __shared__ int hist[NBK];
    const int r = blockIdx.y, tid = threadIdx.x;
    if (tid < NBK) hist[tid] = 0;
    __syncthreads();
    const int* rr = rel_rows + (size_t)r * NNZ_C;
#pragma unroll
    for (int i = 0; i < 16; ++i) {
        int e = blockIdx.x * 4096 + i * 256 + tid;
        if (e < NNZ_C) atomicAdd(&hist[rr[e] >> 9], 1);
    }
    __syncthreads();
    if (tid < NBK && hist[tid]) atomicAdd(&bhist[r * NBK + tid], hist[tid]);
}

// A2: scan bucket totals -> bbase[r][0..NBK]
__global__ __launch_bounds__(256) void bucket_scan_kernel(
    const int* __restrict__ bhist, int* __restrict__ bbase)
{
    __shared__ int s[256];
    const int tid = threadIdx.x;
    for (int r = 0; r < 3; ++r) {
        s[tid] = (tid < NBK) ? bhist[r * NBK + tid] : 0;
        __syncthreads();
        for (int d = 1; d < 256; d <<= 1) {
            int t = (tid >= d) ? s[tid - d] : 0;
            __syncthreads();
            s[tid] += t;
            __syncthreads();
        }
        if (tid < NBK) bbase[r * (NBK + 1) + tid + 1] = s[tid];
        if (tid == 0) bbase[r * (NBK + 1)] = 0;
        __syncthreads();
    }
}

// A3: scatter edges into bucket-contiguous tmp (int2: packed(col|v15), row)
// rows cached in registers across the two passes (no rel_rows re-read).
__global__ __launch_bounds__(256) void bucket_scatter_kernel(
    const int* __restrict__ rel_rows, const int* __restrict__ rel_cols,
    const float* __restrict__ rel_vals, const int* __restrict__ bbase,
    int* __restrict__ cursor, int2* __restrict__ tmp)
{
    __shared__ int hist[NBK], gbase[NBK], cur2[NBK];
    const int r = blockIdx.y, tid = threadIdx.x;
    if (tid < NBK) { hist[tid] = 0; cur2[tid] = 0; }
    __syncthreads();
    const int* rr = rel_rows + (size_t)r * NNZ_C;
    const int* rc = rel_cols + (size_t)r * NNZ_C;
    const float* rv = rel_vals + (size_t)r * NNZ_C;
    int rows[16];
#pragma unroll
    for (int i = 0; i < 16; ++i) {
        int e = blockIdx.x * 4096 + i * 256 + tid;
        rows[i] = (e < NNZ_C) ? rr[e] : -1;
        if (rows[i] >= 0) atomicAdd(&hist[rows[i] >> 9], 1);
    }
    __syncthreads();
    if (tid < NBK)
        gbase[tid] = bbase[r * (NBK + 1) + tid] +
                     (hist[tid] ? atomicAdd(&cursor[r * NBK + tid], hist[tid]) : 0);
    __syncthreads();
    int2* tp = tmp + (size_t)r * NNZ_C;
#pragma unroll
    for (int i = 0; i < 16; ++i) {
        int e = blockIdx.x * 4096 + i * 256 + tid;
        if (rows[i] >= 0) {
            int bk = rows[i] >> 9;
            int rank = atomicAdd(&cur2[bk], 1);
            uint32 fb = __float_as_uint(rv[e]);
            uint32 pk = (uint32)rc[e] | (((fb >> 16) & 0x7FFFu) << 17);
            tp[gbase[bk] + rank] = make_int2((int)pk, rows[i]);
        }
    }
}

// B: refine one bucket: per-row offsets + row-sorted 4B records, all writes coalesced
__global__ __launch_bounds__(256) void bucket_refine_kernel(
    const int2* __restrict__ tmp, const int* __restrict__ bbase,
    int* __restrict__ offs, uint32* __restrict__ edges)
{
    __shared__ int cnt[512], offsL[512], cur[512];
    __shared__ uint32 outb[6656];
    const int b = blockIdx.x, r = blockIdx.y, tid = threadIdx.x;
    const int lane = tid & 63, wid = tid >> 6;
    const int row0 = b << 9;
    const int e0 = bbase[r * (NBK + 1) + b];
    const int e1 = bbase[r * (NBK + 1) + b + 1];
    cnt[tid] = 0; cnt[256 + tid] = 0; cur[tid] = 0; cur[256 + tid] = 0;
    __syncthreads();
    const int2* tp = tmp + (size_t)r * NNZ_C;
    for (int e = e0 + tid; e < e1; e += 256)
        atomicAdd(&cnt[tp[e].y - row0], 1);
    __syncthreads();
    if (wid == 0) {   // wave 0: exclusive scan of 512 counters
        int carry = 0;
        for (int c = 0; c < 8; ++c) {
            int x = cnt[c * 64 + lane];
            int inc = x;
#pragma unroll
            for (int d = 1; d < 64; d <<= 1) {
                int y = __shfl_up(inc, d, 64);
                if (lane >= d) inc += y;
            }
            offsL[c * 64 + lane] = inc - x + carry;
            carry += __shfl(inc, 63, 64);
        }
    }
    __syncthreads();
    // per-row global offsets (covers offs[70000] terminator via bucket 136)
    for (int i = tid; i < 512; i += 256) {
        int row = row0 + i;
        if (row < 70001) offs[(size_t)r * 70001 + row] = e0 + offsL[i];
    }
    for (int e = e0 + tid; e < e1; e += 256) {
        int2 E = tp[e];
        int lr_ = E.y - row0;
        int slot = offsL[lr_] + atomicAdd(&cur[lr_], 1);
        if (slot < 6656) outb[slot] = (uint32)E.x;
    }
    __syncthreads();
    uint32* eo = edges + (size_t)r * NNZ_C + e0;
    for (int i = tid; i < e1 - e0; i += 256) eo[i] = outb[i];
}

// ---------------- gather: T[row][r] = sum_e val * hab[col], all 3 relations fused --------
__global__ __launch_bounds__(256) void gather_kernel(
    const uint32* __restrict__ hab, const uint32* __restrict__ edges,
    const int* __restrict__ offs, uint32* __restrict__ T)
{
    const int row = blockIdx.x * 4 + (threadIdx.x >> 6);
    const int lane = threadIdx.x & 63;
    const int grp = lane >> 4;       // which edge-slot group of the quad
    const int ql  = lane & 15;       // 4 u32 (8 dims) per lane
    const char* __restrict__ habB = (const char*)hab + ql * 16;
    f32x2 acc[3][4];
#pragma unroll
    for (int r = 0; r < 3; ++r)
#pragma unroll
        for (int j = 0; j < 4; ++j) acc[r][j] = (f32x2){0.f, 0.f};
#pragma unroll
    for (int r = 0; r < 3; ++r) {
        const uint32* __restrict__ ed = edges + (size_t)r * NNZ_C;
        const int* __restrict__ of = offs + (size_t)r * 70001;
        const int e0 = of[row], e1 = of[row + 1];
        if (e0 >= e1) continue;
        const uint32 span = (uint32)(e1 - e0);
        const int s0 = e0 & ~3;                      // 16B-aligned edge-record base
        for (int eb = s0; eb < e1; eb += 16) {
            const int base = eb + grp * 4;
            // one aligned 16B load = 4 edge records for this quarter
            uint4 E4 = *(const uint4*)&ed[base];
            uint32 Ej0 = ((uint32)(base + 0 - e0) < span) ? E4.x : 0u;
            uint32 Ej1 = ((uint32)(base + 1 - e0) < span) ? E4.y : 0u;
            uint32 Ej2 = ((uint32)(base + 2 - e0) < span) ? E4.z : 0u;
            uint32 Ej3 = ((uint32)(base + 3 - e0) < span) ? E4.w : 0u;
            // 4 independent row loads -- addresses known before any use
            uint4 u0 = *(const uint4*)(habB + ((Ej0 & 0x1FFFFu) << 8));
            uint4 u1 = *(const uint4*)(habB + ((Ej1 & 0x1FFFFu) << 8));
            uint4 u2 = *(const uint4*)(habB + ((Ej2 & 0x1FFFFu) << 8));
            uint4 u3 = *(const uint4*)(habB + ((Ej3 & 0x1FFFFu) << 8));
            float v0 = __uint_as_float((Ej0 >> 1) & 0x7FFF0000u);
            float v1 = __uint_as_float((Ej1 >> 1) & 0x7FFF0000u);
            float v2 = __uint_as_float((Ej2 >> 1) & 0x7FFF0000u);
            float v3 = __uint_as_float((Ej3 >> 1) & 0x7FFF0000u);
            f32x2 vv;
            vv = (f32x2){v0, v0};
            acc[0 + 0] [0] = acc[0][0]; // no-op to keep formatting stable
            acc[r][0] += vv * (f32x2){bflo(u0.x), bfhi_fast(u0.x)};
            acc[r][1] += vv * (f32x2){bflo(u0.y), bfhi_fast(u0.y)};
            acc[r][2] += vv * (f32x2){bflo(u0.z), bfhi_fast(u0.z)};
            acc[r][3] += vv * (f32x2){bflo(u0.w), bfhi_fast(u0.w)};
            vv = (f32x2){v1, v1};
            acc[r][0] += vv * (f32x2){bflo(u1.x), bfhi_fast(u1.x)};
            acc[r][1] += vv * (f32x2){bflo(u1.y), bfhi_fast(u1.y)};
            acc[r][2] += vv * (f32x2){bflo(u1.z), bfhi_fast(u1.z)};
            acc[r][3] += vv * (f32x2){bflo(u1.w), bfhi_fast(u1.w)};
            vv = (f32x2){v2, v2};
            acc[r][0] += vv * (f32x2){bflo(u2.x), bfhi_fast(u2.x)};
            acc[r][1] += vv * (f32x2){bflo(u2.y), bfhi_fast(u2.y)};
            acc[r][2] += vv * (f32x2){bflo(u2.z), bfhi_fast(u2.z)};
            acc[r][3] += vv * (f32x2){bflo(u2.w), bfhi_fast(u2.w)};
            vv = (f32x2){v3, v3};
            acc[r][0] += vv * (f32x2){bflo(u3.x), bfhi_fast(u3.x)};
            acc[r][1] += vv * (f32x2){bflo(u3.y), bfhi_fast(u3.y)};
            acc[r][2] += vv * (f32x2){bflo(u3.z), bfhi_fast(u3.z)};
            acc[r][3] += vv * (f32x2){bflo(u3.w), bfhi_fast(u3.w)};
        }
    }
    // fold the 4 edge-groups: lanes l, l+16, l+32, l+48 hold same dims
    float* af = (float*)acc;
#pragma unroll
    for (int off = 16; off < 64; off <<= 1)
#pragma unroll
        for (int j = 0; j < 24; ++j) af[j] += __shfl_xor(af[j], off, 64);
    if (grp == 0) {
#pragma unroll
        for (int r = 0; r < 3; ++r) {
            u32x4 o;
            o.x = packbf(acc[r][0].x, acc[r][0].y);
            o.y = packbf(acc[r][1].x, acc[r][1].y);
            o.z = packbf(acc[r][2].x, acc[r][2].y);
            o.w = packbf(acc[r][3].x, acc[r][3].y);
            __builtin_nontemporal_store(o, (u32x4*)&T[(size_t)row * 192 + r * 64 + ql * 4]);
        }
    }
}

// ---------------- weight prep: Wcat[seg][n][r*128+k] = bf16( (U @ W_r)[n][k] ) ----------
__global__ __launch_bounds__(256, 3) void wprep_kernel(
    const float* __restrict__ upi_w, const float* __restrict__ upu_w,
    const float* __restrict__ lin_r_w, int k, uint32* __restrict__ Wcat)
{
    __shared__ float As[128][65];
    __shared__ __align__(8) bf16 Ws[128][66];
    const int which = blockIdx.y, seg = which / 3, r = which % 3;
    const float* U  = (seg == 0 ? upi_w : upu_w) + (size_t)k * 16384;
    const float* Wr = lin_r_w + (size_t)(k * 3 + r) * 16384;
    uint32* out = Wcat + (size_t)seg * 32768;   // u32 row stride 256 (512 bf16)
    const int tid = threadIdx.x;
    const int row0 = blockIdx.x * 64;
#pragma unroll
    for (int i = 0; i < 8; ++i) {
        int id = i * 256 + tid;
        int rr = id >> 5, c4 = (id & 31) << 2;
        float4 v = *(const float4*)&U[(size_t)(row0 + rr) * 128 + c4];
        As[c4][rr] = v.x; As[c4+1][rr] = v.y; As[c4+2][rr] = v.z; As[c4+3][rr] = v.w;
    }
    const int m0 = (tid & 15) * 4;
    const int n0 = (tid >> 4) * 8;
    float acc[4][8];
#pragma unroll
    for (int i = 0; i < 4; ++i)
#pragma unroll
        for (int j = 0; j < 8; ++j) acc[i][j] = 0.f;
    for (int p = 0; p < 2; ++p) {
        if (p) __syncthreads();
        for (int i = 0; i < 32; ++i) {       // Ws[c][kf] = Wr[p*64+kf][c] (transposed)
            int id = i * 256 + tid;
            int c = id >> 6, kf = id & 63;
            Ws[c][kf] = __float2bfloat16(Wr[(size_t)(p * 64 + kf) * 128 + c]);
        }
        __syncthreads();
        for (int k2 = 0; k2 < 32; ++k2) {
            int kk = p * 64 + 2 * k2;
            float av0[4], av1[4];
#pragma unroll
            for (int i = 0; i < 4; ++i) { av0[i] = As[kk][m0 + i]; av1[i] = As[kk + 1][m0 + i]; }
#pragma unroll
            for (int j = 0; j < 8; ++j) {
                uint32 wp = *(const uint32*)&Ws[n0 + j][2 * k2];
                float w0 = bflo(wp), w1 = bfhi(wp);
#pragma unroll
                for (int i = 0; i < 4; ++i)
                    acc[i][j] = fmaf(av1[i], w1, fmaf(av0[i], w0, acc[i][j]));
            }
        }
    }
#pragma unroll
    for (int i = 0; i < 4; ++i) {
        int n = row0 + m0 + i;
#pragma unroll
        for (int j = 0; j < 8; j += 2)
            out[(size_t)n * 256 + (r * 128 + n0 + j) / 2] = packbf(acc[i][j], acc[i][j + 1]);
    }
}

// ---------------- U pack: Wcat[seg][n][384+j] = bf16(U[n][j]) ----------------
__global__ __launch_bounds__(256) void upack_kernel(
    const float* __restrict__ upi_w, const float* __restrict__ upu_w,
    int k, uint32* __restrict__ Wcat)
{
    int id = blockIdx.x * 256 + threadIdx.x;   // 16384 pairs
    int seg = id >> 13, p = id & 8191;
    int n = p >> 6, j2 = (p & 63);
    const float* U = (seg ? upu_w : upi_w) + (size_t)k * 16384;
    float2 w = *(const float2*)&U[(size_t)n * 128 + j2 * 2];
    Wcat[(size_t)seg * 32768 + (size_t)n * 256 + 192 + j2] = packbf(w.x, w.y);
}

// ---------- HGNN update (MFMA, LDS-free, 128-row tiles, items+users in one grid) ----------
// hab = relu([T|hab] @ Wcat^T + b). Blocks [0,391) -> items; [391,548) -> users.
#define HGNN_ITEM_BLOCKS 391
__global__ __launch_bounds__(256) void hgnn_update_mfma_kernel(
    const bf16* __restrict__ T, uint32* __restrict__ hab,
    const bf16* __restrict__ Wcat, const float* __restrict__ upi_b,
    const float* __restrict__ upu_b, int k)
{
    const int tid = threadIdx.x;
    const int wv = tid >> 6, lane = tid & 63, quad = lane >> 4, lr = lane & 15;
    const int bid = blockIdx.x;
    const int seg = (bid >= HGNN_ITEM_BLOCKS) ? 1 : 0;
    const int row0 = seg ? N_ITEMS_C : 0;
    const int M = seg ? N_USERS_C : N_ITEMS_C;
    const int rbase = (seg ? bid - HGNN_ITEM_BLOCKS : bid) * 128;
    const bf16* __restrict__ Wc = Wcat + (size_t)seg * 65536;
    const float* __restrict__ bias = (seg ? upu_b : upi_b) + k * 128;
    const bf16* hb = (const bf16*)hab;
    f32x4 acc[8][2];
#pragma unroll
    for (int mt = 0; mt < 8; ++mt) { acc[mt][0] = (f32x4){0,0,0,0}; acc[mt][1] = (f32x4){0,0,0,0}; }
    int arow[8];
#pragma unroll
    for (int mt = 0; mt < 8; ++mt) {
        int rr = rbase + mt * 16 + lr;
        arow[mt] = row0 + (rr < M ? rr : M - 1);
    }
#pragma unroll
    for (int ks = 0; ks < 16; ++ks) {
        short8 b0 = *(const short8*)&Wc[(size_t)(wv * 32 + lr) * 512 + ks * 32 + quad * 8];
        short8 b1 = *(const short8*)&Wc[(size_t)(wv * 32 + 16 + lr) * 512 + ks * 32 + quad * 8];
#pragma unroll
        for (int mt = 0; mt < 8; ++mt) {
            short8 a;
            if (ks < 12) a = *(const short8*)&T[(size_t)arow[mt] * 384 + ks * 32 + quad * 8];
            else         a = *(const short8*)&hb[(size_t)arow[mt] * 128 + (ks - 12) * 32 + quad * 8];
            acc[mt][0] = __builtin_amdgcn_mfma_f32_16x16x32_bf16(a, b0, acc[mt][0], 0, 0, 0);
            acc[mt][1] = __builtin_amdgcn_mfma_f32_16x16x32_bf16(a, b1, acc[mt][1], 0, 0, 0);
        }
    }
    __syncthreads();   // drain loads: all hab reads done before in-place writes
    unsigned short* hw = (unsigned short*)hab;
#pragma unroll
    for (int s = 0; s < 2; ++s) {
        int col = wv * 32 + s * 16 + lr;
        float bv = bias[col];
#pragma unroll
        for (int mt = 0; mt < 8; ++mt)
#pragma unroll
            for (int reg = 0; reg < 4; ++reg) {
                int rr = rbase + mt * 16 + quad * 4 + reg;
                if (rr < M) {
                    float v = fmaxf(acc[mt][s][reg] + bv, 0.f);
                    hw[(size_t)(row0 + rr) * 128 + col] = __bfloat16_as_ushort(__float2bfloat16(v));
                }
            }
    }
}

// ------- generic MFMA NT gemm (LDS-free, 128-row tiles, single output) -------
__global__ __launch_bounds__(256) void mfma_nt_kernel(
    const bf16* __restrict__ A, const int* __restrict__ rowmap,
    const bf16* __restrict__ W0, const float* __restrict__ b0,
    float* __restrict__ O0, int M)
{
    const int tid = threadIdx.x;
    const int wv = tid >> 6, lane = tid & 63, quad = lane >> 4, lr = lane & 15;
    const int rbase = blockIdx.x * 128;
    int arow[8];
#pragma unroll
    for (int mt = 0; mt < 8; ++mt) {
        int rr = rbase + mt * 16 + lr;
        rr = rr < M ? rr : M - 1;
        arow[mt] = rowmap ? rowmap[rr] : rr;
    }
    f32x4 acc0[8][2];
#pragma unroll
    for (int mt = 0; mt < 8; ++mt) { acc0[mt][0] = (f32x4){0,0,0,0}; acc0[mt][1] = (f32x4){0,0,0,0}; }
#pragma unroll
    for (int ks = 0; ks < 4; ++ks) {
        short8 b00 = *(const short8*)&W0[(size_t)(wv * 32 + lr) * 128 + ks * 32 + quad * 8];
        short8 b01 = *(const short8*)&W0[(size_t)(wv * 32 + 16 + lr) * 128 + ks * 32 + quad * 8];
#pragma unroll
        for (int mt = 0; mt < 8; ++mt) {
            short8 a = *(const short8*)&A[(size_t)arow[mt] * 128 + ks * 32 + quad * 8];
            acc0[mt][0] = __builtin_amdgcn_mfma_f32_16x16x32_bf16(a, b00, acc0[mt][0], 0, 0, 0);
            acc0[mt][1] = __builtin_amdgcn_mfma_f32_16x16x32_bf16(a, b01, acc0[mt][1], 0, 0, 0);
        }
    }
#pragma unroll
    for (int s = 0; s < 2; ++s) {
        int col = wv * 32 + s * 16 + lr;
        float bv0 = b0 ? b0[col] : 0.f;
#pragma unroll
        for (int mt = 0; mt < 8; ++mt)
#pragma unroll
            for (int reg = 0; reg < 4; ++reg) {
                int rr = rbase + mt * 16 + quad * 4 + reg;
                if (rr < M) O0[(size_t)rr * 128 + col] = acc0[mt][s][reg] + bv0;
            }
    }
}

// ------- Ei/Eo GEMM with fused m_i/m_o construction -> AgiG[NTOK][256] bf16 -------
// Source row rr (Ei) feeds dest rr+1 (wrap->0); (Eo) feeds dest rr-1 (wrap->NTOK-1).
// Dest-side mask decides biased-value vs pure-bias; bijective, every dest written once.
__global__ __launch_bounds__(256) void mfma_agi_kernel(
    const bf16* __restrict__ A,
    const bf16* __restrict__ Wi, const bf16* __restrict__ Wo,
    const float* __restrict__ ei_b, const float* __restrict__ eo_b,
    const float* __restrict__ b_iah, const float* __restrict__ b_oah,
    const int* __restrict__ lens, unsigned short* __restrict__ AgiG)
{
    const int tid = threadIdx.x;
    const int wv = tid >> 6, lane = tid & 63, quad = lane >> 4, lr = lane & 15;
    const int rbase = blockIdx.x * 64;
    int arow[4];
#pragma unroll
    for (int mt = 0; mt < 4; ++mt) arow[mt] = rbase + mt * 16 + lr;
    f32x4 acc0[4][2], acc1[4][2];
#pragma unroll
    for (int mt = 0; mt < 4; ++mt) {
        acc0[mt][0] = (f32x4){0,0,0,0}; acc0[mt][1] = (f32x4){0,0,0,0};
        acc1[mt][0] = (f32x4){0,0,0,0}; acc1[mt][1] = (f32x4){0,0,0,0};
    }
#pragma unroll
    for (int ks = 0; ks < 4; ++ks) {
        short8 b00 = *(const short8*)&Wi[(size_t)(wv * 32 + lr) * 128 + ks * 32 + quad * 8];
        short8 b01 = *(const short8*)&Wi[(size_t)(wv * 32 + 16 + lr) * 128 + ks * 32 + quad * 8];
        short8 b10 = *(const short8*)&Wo[(size_t)(wv * 32 + lr) * 128 + ks * 32 + quad * 8];
        short8 b11 = *(const short8*)&Wo[(size_t)(wv * 32 + 16 + lr) * 128 + ks * 32 + quad * 8];
#pragma unroll
        for (int mt = 0; mt < 4; ++mt) {
            short8 a = *(const short8*)&A[(size_t)arow[mt] * 128 + ks * 32 + quad * 8];
            acc0[mt][0] = __builtin_amdgcn_mfma_f32_16x16x32_bf16(a, b00, acc0[mt][0], 0, 0, 0);
            acc0[mt][1] = __builtin_amdgcn_mfma_f32_16x16x32_bf16(a, b01, acc0[mt][1], 0, 0, 0);
            acc1[mt][0] = __builtin_amdgcn_mfma_f32_16x16x32_bf16(a, b10, acc1[mt][0], 0, 0, 0);
            acc1[mt][1] = __builtin_amdgcn_mfma_f32_16x16x32_bf16(a, b11, acc1[mt][1], 0, 0, 0);
        }
    }
#pragma unroll
    for (int s = 0; s < 2; ++s) {
        int col = wv * 32 + s * 16 + lr;
        float bei = ei_b[col], beo = eo_b[col];
        float bia = b_iah[col], boa = b_oah[col];
#pragma unroll
        for (int mt = 0; mt < 4; ++mt)
#pragma unroll
            for (int reg = 0; reg < 4; ++reg) {
                int rr = rbase + mt * 16 + quad * 4 + reg;
                // Ei -> dest rr+1
                int d1 = rr + 1; if (d1 == NTOK) d1 = 0;
                int n1 = d1 / LP, t1 = d1 - n1 * LP, l1 = lens[n1];
                float v1 = bia + ((t1 >= 1 && t1 < l1 - 1) ? acc0[mt][s][reg] + bei : 0.f);
                AgiG[(size_t)d1 * 256 + col] = __bfloat16_as_ushort(__float2bfloat16(v1));
                // Eo -> dest rr-1
                int d2 = rr - 1; if (d2 < 0) d2 = NTOK - 1;
                int n2 = d2 / LP, t2 = d2 - n2 * LP, l2 = lens[n2];
                float v2 = boa + ((t2 < l2 - 2) ? acc1[mt][s][reg] + beo : 0.f);
                AgiG[(size_t)d2 * 256 + 128 + col] = __bfloat16_as_ushort(__float2bfloat16(v2));
            }
    }
}

// ---------------- session prep ----------------
__global__ void session_prep_kernel(const int* __restrict__ ids, const int* __restrict__ uid,
                                    const float* __restrict__ u_type,
                                    int* __restrict__ lens, int* __restrict__ rowmap,
                                    float* __restrict__ out_target, float* __restrict__ out_utype)
{
    int n = blockIdx.x * 256 + threadIdx.x;
    if (n >= NSESS) return;
    int b = n & 255, s = n >> 8;
    const int* row = ids + (size_t)(b * 4 + s) * 50;
    int len = 0;
#pragma unroll
    for (int l = 0; l < 50; ++l) len += (row[l] != 0) ? 1 : 0;
    lens[n] = len;
    rowmap[n] = n * LP + (len - 2);
    out_target[n] = (float)row[len - 1];
    out_utype[n] = u_type[b];
}

// ---------------- c_hist gather from bf16 hab ----------------
__global__ void chist_kernel(const uint32* __restrict__ hab, const int* __restrict__ uid,
                             float* __restrict__ chist) {
    int n = blockIdx.x, d = threadIdx.x;
    uint32 u = hab[(size_t)(N_ITEMS_C + uid[n & 255]) * 64 + (d >> 1)];
    chist[(size_t)n * 128 + d] = (d & 1) ? bfhi(u) : bflo(u);
}

// ---------------- token embedding gather -> bf16 h (4 tokens/block) ----------------
__global__ __launch_bounds__(256) void h0_gather_kernel(
    const float* __restrict__ id_emb, const int* __restrict__ ids,
    const int* __restrict__ lens, uint32* __restrict__ hb) {
    int g = blockIdx.x * 4 + (threadIdx.x >> 6);
    int d = threadIdx.x & 63;          // pair index
    int n = g / LP;
    int tt = g - n * LP;
    int len = lens[n];
    int b = n & 255, s = n >> 8;
    int id = (tt < len - 1) ? ids[(size_t)(b * 4 + s) * 50 + tt] : 0;
    float2 e = *(const float2*)&id_emb[(size_t)id * 128 + d * 2];
    hb[(size_t)g * 64 + d] = packbf(e.x, e.y);
}

// ------- pack session weights f32 -> bf16, plus f32 transpose of fuse_w -------
// ids [0,106496): bf16 pair packs; [106496,139264): ftwf[k][n] = fuse_w[n][k] (f32, exact)
__global__ __launch_bounds__(256) void epack_kernel(
    const float* __restrict__ w_ih, const float* __restrict__ w_hh,
    const float* __restrict__ ei_w, const float* __restrict__ eo_w,
    const float* __restrict__ q2_w, const float* __restrict__ q1_w,
    const float* __restrict__ fuse_w, uint32* __restrict__ dst)
{
    int id = blockIdx.x * 256 + threadIdx.x;   // 139,264 total
    if (id >= 106496) {
        if (id >= 139264) return;
        int f = id - 106496;
        int kk = f >> 7, n = f & 127;
        ((float*)dst)[id] = fuse_w[(size_t)n * 256 + kk];
        return;
    }
    const float* src; int off;
    if      (id <  49152) { src = w_ih; off = id; }
    else if (id <  73728) { src = w_hh; off = id - 49152; }
    else if (id <  81920) { src = ei_w; off = id - 73728; }
    else if (id <  90112) { src = eo_w; off = id - 81920; }
    else if (id <  98304) { src = q2_w; off = id - 90112; }
    else                  { src = q1_w; off = id - 98304; }
    float2 w = *(const float2*)&src[(size_t)off * 2];
    dst[id] = packbf(w.x, w.y);
}

// ---------------- MFMA GRU over bf16 h (in-place, LDS-free) ----------------
// A-fragments read directly from global AgiG (pre-built m_i|m_o) and hb.
// No staging phase, no LDS; one barrier drains hb reads before in-place writes.
__global__ __launch_bounds__(256, 2) void gru_mfma_kernel(
    const bf16* __restrict__ Agi,    // [NTOK][256] bf16
    uint32* __restrict__ hb,
    const bf16* __restrict__ wihb,   // [384][256] bf16
    const bf16* __restrict__ whhb,   // [384][128] bf16
    const float* __restrict__ b_ih, const float* __restrict__ b_hh)
{
    const int tid = threadIdx.x;
    const int wv = tid >> 6;
    const int lane = tid & 63;
    const int quad = lane >> 4;
    const int lr = lane & 15;
    const int c0 = wv * 32;
    const int g0 = blockIdx.x * 64;
    int arow[4];
#pragma unroll
    for (int mt = 0; mt < 4; ++mt) arow[mt] = g0 + mt * 16 + lr;

    // acc[mt][s][j]: j = 0 -> r (gi+gh fused), 1 -> z (gi+gh fused), 2 -> gi_n, 3 -> gh_n
    f32x4 acc[4][2][4];
#pragma unroll
    for (int mt = 0; mt < 4; ++mt)
#pragma unroll
        for (int s = 0; s < 2; ++s)
#pragma unroll
            for (int j = 0; j < 4; ++j) acc[mt][s][j] = (f32x4){0.f, 0.f, 0.f, 0.f};

    // gi: [64x256] @ wihb^T (B fragment reused across 4 M-tiles)
#pragma unroll 2
    for (int ks = 0; ks < 8; ++ks) {
        short8 bfr[2][3];
#pragma unroll
        for (int s = 0; s < 2; ++s)
#pragma unroll
            for (int gte = 0; gte < 3; ++gte) {
                int n0 = gte * 128 + c0 + s * 16 + lr;
                bfr[s][gte] = *(const short8*)&wihb[(size_t)n0 * 256 + ks * 32 + quad * 8];
            }
#pragma unroll
        for (int mt = 0; mt < 4; ++mt) {
            short8 a = *(const short8*)&Agi[(size_t)arow[mt] * 256 + ks * 32 + quad * 8];
#pragma unroll
            for (int s = 0; s < 2; ++s) {
                acc[mt][s][0] = __builtin_amdgcn_mfma_f32_16x16x32_bf16(a, bfr[s][0], acc[mt][s][0], 0, 0, 0);
                acc[mt][s][1] = __builtin_amdgcn_mfma_f32_16x16x32_bf16(a, bfr[s][1], acc[mt][s][1], 0, 0, 0);
                acc[mt][s][2] = __builtin_amdgcn_mfma_f32_16x16x32_bf16(a, bfr[s][2], acc[mt][s][2], 0, 0, 0);
            }
        }
    }
    // gh: [64x128] @ whhb^T -> r/z fuse into same acc; n kept separate (j=3)
    const bf16* hbb = (const bf16*)hb;
#pragma unroll 2
    for (int ks = 0; ks < 4; ++ks) {
        short8 bfr[2][3];
#pragma unroll
        for (int s = 0; s < 2; ++s)
#pragma unroll
            for (int gte = 0; gte < 3; ++gte) {
                int n0 = gte * 128 + c0 + s * 16 + lr;
                bfr[s][gte] = *(const short8*)&whhb[(size_t)n0 * 128 + ks * 32 + quad * 8];
            }
#pragma unroll
        for (int mt = 0; mt < 4; ++mt) {
            short8 a = *(const short8*)&hbb[(size_t)arow[mt] * 128 + ks * 32 + quad * 8];
#pragma unroll
            for (int s = 0; s < 2; ++s) {
                acc[mt][s][0] = __builtin_amdgcn_mfma_f32_16x16x32_bf16(a, bfr[s][0], acc[mt][s][0], 0, 0, 0);
                acc[mt][s][1] = __builtin_amdgcn_mfma_f32_16x16x32_bf16(a, bfr[s][1], acc[mt][s][1], 0, 0, 0);
                acc[mt][s][3] = __builtin_amdgcn_mfma_f32_16x16x32_bf16(a, bfr[s][2], acc[mt][s][3], 0, 0, 0);
            }
        }
    }

    __syncthreads();   // drain all hb reads (all waves) before in-place writes
    unsigned short* hu = (unsigned short*)hb;
#pragma unroll
    for (int s = 0; s < 2; ++s) {
        int col = c0 + s * 16 + lr;
        float brz = b_ih[col] + b_hh[col];
        float bzz = b_ih[col + 128] + b_hh[col + 128];
        float bin = b_ih[col + 256];
        float bhn = b_hh[col + 256];
#pragma unroll
        for (int mt = 0; mt < 4; ++mt)
#pragma unroll
            for (int reg = 0; reg < 4; ++reg) {
                int row = g0 + mt * 16 + quad * 4 + reg;
                float rg = 1.f / (1.f + expf(-(acc[mt][s][0][reg] + brz)));
                float zg = 1.f / (1.f + expf(-(acc[mt][s][1][reg] + bzz)));
                float ng = tanhf(acc[mt][s][2][reg] + bin + rg * (acc[mt][s][3][reg] + bhn));
                size_t idx = (size_t)row * 128 + col;
                float ho = __uint_as_float((uint32)hu[idx] << 16);
                hu[idx] = __bfloat16_as_ushort(__float2bfloat16(ng + zg * (ho - ng)));
            }
    }
}

// ---------------- alpha: al[tok] = att_w . sigmoid(q1[n] + q2[tok]), masked ----------------
// wave per token: coalesced q2 row reads + shfl_xor reduce (replaces attn_fuse's
// per-lane serial 512B row streams).
__global__ __launch_bounds__(256) void alpha_kernel(
    const float* __restrict__ q1h, const float* __restrict__ q2h,
    const float* __restrict__ att_w, const int* __restrict__ lens,
    float* __restrict__ al)
{
    int tok = blockIdx.x * 4 + (threadIdx.x >> 6);
    int lane = threadIdx.x & 63;
    int n = tok / LP, t = tok - n * LP;
    int len = lens[n];
    float2 q2 = *(const float2*)&q2h[(size_t)tok * 128 + lane * 2];
    float2 q1 = *(const float2*)&q1h[(size_t)n * 128 + lane * 2];
    float2 aw = *(const float2*)&att_w[lane * 2];
    float s = aw.x / (1.f + expf(-(q1.x + q2.x))) + aw.y / (1.f + expf(-(q1.y + q2.y)));
#pragma unroll
    for (int off = 1; off < 64; off <<= 1) s += __shfl_xor(s, off, 64);
    if (lane == 0) al[tok] = (t < len - 1) ? s : 0.f;
}

// ---------------- attention readout + fuse layer -> reps (f32 out) ----------------
// alpha precomputed (alG); fuse weights k-major f32 (ftwf) -> all loads coalesced.
__global__ __launch_bounds__(128) void attn_fuse_kernel(
    const float* __restrict__ alG, const unsigned short* __restrict__ hu,
    const float* __restrict__ chist, const int* __restrict__ lens,
    const float* __restrict__ ftwf, const float* __restrict__ fuse_b,
    float* __restrict__ out)
{
    __shared__ float al[64], cv[256];
    const int n = blockIdx.x, tid = threadIdx.x;
    if (tid < 64) al[tid] = (tid < LP) ? alG[(size_t)n * LP + tid] : 0.f;
    __syncthreads();
    const int len = lens[n];
    float ssum = 0.f;
    for (int t = 0; t < len - 1; ++t) ssum += al[t];
    float inv = 1.f / (ssum + 1e-8f);
    float c = 0.f;
    for (int t = 0; t < len - 1; ++t) {
        float hv = __uint_as_float((uint32)hu[(size_t)(n * LP + t) * 128 + tid] << 16);
        c += al[t] * inv * hv;
    }
    cv[tid] = c;
    cv[128 + tid] = chist[(size_t)n * 128 + tid];
    __syncthreads();
    float s = fuse_b[tid];
    for (int kk = 0; kk < 256; ++kk)
        s += cv[kk] * ftwf[(size_t)kk * 128 + tid];
    out[(size_t)n * 128 + tid] = s;
}

// ============================================================================
extern "C" void kernel_launch(void* const* d_in, const int* in_sizes, int n_in,
                              void* d_out, int out_size, void* d_ws, size_t ws_size,
                              hipStream_t stream)
{
    const float* id_emb   = (const float*)d_in[0];
    const float* user_emb = (const float*)d_in[1];
    const float* lin_r_w  = (const float*)d_in[2];
    const float* upi_w    = (const float*)d_in[3];
    const float* upi_b    = (const float*)d_in[4];
    const float* upu_w    = (const float*)d_in[5];
    const float* upu_b    = (const float*)d_in[6];
    const float* w_ih     = (const float*)d_in[7];
    const float* w_hh     = (const float*)d_in[8];
    const float* b_ih     = (const float*)d_in[9];
    const float* b_hh     = (const float*)d_in[10];
    const float* b_iah    = (const float*)d_in[11];
    const float* b_oah    = (const float*)d_in[12];
    const float* ei_w     = (const float*)d_in[13];
    const float* ei_b     = (const float*)d_in[14];
    const float* eo_w     = (const float*)d_in[15];
    const float* eo_b     = (const float*)d_in[16];
    const float* q1_w     = (const float*)d_in[17];
    const float* q2_w     = (const float*)d_in[18];
    const float* att_w    = (const float*)d_in[19];
    const float* fuse_w   = (const float*)d_in[20];
    const float* fuse_b   = (const float*)d_in[21];
    const int*  rel_rows  = (const int*)d_in[22];
    const int*  rel_cols  = (const int*)d_in[23];
    const float* rel_vals = (const float*)d_in[24];
    const int*  ids       = (const int*)d_in[25];
    const int*  uid       = (const int*)d_in[26];
    const float* u_type   = (const float*)d_in[27];
    float* out = (float*)d_out;   // reps[131072] | target[1024] | u_type[1024]

    // ---- workspace layout (u32 units) ----
    uint32* W32    = (uint32*)d_ws;
    uint32* hab    = W32;                                 //  4,480,000 (bf16 nodes)
    uint32* T      = W32 + 4480000;                       // 13,440,000 (bf16, stride 192)
    uint32* edges  = W32 + 17920000;                      //  2,400,000 (4B records)
    int2*   tmp    = (int2*)(W32 + 20320000);             //  2,400,000 int2
    int*    offs   = (int*)(W32 + 25120000);              //  3 x 70001 (pad 210,004)
    int*    bhist  = (int*)(W32 + 25330004);              //  3 x 137
    int*    cursor = (int*)(W32 + 25330415);              //  3 x 137
    int*    bbase  = (int*)(W32 + 25330826);              //  3 x 138
    uint32* Wcat   = W32 + 25331240;                      //  2 x 32768
    float*  q1h    = (float*)(W32 + 25396776);            //  131,072
    float*  chist  = (float*)(W32 + 25527848);            //  131,072
    int*    lens   = (int*)(W32 + 25658920);              //  1024
    int*    rowmap = (int*)(W32 + 25659944);              //  1024
    float*  alG    = (float*)(W32 + 25660968);            //  50,176 (end 25,711,144)
    // session overlays (live only after HGNN):
    uint32* sess_hb = W32;                                // 3,211,264 u32 (bf16 h, over hab)
    float* q2h      = (float*)(W32 + 4480000);            // 6,422,528 f (in T region)
    unsigned short* AgiG = (unsigned short*)(W32 + 10902528); // [NTOK][256] bf16 (in T region)
    uint32* wpk     = W32 + 17920000;                     // packed session wts (over edges)
    uint32* wihb = wpk;              // 49,152
    uint32* whhb = wpk + 49152;      // 24,576
    uint32* eiwb = wpk + 73728;      //  8,192
    uint32* eowb = wpk + 81920;      //  8,192
    uint32* q2wb = wpk + 90112;      //  8,192
    uint32* q1wb = wpk + 98304;      //  8,192
    float*  ftwf = (float*)(wpk + 106496); // 32,768 f32 (fuse_w transposed, k-major)
    if (ws_size < (size_t)27144192 * 4 + 4096) return;

    // ---- init + bucket-sort CSR build (coalesced writes, no 70001-scan) ----
    init_hab_kernel<<<8750, 256, 0, stream>>>((const float4*)id_emb, (const float4*)user_emb, hab);
    hipMemsetAsync(bhist, 0, (size_t)822 * 4, stream);    // bhist + cursor
    bucket_hist_kernel<<<dim3(196, 3), 256, 0, stream>>>(rel_rows, bhist);
    bucket_scan_kernel<<<1, 256, 0, stream>>>(bhist, bbase);
    bucket_scatter_kernel<<<dim3(196, 3), 256, 0, stream>>>(rel_rows, rel_cols, rel_vals,
                                                            bbase, cursor, tmp);
    bucket_refine_kernel<<<dim3(NBK, 3), 256, 0, stream>>>(tmp, bbase, offs, edges);

    // ---- HGNN: 2 layers, MFMA update, no atomics ----
    for (int k = 0; k < 2; ++k) {
        wprep_kernel<<<dim3(2, 6), 256, 0, stream>>>(upi_w, upu_w, lin_r_w, k, Wcat);
        upack_kernel<<<64, 256, 0, stream>>>(upi_w, upu_w, k, Wcat);
        gather_kernel<<<17500, 256, 0, stream>>>(hab, edges, offs, T);
        hgnn_update_mfma_kernel<<<548, 256, 0, stream>>>((const bf16*)T, hab,
            (const bf16*)Wcat, upi_b, upu_b, k);
    }

    // ---- session branch ----
    session_prep_kernel<<<4, 256, 0, stream>>>(ids, uid, u_type, lens, rowmap,
        out + 131072, out + 132096);
    chist_kernel<<<NSESS, 128, 0, stream>>>(hab, uid, chist);   // before sess_hb overwrites hab
    epack_kernel<<<544, 256, 0, stream>>>(w_ih, w_hh, ei_w, eo_w, q2_w, q1_w, fuse_w, wpk);
    h0_gather_kernel<<<NTOK / 4, 256, 0, stream>>>(id_emb, ids, lens, sess_hb);
    mfma_agi_kernel<<<784, 256, 0, stream>>>((const bf16*)sess_hb,
        (const bf16*)eiwb, (const bf16*)eowb, ei_b, eo_b, b_iah, b_oah, lens, AgiG);
    gru_mfma_kernel<<<784, 256, 0, stream>>>((const bf16*)AgiG, sess_hb,
        (const bf16*)wihb, (const bf16*)whhb, b_ih, b_hh);
    mfma_nt_kernel<<<392, 256, 0, stream>>>((const bf16*)sess_hb, nullptr,
        (const bf16*)q2wb, nullptr, q2h, NTOK);
    mfma_nt_kernel<<<8, 256, 0, stream>>>((const bf16*)sess_hb, rowmap,
        (const bf16*)q1wb, nullptr, q1h, NSESS);
    alpha_kernel<<<NTOK / 4, 256, 0, stream>>>(q1h, q2h, att_w, lens, alG);
    attn_fuse_kernel<<<NSESS, 128, 0, stream>>>(alG, (const unsigned short*)sess_hb,
        chist, lens, ftwf, fuse_b, out);
}

// Round 11
// 755.081 us; speedup vs baseline: 1.0194x; 1.0194x over previous
//
#include <hip/hip_runtime.h>
#include <hip/hip_bf16.h>

typedef __hip_bfloat16 bf16;
typedef unsigned int uint32;
typedef __attribute__((ext_vector_type(8))) short short8;   // 8 bf16 (4 VGPRs)
typedef __attribute__((ext_vector_type(4))) float f32x4;
typedef __attribute__((ext_vector_type(2))) float f32x2;
typedef __attribute__((ext_vector_type(4))) uint32 u32x4;   // clang vector: ok for nontemporal

#define N_ITEMS_C 50000
#define N_USERS_C 20000
#define N_NODES_C 70000
#define NNZ_C 800000
#define NSESS 1024
#define LP 49
#define NTOK (NSESS * LP)   // 50176
#define NBK 137             // coarse buckets: row >> 9

__device__ __forceinline__ float bflo(uint32 u) { return __uint_as_float(u << 16); }
__device__ __forceinline__ float bfhi(uint32 u) { return __uint_as_float(u & 0xffff0000u); }
// hi bf16 with low-16 garbage bits: relative error <= 2^-17, far below bf16 rounding.
__device__ __forceinline__ float bfhi_fast(uint32 u) { return __uint_as_float(u); }
__device__ __forceinline__ uint32 packbf(float a, float b) {
    return (uint32)__bfloat16_as_ushort(__float2bfloat16(a)) |
           ((uint32)__bfloat16_as_ushort(__float2bfloat16(b)) << 16);
}

// ---------------- init: hab = bf16(concat(id_emb, user_emb)), 16B/lane ----------------
__global__ void init_hab_kernel(const float4* __restrict__ idp, const float4* __restrict__ usp,
                                uint32* __restrict__ hab) {
    int i = blockIdx.x * 256 + threadIdx.x;           // quad index, 2,240,000 total
    float4 w = (i < 1600000) ? idp[i] : usp[i - 1600000];
    uint2 o = make_uint2(packbf(w.x, w.y), packbf(w.z, w.w));
    *(uint2*)&hab[(size_t)i * 2] = o;
}

// ================= CSR build: coarse-bucket sort with coalesced writes =================
// A1: per-block LDS hist over 137 buckets -> global bhist
__global__ __launch_bounds__(256) void bucket_hist_kernel(
    const int* __restrict__ rel_rows, int* __restrict__ bhist)
{
    __shared__ int hist[NBK];
    const int r = blockIdx.y, tid = threadIdx.x;
    if (tid < NBK) hist[tid] = 0;
    __syncthreads();
    const int* rr = rel_rows + (size_t)r * NNZ_C;
#pragma unroll
    for (int i = 0; i < 16; ++i) {
        int e = blockIdx.x * 4096 + i * 256 + tid;
        if (e < NNZ_C) atomicAdd(&hist[rr[e] >> 9], 1);
    }
    __syncthreads();
    if (tid < NBK && hist[tid]) atomicAdd(&bhist[r * NBK + tid], hist[tid]);
}

// A2: scan bucket totals -> bbase[r][0..NBK]
__global__ __launch_bounds__(256) void bucket_scan_kernel(
    const int* __restrict__ bhist, int* __restrict__ bbase)
{
    __shared__ int s[256];
    const int tid = threadIdx.x;
    for (int r = 0; r < 3; ++r) {
        s[tid] = (tid < NBK) ? bhist[r * NBK + tid] : 0;
        __syncthreads();
        for (int d = 1; d < 256; d <<= 1) {
            int t = (tid >= d) ? s[tid - d] : 0;
            __syncthreads();
            s[tid] += t;
            __syncthreads();
        }
        if (tid < NBK) bbase[r * (NBK + 1) + tid + 1] = s[tid];
        if (tid == 0) bbase[r * (NBK + 1)] = 0;
        __syncthreads();
    }
}

// A3: scatter edges into bucket-contiguous tmp (int2: packed(col|v15), row)
// rows cached in registers across the two passes (no rel_rows re-read).
__global__ __launch_bounds__(256) void bucket_scatter_kernel(
    const int* __restrict__ rel_rows, const int* __restrict__ rel_cols,
    const float* __restrict__ rel_vals, const int* __restrict__ bbase,
    int* __restrict__ cursor, int2* __restrict__ tmp)
{
    __shared__ int hist[NBK], gbase[NBK], cur2[NBK];
    const int r = blockIdx.y, tid = threadIdx.x;
    if (tid < NBK) { hist[tid] = 0; cur2[tid] = 0; }
    __syncthreads();
    const int* rr = rel_rows + (size_t)r * NNZ_C;
    const int* rc = rel_cols + (size_t)r * NNZ_C;
    const float* rv = rel_vals + (size_t)r * NNZ_C;
    int rows[16];
#pragma unroll
    for (int i = 0; i < 16; ++i) {
        int e = blockIdx.x * 4096 + i * 256 + tid;
        rows[i] = (e < NNZ_C) ? rr[e] : -1;
        if (rows[i] >= 0) atomicAdd(&hist[rows[i] >> 9], 1);
    }
    __syncthreads();
    if (tid < NBK)
        gbase[tid] = bbase[r * (NBK + 1) + tid] +
                     (hist[tid] ? atomicAdd(&cursor[r * NBK + tid], hist[tid]) : 0);
    __syncthreads();
    int2* tp = tmp + (size_t)r * NNZ_C;
#pragma unroll
    for (int i = 0; i < 16; ++i) {
        int e = blockIdx.x * 4096 + i * 256 + tid;
        if (rows[i] >= 0) {
            int bk = rows[i] >> 9;
            int rank = atomicAdd(&cur2[bk], 1);
            uint32 fb = __float_as_uint(rv[e]);
            uint32 pk = (uint32)rc[e] | (((fb >> 16) & 0x7FFFu) << 17);
            tp[gbase[bk] + rank] = make_int2((int)pk, rows[i]);
        }
    }
}

// B: refine one bucket: per-row offsets + row-sorted 4B records, all writes coalesced
__global__ __launch_bounds__(256) void bucket_refine_kernel(
    const int2* __restrict__ tmp, const int* __restrict__ bbase,
    int* __restrict__ offs, uint32* __restrict__ edges)
{
    __shared__ int cnt[512], offsL[512], cur[512];
    __shared__ uint32 outb[6656];
    const int b = blockIdx.x, r = blockIdx.y, tid = threadIdx.x;
    const int lane = tid & 63, wid = tid >> 6;
    const int row0 = b << 9;
    const int e0 = bbase[r * (NBK + 1) + b];
    const int e1 = bbase[r * (NBK + 1) + b + 1];
    cnt[tid] = 0; cnt[256 + tid] = 0; cur[tid] = 0; cur[256 + tid] = 0;
    __syncthreads();
    const int2* tp = tmp + (size_t)r * NNZ_C;
    for (int e = e0 + tid; e < e1; e += 256)
        atomicAdd(&cnt[tp[e].y - row0], 1);
    __syncthreads();
    if (wid == 0) {   // wave 0: exclusive scan of 512 counters
        int carry = 0;
        for (int c = 0; c < 8; ++c) {
            int x = cnt[c * 64 + lane];
            int inc = x;
#pragma unroll
            for (int d = 1; d < 64; d <<= 1) {
                int y = __shfl_up(inc, d, 64);
                if (lane >= d) inc += y;
            }
            offsL[c * 64 + lane] = inc - x + carry;
            carry += __shfl(inc, 63, 64);
        }
    }
    __syncthreads();
    // per-row global offsets (covers offs[70000] terminator via bucket 136)
    for (int i = tid; i < 512; i += 256) {
        int row = row0 + i;
        if (row < 70001) offs[(size_t)r * 70001 + row] = e0 + offsL[i];
    }
    for (int e = e0 + tid; e < e1; e += 256) {
        int2 E = tp[e];
        int lr_ = E.y - row0;
        int slot = offsL[lr_] + atomicAdd(&cur[lr_], 1);
        if (slot < 6656) outb[slot] = (uint32)E.x;
    }
    __syncthreads();
    uint32* eo = edges + (size_t)r * NNZ_C + e0;
    for (int i = tid; i < e1 - e0; i += 256) eo[i] = outb[i];
}

// ---------------- gather: T[row][r] = sum_e val * hab[col], all 3 relations fused --------
__global__ __launch_bounds__(256) void gather_kernel(
    const uint32* __restrict__ hab, const uint32* __restrict__ edges,
    const int* __restrict__ offs, uint32* __restrict__ T)
{
    const int row = blockIdx.x * 4 + (threadIdx.x >> 6);
    const int lane = threadIdx.x & 63;
    const int grp = lane >> 4;       // which edge-slot group of the quad
    const int ql  = lane & 15;       // 4 u32 (8 dims) per lane
    const char* __restrict__ habB = (const char*)hab + ql * 16;
    f32x2 acc[3][4];
#pragma unroll
    for (int r = 0; r < 3; ++r)
#pragma unroll
        for (int j = 0; j < 4; ++j) acc[r][j] = (f32x2){0.f, 0.f};
#pragma unroll
    for (int r = 0; r < 3; ++r) {
        const uint32* __restrict__ ed = edges + (size_t)r * NNZ_C;
        const int* __restrict__ of = offs + (size_t)r * 70001;
        const int e0 = of[row], e1 = of[row + 1];
        if (e0 >= e1) continue;
        const uint32 span = (uint32)(e1 - e0);
        const int s0 = e0 & ~3;                      // 16B-aligned edge-record base
        for (int eb = s0; eb < e1; eb += 16) {
            const int base = eb + grp * 4;
            // one aligned 16B load = 4 edge records for this quarter
            uint4 E4 = *(const uint4*)&ed[base];
            uint32 Ej0 = ((uint32)(base + 0 - e0) < span) ? E4.x : 0u;
            uint32 Ej1 = ((uint32)(base + 1 - e0) < span) ? E4.y : 0u;
            uint32 Ej2 = ((uint32)(base + 2 - e0) < span) ? E4.z : 0u;
            uint32 Ej3 = ((uint32)(base + 3 - e0) < span) ? E4.w : 0u;
            // 4 independent row loads -- addresses known before any use
            uint4 u0 = *(const uint4*)(habB + ((Ej0 & 0x1FFFFu) << 8));
            uint4 u1 = *(const uint4*)(habB + ((Ej1 & 0x1FFFFu) << 8));
            uint4 u2 = *(const uint4*)(habB + ((Ej2 & 0x1FFFFu) << 8));
            uint4 u3 = *(const uint4*)(habB + ((Ej3 & 0x1FFFFu) << 8));
            float v0 = __uint_as_float((Ej0 >> 1) & 0x7FFF0000u);
            float v1 = __uint_as_float((Ej1 >> 1) & 0x7FFF0000u);
            float v2 = __uint_as_float((Ej2 >> 1) & 0x7FFF0000u);
            float v3 = __uint_as_float((Ej3 >> 1) & 0x7FFF0000u);
            f32x2 vv;
            vv = (f32x2){v0, v0};
            acc[r][0] += vv * (f32x2){bflo(u0.x), bfhi_fast(u0.x)};
            acc[r][1] += vv * (f32x2){bflo(u0.y), bfhi_fast(u0.y)};
            acc[r][2] += vv * (f32x2){bflo(u0.z), bfhi_fast(u0.z)};
            acc[r][3] += vv * (f32x2){bflo(u0.w), bfhi_fast(u0.w)};
            vv = (f32x2){v1, v1};
            acc[r][0] += vv * (f32x2){bflo(u1.x), bfhi_fast(u1.x)};
            acc[r][1] += vv * (f32x2){bflo(u1.y), bfhi_fast(u1.y)};
            acc[r][2] += vv * (f32x2){bflo(u1.z), bfhi_fast(u1.z)};
            acc[r][3] += vv * (f32x2){bflo(u1.w), bfhi_fast(u1.w)};
            vv = (f32x2){v2, v2};
            acc[r][0] += vv * (f32x2){bflo(u2.x), bfhi_fast(u2.x)};
            acc[r][1] += vv * (f32x2){bflo(u2.y), bfhi_fast(u2.y)};
            acc[r][2] += vv * (f32x2){bflo(u2.z), bfhi_fast(u2.z)};
            acc[r][3] += vv * (f32x2){bflo(u2.w), bfhi_fast(u2.w)};
            vv = (f32x2){v3, v3};
            acc[r][0] += vv * (f32x2){bflo(u3.x), bfhi_fast(u3.x)};
            acc[r][1] += vv * (f32x2){bflo(u3.y), bfhi_fast(u3.y)};
            acc[r][2] += vv * (f32x2){bflo(u3.z), bfhi_fast(u3.z)};
            acc[r][3] += vv * (f32x2){bflo(u3.w), bfhi_fast(u3.w)};
        }
    }
    // fold the 4 edge-groups: lanes l, l+16, l+32, l+48 hold same dims
    float* af = (float*)acc;
#pragma unroll
    for (int off = 16; off < 64; off <<= 1)
#pragma unroll
        for (int j = 0; j < 24; ++j) af[j] += __shfl_xor(af[j], off, 64);
    if (grp == 0) {
#pragma unroll
        for (int r = 0; r < 3; ++r) {
            u32x4 o;
            o.x = packbf(acc[r][0].x, acc[r][0].y);
            o.y = packbf(acc[r][1].x, acc[r][1].y);
            o.z = packbf(acc[r][2].x, acc[r][2].y);
            o.w = packbf(acc[r][3].x, acc[r][3].y);
            __builtin_nontemporal_store(o, (u32x4*)&T[(size_t)row * 192 + r * 64 + ql * 4]);
        }
    }
}

// ---------------- weight prep: Wcat[seg][n][r*128+k] = bf16( (U @ W_r)[n][k] ) ----------
__global__ __launch_bounds__(256, 3) void wprep_kernel(
    const float* __restrict__ upi_w, const float* __restrict__ upu_w,
    const float* __restrict__ lin_r_w, int k, uint32* __restrict__ Wcat)
{
    __shared__ float As[128][65];
    __shared__ __align__(8) bf16 Ws[128][66];
    const int which = blockIdx.y, seg = which / 3, r = which % 3;
    const float* U  = (seg == 0 ? upi_w : upu_w) + (size_t)k * 16384;
    const float* Wr = lin_r_w + (size_t)(k * 3 + r) * 16384;
    uint32* out = Wcat + (size_t)seg * 32768;   // u32 row stride 256 (512 bf16)
    const int tid = threadIdx.x;
    const int row0 = blockIdx.x * 64;
#pragma unroll
    for (int i = 0; i < 8; ++i) {
        int id = i * 256 + tid;
        int rr = id >> 5, c4 = (id & 31) << 2;
        float4 v = *(const float4*)&U[(size_t)(row0 + rr) * 128 + c4];
        As[c4][rr] = v.x; As[c4+1][rr] = v.y; As[c4+2][rr] = v.z; As[c4+3][rr] = v.w;
    }
    const int m0 = (tid & 15) * 4;
    const int n0 = (tid >> 4) * 8;
    float acc[4][8];
#pragma unroll
    for (int i = 0; i < 4; ++i)
#pragma unroll
        for (int j = 0; j < 8; ++j) acc[i][j] = 0.f;
    for (int p = 0; p < 2; ++p) {
        if (p) __syncthreads();
        for (int i = 0; i < 32; ++i) {       // Ws[c][kf] = Wr[p*64+kf][c] (transposed)
            int id = i * 256 + tid;
            int c = id >> 6, kf = id & 63;
            Ws[c][kf] = __float2bfloat16(Wr[(size_t)(p * 64 + kf) * 128 + c]);
        }
        __syncthreads();
        for (int k2 = 0; k2 < 32; ++k2) {
            int kk = p * 64 + 2 * k2;
            float av0[4], av1[4];
#pragma unroll
            for (int i = 0; i < 4; ++i) { av0[i] = As[kk][m0 + i]; av1[i] = As[kk + 1][m0 + i]; }
#pragma unroll
            for (int j = 0; j < 8; ++j) {
                uint32 wp = *(const uint32*)&Ws[n0 + j][2 * k2];
                float w0 = bflo(wp), w1 = bfhi(wp);
#pragma unroll
                for (int i = 0; i < 4; ++i)
                    acc[i][j] = fmaf(av1[i], w1, fmaf(av0[i], w0, acc[i][j]));
            }
        }
    }
#pragma unroll
    for (int i = 0; i < 4; ++i) {
        int n = row0 + m0 + i;
#pragma unroll
        for (int j = 0; j < 8; j += 2)
            out[(size_t)n * 256 + (r * 128 + n0 + j) / 2] = packbf(acc[i][j], acc[i][j + 1]);
    }
}

// ---------------- U pack: Wcat[seg][n][384+j] = bf16(U[n][j]) ----------------
__global__ __launch_bounds__(256) void upack_kernel(
    const float* __restrict__ upi_w, const float* __restrict__ upu_w,
    int k, uint32* __restrict__ Wcat)
{
    int id = blockIdx.x * 256 + threadIdx.x;   // 16384 pairs
    int seg = id >> 13, p = id & 8191;
    int n = p >> 6, j2 = (p & 63);
    const float* U = (seg ? upu_w : upi_w) + (size_t)k * 16384;
    float2 w = *(const float2*)&U[(size_t)n * 128 + j2 * 2];
    Wcat[(size_t)seg * 32768 + (size_t)n * 256 + 192 + j2] = packbf(w.x, w.y);
}

// ---------- HGNN update (MFMA, LDS-free, 128-row tiles, items+users in one grid) ----------
// hab = relu([T|hab] @ Wcat^T + b). Blocks [0,391) -> items; [391,548) -> users.
#define HGNN_ITEM_BLOCKS 391
__global__ __launch_bounds__(256) void hgnn_update_mfma_kernel(
    const bf16* __restrict__ T, uint32* __restrict__ hab,
    const bf16* __restrict__ Wcat, const float* __restrict__ upi_b,
    const float* __restrict__ upu_b, int k)
{
    const int tid = threadIdx.x;
    const int wv = tid >> 6, lane = tid & 63, quad = lane >> 4, lr = lane & 15;
    const int bid = blockIdx.x;
    const int seg = (bid >= HGNN_ITEM_BLOCKS) ? 1 : 0;
    const int row0 = seg ? N_ITEMS_C : 0;
    const int M = seg ? N_USERS_C : N_ITEMS_C;
    const int rbase = (seg ? bid - HGNN_ITEM_BLOCKS : bid) * 128;
    const bf16* __restrict__ Wc = Wcat + (size_t)seg * 65536;
    const float* __restrict__ bias = (seg ? upu_b : upi_b) + k * 128;
    const bf16* hb = (const bf16*)hab;
    f32x4 acc[8][2];
#pragma unroll
    for (int mt = 0; mt < 8; ++mt) { acc[mt][0] = (f32x4){0,0,0,0}; acc[mt][1] = (f32x4){0,0,0,0}; }
    int arow[8];
#pragma unroll
    for (int mt = 0; mt < 8; ++mt) {
        int rr = rbase + mt * 16 + lr;
        arow[mt] = row0 + (rr < M ? rr : M - 1);
    }
#pragma unroll
    for (int ks = 0; ks < 16; ++ks) {
        short8 b0 = *(const short8*)&Wc[(size_t)(wv * 32 + lr) * 512 + ks * 32 + quad * 8];
        short8 b1 = *(const short8*)&Wc[(size_t)(wv * 32 + 16 + lr) * 512 + ks * 32 + quad * 8];
#pragma unroll
        for (int mt = 0; mt < 8; ++mt) {
            short8 a;
            if (ks < 12) a = *(const short8*)&T[(size_t)arow[mt] * 384 + ks * 32 + quad * 8];
            else         a = *(const short8*)&hb[(size_t)arow[mt] * 128 + (ks - 12) * 32 + quad * 8];
            acc[mt][0] = __builtin_amdgcn_mfma_f32_16x16x32_bf16(a, b0, acc[mt][0], 0, 0, 0);
            acc[mt][1] = __builtin_amdgcn_mfma_f32_16x16x32_bf16(a, b1, acc[mt][1], 0, 0, 0);
        }
    }
    __syncthreads();   // drain loads: all hab reads done before in-place writes
    unsigned short* hw = (unsigned short*)hab;
#pragma unroll
    for (int s = 0; s < 2; ++s) {
        int col = wv * 32 + s * 16 + lr;
        float bv = bias[col];
#pragma unroll
        for (int mt = 0; mt < 8; ++mt)
#pragma unroll
            for (int reg = 0; reg < 4; ++reg) {
                int rr = rbase + mt * 16 + quad * 4 + reg;
                if (rr < M) {
                    float v = fmaxf(acc[mt][s][reg] + bv, 0.f);
                    hw[(size_t)(row0 + rr) * 128 + col] = __bfloat16_as_ushort(__float2bfloat16(v));
                }
            }
    }
}

// ------- generic MFMA NT gemm (LDS-free, 128-row tiles, single output) -------
__global__ __launch_bounds__(256) void mfma_nt_kernel(
    const bf16* __restrict__ A, const int* __restrict__ rowmap,
    const bf16* __restrict__ W0, const float* __restrict__ b0,
    float* __restrict__ O0, int M)
{
    const int tid = threadIdx.x;
    const int wv = tid >> 6, lane = tid & 63, quad = lane >> 4, lr = lane & 15;
    const int rbase = blockIdx.x * 128;
    int arow[8];
#pragma unroll
    for (int mt = 0; mt < 8; ++mt) {
        int rr = rbase + mt * 16 + lr;
        rr = rr < M ? rr : M - 1;
        arow[mt] = rowmap ? rowmap[rr] : rr;
    }
    f32x4 acc0[8][2];
#pragma unroll
    for (int mt = 0; mt < 8; ++mt) { acc0[mt][0] = (f32x4){0,0,0,0}; acc0[mt][1] = (f32x4){0,0,0,0}; }
#pragma unroll
    for (int ks = 0; ks < 4; ++ks) {
        short8 b00 = *(const short8*)&W0[(size_t)(wv * 32 + lr) * 128 + ks * 32 + quad * 8];
        short8 b01 = *(const short8*)&W0[(size_t)(wv * 32 + 16 + lr) * 128 + ks * 32 + quad * 8];
#pragma unroll
        for (int mt = 0; mt < 8; ++mt) {
            short8 a = *(const short8*)&A[(size_t)arow[mt] * 128 + ks * 32 + quad * 8];
            acc0[mt][0] = __builtin_amdgcn_mfma_f32_16x16x32_bf16(a, b00, acc0[mt][0], 0, 0, 0);
            acc0[mt][1] = __builtin_amdgcn_mfma_f32_16x16x32_bf16(a, b01, acc0[mt][1], 0, 0, 0);
        }
    }
#pragma unroll
    for (int s = 0; s < 2; ++s) {
        int col = wv * 32 + s * 16 + lr;
        float bv0 = b0 ? b0[col] : 0.f;
#pragma unroll
        for (int mt = 0; mt < 8; ++mt)
#pragma unroll
            for (int reg = 0; reg < 4; ++reg) {
                int rr = rbase + mt * 16 + quad * 4 + reg;
                if (rr < M) O0[(size_t)rr * 128 + col] = acc0[mt][s][reg] + bv0;
            }
    }
}

// ------- Ei/Eo GEMM with fused m_i/m_o construction -> AgiG[NTOK][256] bf16 -------
// 32 rows/block (grid 1568) for 6+ waves/SIMD of latency hiding.
// Source row rr (Ei) feeds dest rr+1 (wrap->0); (Eo) feeds dest rr-1 (wrap->NTOK-1).
__global__ __launch_bounds__(256) void mfma_agi_kernel(
    const bf16* __restrict__ A,
    const bf16* __restrict__ Wi, const bf16* __restrict__ Wo,
    const float* __restrict__ ei_b, const float* __restrict__ eo_b,
    const float* __restrict__ b_iah, const float* __restrict__ b_oah,
    const int* __restrict__ lens, unsigned short* __restrict__ AgiG)
{
    const int tid = threadIdx.x;
    const int wv = tid >> 6, lane = tid & 63, quad = lane >> 4, lr = lane & 15;
    const int rbase = blockIdx.x * 32;
    int arow[2];
#pragma unroll
    for (int mt = 0; mt < 2; ++mt) arow[mt] = rbase + mt * 16 + lr;
    f32x4 acc0[2][2], acc1[2][2];
#pragma unroll
    for (int mt = 0; mt < 2; ++mt) {
        acc0[mt][0] = (f32x4){0,0,0,0}; acc0[mt][1] = (f32x4){0,0,0,0};
        acc1[mt][0] = (f32x4){0,0,0,0}; acc1[mt][1] = (f32x4){0,0,0,0};
    }
#pragma unroll
    for (int ks = 0; ks < 4; ++ks) {
        short8 b00 = *(const short8*)&Wi[(size_t)(wv * 32 + lr) * 128 + ks * 32 + quad * 8];
        short8 b01 = *(const short8*)&Wi[(size_t)(wv * 32 + 16 + lr) * 128 + ks * 32 + quad * 8];
        short8 b10 = *(const short8*)&Wo[(size_t)(wv * 32 + lr) * 128 + ks * 32 + quad * 8];
        short8 b11 = *(const short8*)&Wo[(size_t)(wv * 32 + 16 + lr) * 128 + ks * 32 + quad * 8];
#pragma unroll
        for (int mt = 0; mt < 2; ++mt) {
            short8 a = *(const short8*)&A[(size_t)arow[mt] * 128 + ks * 32 + quad * 8];
            acc0[mt][0] = __builtin_amdgcn_mfma_f32_16x16x32_bf16(a, b00, acc0[mt][0], 0, 0, 0);
            acc0[mt][1] = __builtin_amdgcn_mfma_f32_16x16x32_bf16(a, b01, acc0[mt][1], 0, 0, 0);
            acc1[mt][0] = __builtin_amdgcn_mfma_f32_16x16x32_bf16(a, b10, acc1[mt][0], 0, 0, 0);
            acc1[mt][1] = __builtin_amdgcn_mfma_f32_16x16x32_bf16(a, b11, acc1[mt][1], 0, 0, 0);
        }
    }
#pragma unroll
    for (int s = 0; s < 2; ++s) {
        int col = wv * 32 + s * 16 + lr;
        float bei = ei_b[col], beo = eo_b[col];
        float bia = b_iah[col], boa = b_oah[col];
#pragma unroll
        for (int mt = 0; mt < 2; ++mt)
#pragma unroll
            for (int reg = 0; reg < 4; ++reg) {
                int rr = rbase + mt * 16 + quad * 4 + reg;
                // Ei -> dest rr+1
                int d1 = rr + 1; if (d1 == NTOK) d1 = 0;
                int n1 = d1 / LP, t1 = d1 - n1 * LP, l1 = lens[n1];
                float v1 = bia + ((t1 >= 1 && t1 < l1 - 1) ? acc0[mt][s][reg] + bei : 0.f);
                AgiG[(size_t)d1 * 256 + col] = __bfloat16_as_ushort(__float2bfloat16(v1));
                // Eo -> dest rr-1
                int d2 = rr - 1; if (d2 < 0) d2 = NTOK - 1;
                int n2 = d2 / LP, t2 = d2 - n2 * LP, l2 = lens[n2];
                float v2 = boa + ((t2 < l2 - 2) ? acc1[mt][s][reg] + beo : 0.f);
                AgiG[(size_t)d2 * 256 + 128 + col] = __bfloat16_as_ushort(__float2bfloat16(v2));
            }
    }
}

// ---------------- session prep ----------------
__global__ void session_prep_kernel(const int* __restrict__ ids, const int* __restrict__ uid,
                                    const float* __restrict__ u_type,
                                    int* __restrict__ lens, int* __restrict__ rowmap,
                                    float* __restrict__ out_target, float* __restrict__ out_utype)
{
    int n = blockIdx.x * 256 + threadIdx.x;
    if (n >= NSESS) return;
    int b = n & 255, s = n >> 8;
    const int* row = ids + (size_t)(b * 4 + s) * 50;
    int len = 0;
#pragma unroll
    for (int l = 0; l < 50; ++l) len += (row[l] != 0) ? 1 : 0;
    lens[n] = len;
    rowmap[n] = n * LP + (len - 2);
    out_target[n] = (float)row[len - 1];
    out_utype[n] = u_type[b];
}

// ---------------- c_hist gather from bf16 hab ----------------
__global__ void chist_kernel(const uint32* __restrict__ hab, const int* __restrict__ uid,
                             float* __restrict__ chist) {
    int n = blockIdx.x, d = threadIdx.x;
    uint32 u = hab[(size_t)(N_ITEMS_C + uid[n & 255]) * 64 + (d >> 1)];
    chist[(size_t)n * 128 + d] = (d & 1) ? bfhi(u) : bflo(u);
}

// ---------------- token embedding gather -> bf16 h (4 tokens/block) ----------------
__global__ __launch_bounds__(256) void h0_gather_kernel(
    const float* __restrict__ id_emb, const int* __restrict__ ids,
    const int* __restrict__ lens, uint32* __restrict__ hb) {
    int g = blockIdx.x * 4 + (threadIdx.x >> 6);
    int d = threadIdx.x & 63;          // pair index
    int n = g / LP;
    int tt = g - n * LP;
    int len = lens[n];
    int b = n & 255, s = n >> 8;
    int id = (tt < len - 1) ? ids[(size_t)(b * 4 + s) * 50 + tt] : 0;
    float2 e = *(const float2*)&id_emb[(size_t)id * 128 + d * 2];
    hb[(size_t)g * 64 + d] = packbf(e.x, e.y);
}

// ------- pack session weights f32 -> bf16, plus f32 transpose of fuse_w -------
// ids [0,106496): bf16 pair packs; [106496,139264): ftwf[k][n] = fuse_w[n][k] (f32, exact)
__global__ __launch_bounds__(256) void epack_kernel(
    const float* __restrict__ w_ih, const float* __restrict__ w_hh,
    const float* __restrict__ ei_w, const float* __restrict__ eo_w,
    const float* __restrict__ q2_w, const float* __restrict__ q1_w,
    const float* __restrict__ fuse_w, uint32* __restrict__ dst)
{
    int id = blockIdx.x * 256 + threadIdx.x;   // 139,264 total
    if (id >= 106496) {
        if (id >= 139264) return;
        int f = id - 106496;
        int kk = f >> 7, n = f & 127;
        ((float*)dst)[id] = fuse_w[(size_t)n * 256 + kk];
        return;
    }
    const float* src; int off;
    if      (id <  49152) { src = w_ih; off = id; }
    else if (id <  73728) { src = w_hh; off = id - 49152; }
    else if (id <  81920) { src = ei_w; off = id - 73728; }
    else if (id <  90112) { src = eo_w; off = id - 81920; }
    else if (id <  98304) { src = q2_w; off = id - 90112; }
    else                  { src = q1_w; off = id - 98304; }
    float2 w = *(const float2*)&src[(size_t)off * 2];
    dst[id] = packbf(w.x, w.y);
}

// ---------------- MFMA GRU over bf16 h (in-place, LDS-free, 32 rows/block) ----------------
// grid 1568 -> ~6 waves/SIMD for latency hiding (784x64-row starved at 3/SIMD).
// A-fragments read directly from global AgiG and hb; barrier before in-place write.
__global__ __launch_bounds__(256, 2) void gru_mfma_kernel(
    const bf16* __restrict__ Agi,    // [NTOK][256] bf16
    uint32* __restrict__ hb,
    const bf16* __restrict__ wihb,   // [384][256] bf16
    const bf16* __restrict__ whhb,   // [384][128] bf16
    const float* __restrict__ b_ih, const float* __restrict__ b_hh)
{
    const int tid = threadIdx.x;
    const int wv = tid >> 6;
    const int lane = tid & 63;
    const int quad = lane >> 4;
    const int lr = lane & 15;
    const int c0 = wv * 32;
    const int g0 = blockIdx.x * 32;
    int arow[2];
#pragma unroll
    for (int mt = 0; mt < 2; ++mt) arow[mt] = g0 + mt * 16 + lr;

    // acc[mt][s][j]: j = 0 -> r (gi+gh fused), 1 -> z (gi+gh fused), 2 -> gi_n, 3 -> gh_n
    f32x4 acc[2][2][4];
#pragma unroll
    for (int mt = 0; mt < 2; ++mt)
#pragma unroll
        for (int s = 0; s < 2; ++s)
#pragma unroll
            for (int j = 0; j < 4; ++j) acc[mt][s][j] = (f32x4){0.f, 0.f, 0.f, 0.f};

    // gi: [32x256] @ wihb^T (B fragment reused across 2 M-tiles)
#pragma unroll 2
    for (int ks = 0; ks < 8; ++ks) {
        short8 bfr[2][3];
#pragma unroll
        for (int s = 0; s < 2; ++s)
#pragma unroll
            for (int gte = 0; gte < 3; ++gte) {
                int n0 = gte * 128 + c0 + s * 16 + lr;
                bfr[s][gte] = *(const short8*)&wihb[(size_t)n0 * 256 + ks * 32 + quad * 8];
            }
#pragma unroll
        for (int mt = 0; mt < 2; ++mt) {
            short8 a = *(const short8*)&Agi[(size_t)arow[mt] * 256 + ks * 32 + quad * 8];
#pragma unroll
            for (int s = 0; s < 2; ++s) {
                acc[mt][s][0] = __builtin_amdgcn_mfma_f32_16x16x32_bf16(a, bfr[s][0], acc[mt][s][0], 0, 0, 0);
                acc[mt][s][1] = __builtin_amdgcn_mfma_f32_16x16x32_bf16(a, bfr[s][1], acc[mt][s][1], 0, 0, 0);
                acc[mt][s][2] = __builtin_amdgcn_mfma_f32_16x16x32_bf16(a, bfr[s][2], acc[mt][s][2], 0, 0, 0);
            }
        }
    }
    // gh: [32x128] @ whhb^T -> r/z fuse into same acc; n kept separate (j=3)
    const bf16* hbb = (const bf16*)hb;
#pragma unroll 2
    for (int ks = 0; ks < 4; ++ks) {
        short8 bfr[2][3];
#pragma unroll
        for (int s = 0; s < 2; ++s)
#pragma unroll
            for (int gte = 0; gte < 3; ++gte) {
                int n0 = gte * 128 + c0 + s * 16 + lr;
                bfr[s][gte] = *(const short8*)&whhb[(size_t)n0 * 128 + ks * 32 + quad * 8];
            }
#pragma unroll
        for (int mt = 0; mt < 2; ++mt) {
            short8 a = *(const short8*)&hbb[(size_t)arow[mt] * 128 + ks * 32 + quad * 8];
#pragma unroll
            for (int s = 0; s < 2; ++s) {
                acc[mt][s][0] = __builtin_amdgcn_mfma_f32_16x16x32_bf16(a, bfr[s][0], acc[mt][s][0], 0, 0, 0);
                acc[mt][s][1] = __builtin_amdgcn_mfma_f32_16x16x32_bf16(a, bfr[s][1], acc[mt][s][1], 0, 0, 0);
                acc[mt][s][3] = __builtin_amdgcn_mfma_f32_16x16x32_bf16(a, bfr[s][2], acc[mt][s][3], 0, 0, 0);
            }
        }
    }

    __syncthreads();   // drain all hb reads (all waves) before in-place writes
    unsigned short* hu = (unsigned short*)hb;
#pragma unroll
    for (int s = 0; s < 2; ++s) {
        int col = c0 + s * 16 + lr;
        float brz = b_ih[col] + b_hh[col];
        float bzz = b_ih[col + 128] + b_hh[col + 128];
        float bin = b_ih[col + 256];
        float bhn = b_hh[col + 256];
#pragma unroll
        for (int mt = 0; mt < 2; ++mt)
#pragma unroll
            for (int reg = 0; reg < 4; ++reg) {
                int row = g0 + mt * 16 + quad * 4 + reg;
                float rg = 1.f / (1.f + expf(-(acc[mt][s][0][reg] + brz)));
                float zg = 1.f / (1.f + expf(-(acc[mt][s][1][reg] + bzz)));
                float ng = tanhf(acc[mt][s][2][reg] + bin + rg * (acc[mt][s][3][reg] + bhn));
                size_t idx = (size_t)row * 128 + col;
                float ho = __uint_as_float((uint32)hu[idx] << 16);
                hu[idx] = __bfloat16_as_ushort(__float2bfloat16(ng + zg * (ho - ng)));
            }
    }
}

// ---------------- alpha: al[tok] = att_w . sigmoid(q1[n] + q2[tok]), masked ----------------
// wave per token: coalesced q2 row reads + shfl_xor reduce.
__global__ __launch_bounds__(256) void alpha_kernel(
    const float* __restrict__ q1h, const float* __restrict__ q2h,
    const float* __restrict__ att_w, const int* __restrict__ lens,
    float* __restrict__ al)
{
    int tok = blockIdx.x * 4 + (threadIdx.x >> 6);
    int lane = threadIdx.x & 63;
    int n = tok / LP, t = tok - n * LP;
    int len = lens[n];
    float2 q2 = *(const float2*)&q2h[(size_t)tok * 128 + lane * 2];
    float2 q1 = *(const float2*)&q1h[(size_t)n * 128 + lane * 2];
    float2 aw = *(const float2*)&att_w[lane * 2];
    float s = aw.x / (1.f + expf(-(q1.x + q2.x))) + aw.y / (1.f + expf(-(q1.y + q2.y)));
#pragma unroll
    for (int off = 1; off < 64; off <<= 1) s += __shfl_xor(s, off, 64);
    if (lane == 0) al[tok] = (t < len - 1) ? s : 0.f;
}

// ---------------- attention readout + fuse layer -> reps (f32 out) ----------------
// alpha precomputed (alG); fuse weights k-major f32 (ftwf) -> all loads coalesced.
__global__ __launch_bounds__(128) void attn_fuse_kernel(
    const float* __restrict__ alG, const unsigned short* __restrict__ hu,
    const float* __restrict__ chist, const int* __restrict__ lens,
    const float* __restrict__ ftwf, const float* __restrict__ fuse_b,
    float* __restrict__ out)
{
    __shared__ float al[64], cv[256];
    const int n = blockIdx.x, tid = threadIdx.x;
    if (tid < 64) al[tid] = (tid < LP) ? alG[(size_t)n * LP + tid] : 0.f;
    __syncthreads();
    const int len = lens[n];
    float ssum = 0.f;
    for (int t = 0; t < len - 1; ++t) ssum += al[t];
    float inv = 1.f / (ssum + 1e-8f);
    float c = 0.f;
    for (int t = 0; t < len - 1; ++t) {
        float hv = __uint_as_float((uint32)hu[(size_t)(n * LP + t) * 128 + tid] << 16);
        c += al[t] * inv * hv;
    }
    cv[tid] = c;
    cv[128 + tid] = chist[(size_t)n * 128 + tid];
    __syncthreads();
    float s = fuse_b[tid];
    for (int kk = 0; kk < 256; ++kk)
        s += cv[kk] * ftwf[(size_t)kk * 128 + tid];
    out[(size_t)n * 128 + tid] = s;
}

// ============================================================================
extern "C" void kernel_launch(void* const* d_in, const int* in_sizes, int n_in,
                              void* d_out, int out_size, void* d_ws, size_t ws_size,
                              hipStream_t stream)
{
    const float* id_emb   = (const float*)d_in[0];
    const float* user_emb = (const float*)d_in[1];
    const float* lin_r_w  = (const float*)d_in[2];
    const float* upi_w    = (const float*)d_in[3];
    const float* upi_b    = (const float*)d_in[4];
    const float* upu_w    = (const float*)d_in[5];
    const float* upu_b    = (const float*)d_in[6];
    const float* w_ih     = (const float*)d_in[7];
    const float* w_hh     = (const float*)d_in[8];
    const float* b_ih     = (const float*)d_in[9];
    const float* b_hh     = (const float*)d_in[10];
    const float* b_iah    = (const float*)d_in[11];
    const float* b_oah    = (const float*)d_in[12];
    const float* ei_w     = (const float*)d_in[13];
    const float* ei_b     = (const float*)d_in[14];
    const float* eo_w     = (const float*)d_in[15];
    const float* eo_b     = (const float*)d_in[16];
    const float* q1_w     = (const float*)d_in[17];
    const float* q2_w     = (const float*)d_in[18];
    const float* att_w    = (const float*)d_in[19];
    const float* fuse_w   = (const float*)d_in[20];
    const float* fuse_b   = (const float*)d_in[21];
    const int*  rel_rows  = (const int*)d_in[22];
    const int*  rel_cols  = (const int*)d_in[23];
    const float* rel_vals = (const float*)d_in[24];
    const int*  ids       = (const int*)d_in[25];
    const int*  uid       = (const int*)d_in[26];
    const float* u_type   = (const float*)d_in[27];
    float* out = (float*)d_out;   // reps[131072] | target[1024] | u_type[1024]

    // ---- workspace layout (u32 units) ----
    uint32* W32    = (uint32*)d_ws;
    uint32* hab    = W32;                                 //  4,480,000 (bf16 nodes)
    uint32* T      = W32 + 4480000;                       // 13,440,000 (bf16, stride 192)
    uint32* edges  = W32 + 17920000;                      //  2,400,000 (4B records)
    int2*   tmp    = (int2*)(W32 + 20320000);             //  2,400,000 int2
    int*    offs   = (int*)(W32 + 25120000);              //  3 x 70001 (pad 210,004)
    int*    bhist  = (int*)(W32 + 25330004);              //  3 x 137
    int*    cursor = (int*)(W32 + 25330415);              //  3 x 137
    int*    bbase  = (int*)(W32 + 25330826);              //  3 x 138
    uint32* Wcat   = W32 + 25331240;                      //  2 x 32768
    float*  q1h    = (float*)(W32 + 25396776);            //  131,072
    float*  chist  = (float*)(W32 + 25527848);            //  131,072
    int*    lens   = (int*)(W32 + 25658920);              //  1024
    int*    rowmap = (int*)(W32 + 25659944);              //  1024
    float*  alG    = (float*)(W32 + 25660968);            //  50,176 (end 25,711,144)
    // session overlays (live only after HGNN):
    uint32* sess_hb = W32;                                // 3,211,264 u32 (bf16 h, over hab)
    float* q2h      = (float*)(W32 + 4480000);            // 6,422,528 f (in T region)
    unsigned short* AgiG = (unsigned short*)(W32 + 10902528); // [NTOK][256] bf16 (in T region)
    uint32* wpk     = W32 + 17920000;                     // packed session wts (over edges)
    uint32* wihb = wpk;              // 49,152
    uint32* whhb = wpk + 49152;      // 24,576
    uint32* eiwb = wpk + 73728;      //  8,192
    uint32* eowb = wpk + 81920;      //  8,192
    uint32* q2wb = wpk + 90112;      //  8,192
    uint32* q1wb = wpk + 98304;      //  8,192
    float*  ftwf = (float*)(wpk + 106496); // 32,768 f32 (fuse_w transposed, k-major)
    if (ws_size < (size_t)27144192 * 4 + 4096) return;

    // ---- init + bucket-sort CSR build (coalesced writes, no 70001-scan) ----
    init_hab_kernel<<<8750, 256, 0, stream>>>((const float4*)id_emb, (const float4*)user_emb, hab);
    hipMemsetAsync(bhist, 0, (size_t)822 * 4, stream);    // bhist + cursor
    bucket_hist_kernel<<<dim3(196, 3), 256, 0, stream>>>(rel_rows, bhist);
    bucket_scan_kernel<<<1, 256, 0, stream>>>(bhist, bbase);
    bucket_scatter_kernel<<<dim3(196, 3), 256, 0, stream>>>(rel_rows, rel_cols, rel_vals,
                                                            bbase, cursor, tmp);
    bucket_refine_kernel<<<dim3(NBK, 3), 256, 0, stream>>>(tmp, bbase, offs, edges);

    // ---- HGNN: 2 layers, MFMA update, no atomics ----
    for (int k = 0; k < 2; ++k) {
        wprep_kernel<<<dim3(2, 6), 256, 0, stream>>>(upi_w, upu_w, lin_r_w, k, Wcat);
        upack_kernel<<<64, 256, 0, stream>>>(upi_w, upu_w, k, Wcat);
        gather_kernel<<<17500, 256, 0, stream>>>(hab, edges, offs, T);
        hgnn_update_mfma_kernel<<<548, 256, 0, stream>>>((const bf16*)T, hab,
            (const bf16*)Wcat, upi_b, upu_b, k);
    }

    // ---- session branch ----
    session_prep_kernel<<<4, 256, 0, stream>>>(ids, uid, u_type, lens, rowmap,
        out + 131072, out + 132096);
    chist_kernel<<<NSESS, 128, 0, stream>>>(hab, uid, chist);   // before sess_hb overwrites hab
    epack_kernel<<<544, 256, 0, stream>>>(w_ih, w_hh, ei_w, eo_w, q2_w, q1_w, fuse_w, wpk);
    h0_gather_kernel<<<NTOK / 4, 256, 0, stream>>>(id_emb, ids, lens, sess_hb);
    mfma_agi_kernel<<<1568, 256, 0, stream>>>((const bf16*)sess_hb,
        (const bf16*)eiwb, (const bf16*)eowb, ei_b, eo_b, b_iah, b_oah, lens, AgiG);
    gru_mfma_kernel<<<1568, 256, 0, stream>>>((const bf16*)AgiG, sess_hb,
        (const bf16*)wihb, (const bf16*)whhb, b_ih, b_hh);
    mfma_nt_kernel<<<392, 256, 0, stream>>>((const bf16*)sess_hb, nullptr,
        (const bf16*)q2wb, nullptr, q2h, NTOK);
    mfma_nt_kernel<<<8, 256, 0, stream>>>((const bf16*)sess_hb, rowmap,
        (const bf16*)q1wb, nullptr, q1h, NSESS);
    alpha_kernel<<<NTOK / 4, 256, 0, stream>>>(q1h, q2h, att_w, lens, alG);
    attn_fuse_kernel<<<NSESS, 128, 0, stream>>>(alG, (const unsigned short*)sess_hb,
        chist, lens, ftwf, fuse_b, out);
}

// Round 12
// 748.160 us; speedup vs baseline: 1.0288x; 1.0093x over previous
//
#include <hip/hip_runtime.h>
#include <hip/hip_bf16.h>

typedef __hip_bfloat16 bf16;
typedef unsigned int uint32;
typedef __attribute__((ext_vector_type(8))) short short8;   // 8 bf16 (4 VGPRs)
typedef __attribute__((ext_vector_type(4))) float f32x4;
typedef __attribute__((ext_vector_type(2))) float f32x2;
typedef __attribute__((ext_vector_type(4))) uint32 u32x4;   // clang vector: ok for nontemporal

#define N_ITEMS_C 50000
#define N_USERS_C 20000
#define N_NODES_C 70000
#define NNZ_C 800000
#define NSESS 1024
#define LP 49
#define NTOK (NSESS * LP)   // 50176
#define NBK 137             // coarse buckets: row >> 9

__device__ __forceinline__ float bflo(uint32 u) { return __uint_as_float(u << 16); }
__device__ __forceinline__ float bfhi(uint32 u) { return __uint_as_float(u & 0xffff0000u); }
// hi bf16 with low-16 garbage bits: relative error <= 2^-17, far below bf16 rounding.
__device__ __forceinline__ float bfhi_fast(uint32 u) { return __uint_as_float(u); }
__device__ __forceinline__ uint32 packbf(float a, float b) {
    return (uint32)__bfloat16_as_ushort(__float2bfloat16(a)) |
           ((uint32)__bfloat16_as_ushort(__float2bfloat16(b)) << 16);
}

// ---------------- init: hab = bf16(concat(id_emb, user_emb)), 16B/lane ----------------
__global__ void init_hab_kernel(const float4* __restrict__ idp, const float4* __restrict__ usp,
                                uint32* __restrict__ hab) {
    int i = blockIdx.x * 256 + threadIdx.x;           // quad index, 2,240,000 total
    float4 w = (i < 1600000) ? idp[i] : usp[i - 1600000];
    uint2 o = make_uint2(packbf(w.x, w.y), packbf(w.z, w.w));
    *(uint2*)&hab[(size_t)i * 2] = o;
}

// ================= CSR build: coarse-bucket sort with coalesced writes =================
// A1: per-block LDS hist over 137 buckets -> global bhist
__global__ __launch_bounds__(256) void bucket_hist_kernel(
    const int* __restrict__ rel_rows, int* __restrict__ bhist)
{
    __shared__ int hist[NBK];
    const int r = blockIdx.y, tid = threadIdx.x;
    if (tid < NBK) hist[tid] = 0;
    __syncthreads();
    const int* rr = rel_rows + (size_t)r * NNZ_C;
#pragma unroll
    for (int i = 0; i < 16; ++i) {
        int e = blockIdx.x * 4096 + i * 256 + tid;
        if (e < NNZ_C) atomicAdd(&hist[rr[e] >> 9], 1);
    }
    __syncthreads();
    if (tid < NBK && hist[tid]) atomicAdd(&bhist[r * NBK + tid], hist[tid]);
}

// A2: scan bucket totals -> bbase[r][0..NBK]
__global__ __launch_bounds__(256) void bucket_scan_kernel(
    const int* __restrict__ bhist, int* __restrict__ bbase)
{
    __shared__ int s[256];
    const int tid = threadIdx.x;
    for (int r = 0; r < 3; ++r) {
        s[tid] = (tid < NBK) ? bhist[r * NBK + tid] : 0;
        __syncthreads();
        for (int d = 1; d < 256; d <<= 1) {
            int t = (tid >= d) ? s[tid - d] : 0;
            __syncthreads();
            s[tid] += t;
            __syncthreads();
        }
        if (tid < NBK) bbase[r * (NBK + 1) + tid + 1] = s[tid];
        if (tid == 0) bbase[r * (NBK + 1)] = 0;
        __syncthreads();
    }
}

// A3: scatter edges into bucket-contiguous tmp (int2: packed(col|v15), row)
// rows cached in registers across the two passes (no rel_rows re-read).
__global__ __launch_bounds__(256) void bucket_scatter_kernel(
    const int* __restrict__ rel_rows, const int* __restrict__ rel_cols,
    const float* __restrict__ rel_vals, const int* __restrict__ bbase,
    int* __restrict__ cursor, int2* __restrict__ tmp)
{
    __shared__ int hist[NBK], gbase[NBK], cur2[NBK];
    const int r = blockIdx.y, tid = threadIdx.x;
    if (tid < NBK) { hist[tid] = 0; cur2[tid] = 0; }
    __syncthreads();
    const int* rr = rel_rows + (size_t)r * NNZ_C;
    const int* rc = rel_cols + (size_t)r * NNZ_C;
    const float* rv = rel_vals + (size_t)r * NNZ_C;
    int rows[16];
#pragma unroll
    for (int i = 0; i < 16; ++i) {
        int e = blockIdx.x * 4096 + i * 256 + tid;
        rows[i] = (e < NNZ_C) ? rr[e] : -1;
        if (rows[i] >= 0) atomicAdd(&hist[rows[i] >> 9], 1);
    }
    __syncthreads();
    if (tid < NBK)
        gbase[tid] = bbase[r * (NBK + 1) + tid] +
                     (hist[tid] ? atomicAdd(&cursor[r * NBK + tid], hist[tid]) : 0);
    __syncthreads();
    int2* tp = tmp + (size_t)r * NNZ_C;
#pragma unroll
    for (int i = 0; i < 16; ++i) {
        int e = blockIdx.x * 4096 + i * 256 + tid;
        if (rows[i] >= 0) {
            int bk = rows[i] >> 9;
            int rank = atomicAdd(&cur2[bk], 1);
            uint32 fb = __float_as_uint(rv[e]);
            uint32 pk = (uint32)rc[e] | (((fb >> 16) & 0x7FFFu) << 17);
            tp[gbase[bk] + rank] = make_int2((int)pk, rows[i]);
        }
    }
}

// B: refine one bucket: per-row offsets + row-sorted 4B records, all writes coalesced
__global__ __launch_bounds__(256) void bucket_refine_kernel(
    const int2* __restrict__ tmp, const int* __restrict__ bbase,
    int* __restrict__ offs, uint32* __restrict__ edges)
{
    __shared__ int cnt[512], offsL[512], cur[512];
    __shared__ uint32 outb[6656];
    const int b = blockIdx.x, r = blockIdx.y, tid = threadIdx.x;
    const int lane = tid & 63, wid = tid >> 6;
    const int row0 = b << 9;
    const int e0 = bbase[r * (NBK + 1) + b];
    const int e1 = bbase[r * (NBK + 1) + b + 1];
    cnt[tid] = 0; cnt[256 + tid] = 0; cur[tid] = 0; cur[256 + tid] = 0;
    __syncthreads();
    const int2* tp = tmp + (size_t)r * NNZ_C;
    for (int e = e0 + tid; e < e1; e += 256)
        atomicAdd(&cnt[tp[e].y - row0], 1);
    __syncthreads();
    if (wid == 0) {   // wave 0: exclusive scan of 512 counters
        int carry = 0;
        for (int c = 0; c < 8; ++c) {
            int x = cnt[c * 64 + lane];
            int inc = x;
#pragma unroll
            for (int d = 1; d < 64; d <<= 1) {
                int y = __shfl_up(inc, d, 64);
                if (lane >= d) inc += y;
            }
            offsL[c * 64 + lane] = inc - x + carry;
            carry += __shfl(inc, 63, 64);
        }
    }
    __syncthreads();
    // per-row global offsets (covers offs[70000] terminator via bucket 136)
    for (int i = tid; i < 512; i += 256) {
        int row = row0 + i;
        if (row < 70001) offs[(size_t)r * 70001 + row] = e0 + offsL[i];
    }
    for (int e = e0 + tid; e < e1; e += 256) {
        int2 E = tp[e];
        int lr_ = E.y - row0;
        int slot = offsL[lr_] + atomicAdd(&cur[lr_], 1);
        if (slot < 6656) outb[slot] = (uint32)E.x;
    }
    __syncthreads();
    uint32* eo = edges + (size_t)r * NNZ_C + e0;
    for (int i = tid; i < e1 - e0; i += 256) eo[i] = outb[i];
}

// ---------------- gather: T[row][r] = sum_e val * hab[col], all 3 relations fused --------
__global__ __launch_bounds__(256) void gather_kernel(
    const uint32* __restrict__ hab, const uint32* __restrict__ edges,
    const int* __restrict__ offs, uint32* __restrict__ T)
{
    const int row = blockIdx.x * 4 + (threadIdx.x >> 6);
    const int lane = threadIdx.x & 63;
    const int grp = lane >> 4;       // which edge-slot group of the quad
    const int ql  = lane & 15;       // 4 u32 (8 dims) per lane
    const char* __restrict__ habB = (const char*)hab + ql * 16;
    f32x2 acc[3][4];
#pragma unroll
    for (int r = 0; r < 3; ++r)
#pragma unroll
        for (int j = 0; j < 4; ++j) acc[r][j] = (f32x2){0.f, 0.f};
#pragma unroll
    for (int r = 0; r < 3; ++r) {
        const uint32* __restrict__ ed = edges + (size_t)r * NNZ_C;
        const int* __restrict__ of = offs + (size_t)r * 70001;
        const int e0 = of[row], e1 = of[row + 1];
        if (e0 >= e1) continue;
        const uint32 span = (uint32)(e1 - e0);
        const int s0 = e0 & ~3;                      // 16B-aligned edge-record base
        for (int eb = s0; eb < e1; eb += 16) {
            const int base = eb + grp * 4;
            // one aligned 16B load = 4 edge records for this quarter
            uint4 E4 = *(const uint4*)&ed[base];
            uint32 Ej0 = ((uint32)(base + 0 - e0) < span) ? E4.x : 0u;
            uint32 Ej1 = ((uint32)(base + 1 - e0) < span) ? E4.y : 0u;
            uint32 Ej2 = ((uint32)(base + 2 - e0) < span) ? E4.z : 0u;
            uint32 Ej3 = ((uint32)(base + 3 - e0) < span) ? E4.w : 0u;
            // 4 independent row loads -- addresses known before any use
            uint4 u0 = *(const uint4*)(habB + ((Ej0 & 0x1FFFFu) << 8));
            uint4 u1 = *(const uint4*)(habB + ((Ej1 & 0x1FFFFu) << 8));
            uint4 u2 = *(const uint4*)(habB + ((Ej2 & 0x1FFFFu) << 8));
            uint4 u3 = *(const uint4*)(habB + ((Ej3 & 0x1FFFFu) << 8));
            float v0 = __uint_as_float((Ej0 >> 1) & 0x7FFF0000u);
            float v1 = __uint_as_float((Ej1 >> 1) & 0x7FFF0000u);
            float v2 = __uint_as_float((Ej2 >> 1) & 0x7FFF0000u);
            float v3 = __uint_as_float((Ej3 >> 1) & 0x7FFF0000u);
            f32x2 vv;
            vv = (f32x2){v0, v0};
            acc[r][0] += vv * (f32x2){bflo(u0.x), bfhi_fast(u0.x)};
            acc[r][1] += vv * (f32x2){bflo(u0.y), bfhi_fast(u0.y)};
            acc[r][2] += vv * (f32x2){bflo(u0.z), bfhi_fast(u0.z)};
            acc[r][3] += vv * (f32x2){bflo(u0.w), bfhi_fast(u0.w)};
            vv = (f32x2){v1, v1};
            acc[r][0] += vv * (f32x2){bflo(u1.x), bfhi_fast(u1.x)};
            acc[r][1] += vv * (f32x2){bflo(u1.y), bfhi_fast(u1.y)};
            acc[r][2] += vv * (f32x2){bflo(u1.z), bfhi_fast(u1.z)};
            acc[r][3] += vv * (f32x2){bflo(u1.w), bfhi_fast(u1.w)};
            vv = (f32x2){v2, v2};
            acc[r][0] += vv * (f32x2){bflo(u2.x), bfhi_fast(u2.x)};
            acc[r][1] += vv * (f32x2){bflo(u2.y), bfhi_fast(u2.y)};
            acc[r][2] += vv * (f32x2){bflo(u2.z), bfhi_fast(u2.z)};
            acc[r][3] += vv * (f32x2){bflo(u2.w), bfhi_fast(u2.w)};
            vv = (f32x2){v3, v3};
            acc[r][0] += vv * (f32x2){bflo(u3.x), bfhi_fast(u3.x)};
            acc[r][1] += vv * (f32x2){bflo(u3.y), bfhi_fast(u3.y)};
            acc[r][2] += vv * (f32x2){bflo(u3.z), bfhi_fast(u3.z)};
            acc[r][3] += vv * (f32x2){bflo(u3.w), bfhi_fast(u3.w)};
        }
    }
    // fold the 4 edge-groups: lanes l, l+16, l+32, l+48 hold same dims
    float* af = (float*)acc;
#pragma unroll
    for (int off = 16; off < 64; off <<= 1)
#pragma unroll
        for (int j = 0; j < 24; ++j) af[j] += __shfl_xor(af[j], off, 64);
    if (grp == 0) {
#pragma unroll
        for (int r = 0; r < 3; ++r) {
            u32x4 o;
            o.x = packbf(acc[r][0].x, acc[r][0].y);
            o.y = packbf(acc[r][1].x, acc[r][1].y);
            o.z = packbf(acc[r][2].x, acc[r][2].y);
            o.w = packbf(acc[r][3].x, acc[r][3].y);
            __builtin_nontemporal_store(o, (u32x4*)&T[(size_t)row * 192 + r * 64 + ql * 4]);
        }
    }
}

// ---------------- weight prep: Wcat[seg][n][r*128+k] = bf16( (U @ W_r)[n][k] ) ----------
__global__ __launch_bounds__(256, 3) void wprep_kernel(
    const float* __restrict__ upi_w, const float* __restrict__ upu_w,
    const float* __restrict__ lin_r_w, int k, uint32* __restrict__ Wcat)
{
    __shared__ float As[128][65];
    __shared__ __align__(8) bf16 Ws[128][66];
    const int which = blockIdx.y, seg = which / 3, r = which % 3;
    const float* U  = (seg == 0 ? upi_w : upu_w) + (size_t)k * 16384;
    const float* Wr = lin_r_w + (size_t)(k * 3 + r) * 16384;
    uint32* out = Wcat + (size_t)seg * 32768;   // u32 row stride 256 (512 bf16)
    const int tid = threadIdx.x;
    const int row0 = blockIdx.x * 64;
#pragma unroll
    for (int i = 0; i < 8; ++i) {
        int id = i * 256 + tid;
        int rr = id >> 5, c4 = (id & 31) << 2;
        float4 v = *(const float4*)&U[(size_t)(row0 + rr) * 128 + c4];
        As[c4][rr] = v.x; As[c4+1][rr] = v.y; As[c4+2][rr] = v.z; As[c4+3][rr] = v.w;
    }
    const int m0 = (tid & 15) * 4;
    const int n0 = (tid >> 4) * 8;
    float acc[4][8];
#pragma unroll
    for (int i = 0; i < 4; ++i)
#pragma unroll
        for (int j = 0; j < 8; ++j) acc[i][j] = 0.f;
    for (int p = 0; p < 2; ++p) {
        if (p) __syncthreads();
        for (int i = 0; i < 32; ++i) {       // Ws[c][kf] = Wr[p*64+kf][c] (transposed)
            int id = i * 256 + tid;
            int c = id >> 6, kf = id & 63;
            Ws[c][kf] = __float2bfloat16(Wr[(size_t)(p * 64 + kf) * 128 + c]);
        }
        __syncthreads();
        for (int k2 = 0; k2 < 32; ++k2) {
            int kk = p * 64 + 2 * k2;
            float av0[4], av1[4];
#pragma unroll
            for (int i = 0; i < 4; ++i) { av0[i] = As[kk][m0 + i]; av1[i] = As[kk + 1][m0 + i]; }
#pragma unroll
            for (int j = 0; j < 8; ++j) {
                uint32 wp = *(const uint32*)&Ws[n0 + j][2 * k2];
                float w0 = bflo(wp), w1 = bfhi(wp);
#pragma unroll
                for (int i = 0; i < 4; ++i)
                    acc[i][j] = fmaf(av1[i], w1, fmaf(av0[i], w0, acc[i][j]));
            }
        }
    }
#pragma unroll
    for (int i = 0; i < 4; ++i) {
        int n = row0 + m0 + i;
#pragma unroll
        for (int j = 0; j < 8; j += 2)
            out[(size_t)n * 256 + (r * 128 + n0 + j) / 2] = packbf(acc[i][j], acc[i][j + 1]);
    }
}

// ---------------- U pack: Wcat[seg][n][384+j] = bf16(U[n][j]) ----------------
__global__ __launch_bounds__(256) void upack_kernel(
    const float* __restrict__ upi_w, const float* __restrict__ upu_w,
    int k, uint32* __restrict__ Wcat)
{
    int id = blockIdx.x * 256 + threadIdx.x;   // 16384 pairs
    int seg = id >> 13, p = id & 8191;
    int n = p >> 6, j2 = (p & 63);
    const float* U = (seg ? upu_w : upi_w) + (size_t)k * 16384;
    float2 w = *(const float2*)&U[(size_t)n * 128 + j2 * 2];
    Wcat[(size_t)seg * 32768 + (size_t)n * 256 + 192 + j2] = packbf(w.x, w.y);
}

// ---------- HGNN update (MFMA, LDS-free, 128-row tiles, items+users in one grid) ----------
// hab = relu([T|hab] @ Wcat^T + b). Blocks [0,391) -> items; [391,548) -> users.
#define HGNN_ITEM_BLOCKS 391
__global__ __launch_bounds__(256) void hgnn_update_mfma_kernel(
    const bf16* __restrict__ T, uint32* __restrict__ hab,
    const bf16* __restrict__ Wcat, const float* __restrict__ upi_b,
    const float* __restrict__ upu_b, int k)
{
    const int tid = threadIdx.x;
    const int wv = tid >> 6, lane = tid & 63, quad = lane >> 4, lr = lane & 15;
    const int bid = blockIdx.x;
    const int seg = (bid >= HGNN_ITEM_BLOCKS) ? 1 : 0;
    const int row0 = seg ? N_ITEMS_C : 0;
    const int M = seg ? N_USERS_C : N_ITEMS_C;
    const int rbase = (seg ? bid - HGNN_ITEM_BLOCKS : bid) * 128;
    const bf16* __restrict__ Wc = Wcat + (size_t)seg * 65536;
    const float* __restrict__ bias = (seg ? upu_b : upi_b) + k * 128;
    const bf16* hb = (const bf16*)hab;
    f32x4 acc[8][2];
#pragma unroll
    for (int mt = 0; mt < 8; ++mt) { acc[mt][0] = (f32x4){0,0,0,0}; acc[mt][1] = (f32x4){0,0,0,0}; }
    int arow[8];
#pragma unroll
    for (int mt = 0; mt < 8; ++mt) {
        int rr = rbase + mt * 16 + lr;
        arow[mt] = row0 + (rr < M ? rr : M - 1);
    }
#pragma unroll
    for (int ks = 0; ks < 16; ++ks) {
        short8 b0 = *(const short8*)&Wc[(size_t)(wv * 32 + lr) * 512 + ks * 32 + quad * 8];
        short8 b1 = *(const short8*)&Wc[(size_t)(wv * 32 + 16 + lr) * 512 + ks * 32 + quad * 8];
#pragma unroll
        for (int mt = 0; mt < 8; ++mt) {
            short8 a;
            if (ks < 12) a = *(const short8*)&T[(size_t)arow[mt] * 384 + ks * 32 + quad * 8];
            else         a = *(const short8*)&hb[(size_t)arow[mt] * 128 + (ks - 12) * 32 + quad * 8];
            acc[mt][0] = __builtin_amdgcn_mfma_f32_16x16x32_bf16(a, b0, acc[mt][0], 0, 0, 0);
            acc[mt][1] = __builtin_amdgcn_mfma_f32_16x16x32_bf16(a, b1, acc[mt][1], 0, 0, 0);
        }
    }
    __syncthreads();   // drain loads: all hab reads done before in-place writes
    unsigned short* hw = (unsigned short*)hab;
#pragma unroll
    for (int s = 0; s < 2; ++s) {
        int col = wv * 32 + s * 16 + lr;
        float bv = bias[col];
#pragma unroll
        for (int mt = 0; mt < 8; ++mt)
#pragma unroll
            for (int reg = 0; reg < 4; ++reg) {
                int rr = rbase + mt * 16 + quad * 4 + reg;
                if (rr < M) {
                    float v = fmaxf(acc[mt][s][reg] + bv, 0.f);
                    hw[(size_t)(row0 + rr) * 128 + col] = __bfloat16_as_ushort(__float2bfloat16(v));
                }
            }
    }
}

// ------- generic MFMA NT gemm (LDS-free, 128-row tiles, single output) -------
__global__ __launch_bounds__(256) void mfma_nt_kernel(
    const bf16* __restrict__ A, const int* __restrict__ rowmap,
    const bf16* __restrict__ W0, const float* __restrict__ b0,
    float* __restrict__ O0, int M)
{
    const int tid = threadIdx.x;
    const int wv = tid >> 6, lane = tid & 63, quad = lane >> 4, lr = lane & 15;
    const int rbase = blockIdx.x * 128;
    int arow[8];
#pragma unroll
    for (int mt = 0; mt < 8; ++mt) {
        int rr = rbase + mt * 16 + lr;
        rr = rr < M ? rr : M - 1;
        arow[mt] = rowmap ? rowmap[rr] : rr;
    }
    f32x4 acc0[8][2];
#pragma unroll
    for (int mt = 0; mt < 8; ++mt) { acc0[mt][0] = (f32x4){0,0,0,0}; acc0[mt][1] = (f32x4){0,0,0,0}; }
#pragma unroll
    for (int ks = 0; ks < 4; ++ks) {
        short8 b00 = *(const short8*)&W0[(size_t)(wv * 32 + lr) * 128 + ks * 32 + quad * 8];
        short8 b01 = *(const short8*)&W0[(size_t)(wv * 32 + 16 + lr) * 128 + ks * 32 + quad * 8];
#pragma unroll
        for (int mt = 0; mt < 8; ++mt) {
            short8 a = *(const short8*)&A[(size_t)arow[mt] * 128 + ks * 32 + quad * 8];
            acc0[mt][0] = __builtin_amdgcn_mfma_f32_16x16x32_bf16(a, b00, acc0[mt][0], 0, 0, 0);
            acc0[mt][1] = __builtin_amdgcn_mfma_f32_16x16x32_bf16(a, b01, acc0[mt][1], 0, 0, 0);
        }
    }
#pragma unroll
    for (int s = 0; s < 2; ++s) {
        int col = wv * 32 + s * 16 + lr;
        float bv0 = b0 ? b0[col] : 0.f;
#pragma unroll
        for (int mt = 0; mt < 8; ++mt)
#pragma unroll
            for (int reg = 0; reg < 4; ++reg) {
                int rr = rbase + mt * 16 + quad * 4 + reg;
                if (rr < M) O0[(size_t)rr * 128 + col] = acc0[mt][s][reg] + bv0;
            }
    }
}

// ---------------- session prep ----------------
__global__ void session_prep_kernel(const int* __restrict__ ids, const int* __restrict__ uid,
                                    const float* __restrict__ u_type,
                                    int* __restrict__ lens, int* __restrict__ rowmap,
                                    float* __restrict__ out_target, float* __restrict__ out_utype)
{
    int n = blockIdx.x * 256 + threadIdx.x;
    if (n >= NSESS) return;
    int b = n & 255, s = n >> 8;
    const int* row = ids + (size_t)(b * 4 + s) * 50;
    int len = 0;
#pragma unroll
    for (int l = 0; l < 50; ++l) len += (row[l] != 0) ? 1 : 0;
    lens[n] = len;
    rowmap[n] = n * LP + (len - 2);
    out_target[n] = (float)row[len - 1];
    out_utype[n] = u_type[b];
}

// ---------------- c_hist gather from bf16 hab ----------------
__global__ void chist_kernel(const uint32* __restrict__ hab, const int* __restrict__ uid,
                             float* __restrict__ chist) {
    int n = blockIdx.x, d = threadIdx.x;
    uint32 u = hab[(size_t)(N_ITEMS_C + uid[n & 255]) * 64 + (d >> 1)];
    chist[(size_t)n * 128 + d] = (d & 1) ? bfhi(u) : bflo(u);
}

// ---------------- token embedding gather -> bf16 h (4 tokens/block) ----------------
__global__ __launch_bounds__(256) void h0_gather_kernel(
    const float* __restrict__ id_emb, const int* __restrict__ ids,
    const int* __restrict__ lens, uint32* __restrict__ hb) {
    int g = blockIdx.x * 4 + (threadIdx.x >> 6);
    int d = threadIdx.x & 63;          // pair index
    int n = g / LP;
    int tt = g - n * LP;
    int len = lens[n];
    int b = n & 255, s = n >> 8;
    int id = (tt < len - 1) ? ids[(size_t)(b * 4 + s) * 50 + tt] : 0;
    float2 e = *(const float2*)&id_emb[(size_t)id * 128 + d * 2];
    hb[(size_t)g * 64 + d] = packbf(e.x, e.y);
}

// ------- pack session weights f32 -> bf16, plus f32 transpose of fuse_w -------
// ids [0,106496): bf16 pair packs; [106496,139264): ftwf[k][n] = fuse_w[n][k] (f32, exact)
__global__ __launch_bounds__(256) void epack_kernel(
    const float* __restrict__ w_ih, const float* __restrict__ w_hh,
    const float* __restrict__ ei_w, const float* __restrict__ eo_w,
    const float* __restrict__ q2_w, const float* __restrict__ q1_w,
    const float* __restrict__ fuse_w, uint32* __restrict__ dst)
{
    int id = blockIdx.x * 256 + threadIdx.x;   // 139,264 total
    if (id >= 106496) {
        if (id >= 139264) return;
        int f = id - 106496;
        int kk = f >> 7, n = f & 127;
        ((float*)dst)[id] = fuse_w[(size_t)n * 256 + kk];
        return;
    }
    const float* src; int off;
    if      (id <  49152) { src = w_ih; off = id; }
    else if (id <  73728) { src = w_hh; off = id - 49152; }
    else if (id <  81920) { src = ei_w; off = id - 73728; }
    else if (id <  90112) { src = eo_w; off = id - 81920; }
    else if (id <  98304) { src = q2_w; off = id - 90112; }
    else                  { src = q1_w; off = id - 98304; }
    float2 w = *(const float2*)&src[(size_t)off * 2];
    dst[id] = packbf(w.x, w.y);
}

// ======== FUSED Ei/Eo + GRU (32 rows/block, grid 1568) ========
// Phase 1: Ei over src tiles {g0-16,g0,g0+16}, Eo over {g0,g0+16,g0+32} (wrap; 1.5x
//          redundant halo tiles, trivially cheap). Phase 2: shift/mask/bias epilogue
//          into LDS Agi[32][264] (m_i | m_o, bf16). Phase 3: gi GEMM from LDS +
//          gh GEMM from global h; GRU cell; write h' to hb2 (NOT in-place -- blocks
//          read neighbor h rows in phase 1, so in-place would race).
__global__ __launch_bounds__(256) void gru_fused_kernel(
    const uint32* __restrict__ hb,          // [NTOK][64] u32 (bf16 h in)
    unsigned short* __restrict__ hb2,       // [NTOK][128] bf16 h out
    const bf16* __restrict__ Wi, const bf16* __restrict__ Wo,   // [128][128] bf16
    const bf16* __restrict__ wihb,   // [384][256] bf16
    const bf16* __restrict__ whhb,   // [384][128] bf16
    const float* __restrict__ ei_b, const float* __restrict__ eo_b,
    const float* __restrict__ b_iah, const float* __restrict__ b_oah,
    const float* __restrict__ b_ih, const float* __restrict__ b_hh,
    const int* __restrict__ lens)
{
    __shared__ __align__(16) bf16 Agi[32][264];   // 528B pitch (16B-aligned rows)
    const int tid = threadIdx.x;
    const int wv = tid >> 6;
    const int lane = tid & 63;
    const int quad = lane >> 4;
    const int lr = lane & 15;
    const int c0 = wv * 32;
    const int g0 = blockIdx.x * 32;
    const bf16* hbb = (const bf16*)hb;

    // ---- phase 1: halo Ei/Eo GEMMs over 4 src tiles [g0-16, g0+48) ----
    int arows[4];
#pragma unroll
    for (int t = 0; t < 4; ++t) {
        int r = g0 + (t - 1) * 16 + lr;
        arows[t] = (r < 0) ? r + NTOK : (r >= NTOK ? r - NTOK : r);
    }
    f32x4 aEi[3][2], aEo[3][2];
#pragma unroll
    for (int t = 0; t < 3; ++t) {
        aEi[t][0] = (f32x4){0,0,0,0}; aEi[t][1] = (f32x4){0,0,0,0};
        aEo[t][0] = (f32x4){0,0,0,0}; aEo[t][1] = (f32x4){0,0,0,0};
    }
#pragma unroll
    for (int ks = 0; ks < 4; ++ks) {
        short8 bi0 = *(const short8*)&Wi[(size_t)(wv * 32 + lr) * 128 + ks * 32 + quad * 8];
        short8 bi1 = *(const short8*)&Wi[(size_t)(wv * 32 + 16 + lr) * 128 + ks * 32 + quad * 8];
        short8 bo0 = *(const short8*)&Wo[(size_t)(wv * 32 + lr) * 128 + ks * 32 + quad * 8];
        short8 bo1 = *(const short8*)&Wo[(size_t)(wv * 32 + 16 + lr) * 128 + ks * 32 + quad * 8];
        short8 a[4];
#pragma unroll
        for (int t = 0; t < 4; ++t)
            a[t] = *(const short8*)&hbb[(size_t)arows[t] * 128 + ks * 32 + quad * 8];
#pragma unroll
        for (int t = 0; t < 3; ++t) {
            aEi[t][0] = __builtin_amdgcn_mfma_f32_16x16x32_bf16(a[t], bi0, aEi[t][0], 0, 0, 0);
            aEi[t][1] = __builtin_amdgcn_mfma_f32_16x16x32_bf16(a[t], bi1, aEi[t][1], 0, 0, 0);
            aEo[t][0] = __builtin_amdgcn_mfma_f32_16x16x32_bf16(a[t + 1], bo0, aEo[t][0], 0, 0, 0);
            aEo[t][1] = __builtin_amdgcn_mfma_f32_16x16x32_bf16(a[t + 1], bo1, aEo[t][1], 0, 0, 0);
        }
    }
    // ---- phase 2: shifted/masked epilogue into LDS (every dest row covered once) ----
#pragma unroll
    for (int s = 0; s < 2; ++s) {
        int col = c0 + s * 16 + lr;
        float bei = ei_b[col], beo = eo_b[col];
        float bia = b_iah[col], boa = b_oah[col];
#pragma unroll
        for (int t = 0; t < 3; ++t)
#pragma unroll
            for (int reg = 0; reg < 4; ++reg) {
                // Ei: src tile base g0+(t-1)*16 -> dest src+1
                int src = g0 + (t - 1) * 16 + quad * 4 + reg;
                int ssrc = (src < 0) ? src + NTOK : (src >= NTOK ? src - NTOK : src);
                int d1 = ssrc + 1; if (d1 == NTOK) d1 = 0;
                int ld = d1 - g0;
                if ((unsigned)ld < 32u) {
                    int n1 = d1 / LP, t1 = d1 - n1 * LP, l1 = lens[n1];
                    float v = bia + ((t1 >= 1 && t1 < l1 - 1) ? aEi[t][s][reg] + bei : 0.f);
                    Agi[ld][col] = __float2bfloat16(v);
                }
                // Eo: src tile base g0+t*16 -> dest src-1
                int src2 = g0 + t * 16 + quad * 4 + reg;
                int ssrc2 = (src2 >= NTOK) ? src2 - NTOK : src2;
                int d2 = (ssrc2 == 0) ? NTOK - 1 : ssrc2 - 1;
                int ld2 = d2 - g0;
                if ((unsigned)ld2 < 32u) {
                    int n2 = d2 / LP, t2 = d2 - n2 * LP, l2 = lens[n2];
                    float v = boa + ((t2 < l2 - 2) ? aEo[t][s][reg] + beo : 0.f);
                    Agi[ld2][128 + col] = __float2bfloat16(v);
                }
            }
    }
    __syncthreads();

    // ---- phase 3: GRU GEMMs. gi from LDS Agi, gh from global h ----
    int arow[2];
#pragma unroll
    for (int mt = 0; mt < 2; ++mt) arow[mt] = g0 + mt * 16 + lr;
    // acc[mt][s][j]: j = 0 -> r (gi+gh fused), 1 -> z (gi+gh fused), 2 -> gi_n, 3 -> gh_n
    f32x4 acc[2][2][4];
#pragma unroll
    for (int mt = 0; mt < 2; ++mt)
#pragma unroll
        for (int s = 0; s < 2; ++s)
#pragma unroll
            for (int j = 0; j < 4; ++j) acc[mt][s][j] = (f32x4){0.f, 0.f, 0.f, 0.f};

#pragma unroll 2
    for (int ks = 0; ks < 8; ++ks) {
        short8 bfr[2][3];
#pragma unroll
        for (int s = 0; s < 2; ++s)
#pragma unroll
            for (int gte = 0; gte < 3; ++gte) {
                int n0 = gte * 128 + c0 + s * 16 + lr;
                bfr[s][gte] = *(const short8*)&wihb[(size_t)n0 * 256 + ks * 32 + quad * 8];
            }
#pragma unroll
        for (int mt = 0; mt < 2; ++mt) {
            short8 a = *(const short8*)&Agi[mt * 16 + lr][ks * 32 + quad * 8];
#pragma unroll
            for (int s = 0; s < 2; ++s) {
                acc[mt][s][0] = __builtin_amdgcn_mfma_f32_16x16x32_bf16(a, bfr[s][0], acc[mt][s][0], 0, 0, 0);
                acc[mt][s][1] = __builtin_amdgcn_mfma_f32_16x16x32_bf16(a, bfr[s][1], acc[mt][s][1], 0, 0, 0);
                acc[mt][s][2] = __builtin_amdgcn_mfma_f32_16x16x32_bf16(a, bfr[s][2], acc[mt][s][2], 0, 0, 0);
            }
        }
    }
#pragma unroll 2
    for (int ks = 0; ks < 4; ++ks) {
        short8 bfr[2][3];
#pragma unroll
        for (int s = 0; s < 2; ++s)
#pragma unroll
            for (int gte = 0; gte < 3; ++gte) {
                int n0 = gte * 128 + c0 + s * 16 + lr;
                bfr[s][gte] = *(const short8*)&whhb[(size_t)n0 * 128 + ks * 32 + quad * 8];
            }
#pragma unroll
        for (int mt = 0; mt < 2; ++mt) {
            short8 a = *(const short8*)&hbb[(size_t)arow[mt] * 128 + ks * 32 + quad * 8];
#pragma unroll
            for (int s = 0; s < 2; ++s) {
                acc[mt][s][0] = __builtin_amdgcn_mfma_f32_16x16x32_bf16(a, bfr[s][0], acc[mt][s][0], 0, 0, 0);
                acc[mt][s][1] = __builtin_amdgcn_mfma_f32_16x16x32_bf16(a, bfr[s][1], acc[mt][s][1], 0, 0, 0);
                acc[mt][s][3] = __builtin_amdgcn_mfma_f32_16x16x32_bf16(a, bfr[s][2], acc[mt][s][3], 0, 0, 0);
            }
        }
    }

    // GRU cell epilogue -> hb2 (no in-place hazard, no barrier needed)
    const unsigned short* hold = (const unsigned short*)hb;
#pragma unroll
    for (int s = 0; s < 2; ++s) {
        int col = c0 + s * 16 + lr;
        float brz = b_ih[col] + b_hh[col];
        float bzz = b_ih[col + 128] + b_hh[col + 128];
        float bin = b_ih[col + 256];
        float bhn = b_hh[col + 256];
#pragma unroll
        for (int mt = 0; mt < 2; ++mt)
#pragma unroll
            for (int reg = 0; reg < 4; ++reg) {
                int row = g0 + mt * 16 + quad * 4 + reg;
                float rg = 1.f / (1.f + expf(-(acc[mt][s][0][reg] + brz)));
                float zg = 1.f / (1.f + expf(-(acc[mt][s][1][reg] + bzz)));
                float ng = tanhf(acc[mt][s][2][reg] + bin + rg * (acc[mt][s][3][reg] + bhn));
                size_t idx = (size_t)row * 128 + col;
                float ho = __uint_as_float((uint32)hold[idx] << 16);
                hb2[idx] = __bfloat16_as_ushort(__float2bfloat16(ng + zg * (ho - ng)));
            }
    }
}

// ---------------- alpha: al[tok] = att_w . sigmoid(q1[n] + q2[tok]), masked ----------------
// wave per token: coalesced q2 row reads + shfl_xor reduce.
__global__ __launch_bounds__(256) void alpha_kernel(
    const float* __restrict__ q1h, const float* __restrict__ q2h,
    const float* __restrict__ att_w, const int* __restrict__ lens,
    float* __restrict__ al)
{
    int tok = blockIdx.x * 4 + (threadIdx.x >> 6);
    int lane = threadIdx.x & 63;
    int n = tok / LP, t = tok - n * LP;
    int len = lens[n];
    float2 q2 = *(const float2*)&q2h[(size_t)tok * 128 + lane * 2];
    float2 q1 = *(const float2*)&q1h[(size_t)n * 128 + lane * 2];
    float2 aw = *(const float2*)&att_w[lane * 2];
    float s = aw.x / (1.f + expf(-(q1.x + q2.x))) + aw.y / (1.f + expf(-(q1.y + q2.y)));
#pragma unroll
    for (int off = 1; off < 64; off <<= 1) s += __shfl_xor(s, off, 64);
    if (lane == 0) al[tok] = (t < len - 1) ? s : 0.f;
}

// ---------------- attention readout + fuse layer -> reps (f32 out) ----------------
// alpha precomputed (alG); fuse weights k-major f32 (ftwf) -> all loads coalesced.
__global__ __launch_bounds__(128) void attn_fuse_kernel(
    const float* __restrict__ alG, const unsigned short* __restrict__ hu,
    const float* __restrict__ chist, const int* __restrict__ lens,
    const float* __restrict__ ftwf, const float* __restrict__ fuse_b,
    float* __restrict__ out)
{
    __shared__ float al[64], cv[256];
    const int n = blockIdx.x, tid = threadIdx.x;
    if (tid < 64) al[tid] = (tid < LP) ? alG[(size_t)n * LP + tid] : 0.f;
    __syncthreads();
    const int len = lens[n];
    float ssum = 0.f;
    for (int t = 0; t < len - 1; ++t) ssum += al[t];
    float inv = 1.f / (ssum + 1e-8f);
    float c = 0.f;
    for (int t = 0; t < len - 1; ++t) {
        float hv = __uint_as_float((uint32)hu[(size_t)(n * LP + t) * 128 + tid] << 16);
        c += al[t] * inv * hv;
    }
    cv[tid] = c;
    cv[128 + tid] = chist[(size_t)n * 128 + tid];
    __syncthreads();
    float s = fuse_b[tid];
    for (int kk = 0; kk < 256; ++kk)
        s += cv[kk] * ftwf[(size_t)kk * 128 + tid];
    out[(size_t)n * 128 + tid] = s;
}

// ============================================================================
extern "C" void kernel_launch(void* const* d_in, const int* in_sizes, int n_in,
                              void* d_out, int out_size, void* d_ws, size_t ws_size,
                              hipStream_t stream)
{
    const float* id_emb   = (const float*)d_in[0];
    const float* user_emb = (const float*)d_in[1];
    const float* lin_r_w  = (const float*)d_in[2];
    const float* upi_w    = (const float*)d_in[3];
    const float* upi_b    = (const float*)d_in[4];
    const float* upu_w    = (const float*)d_in[5];
    const float* upu_b    = (const float*)d_in[6];
    const float* w_ih     = (const float*)d_in[7];
    const float* w_hh     = (const float*)d_in[8];
    const float* b_ih     = (const float*)d_in[9];
    const float* b_hh     = (const float*)d_in[10];
    const float* b_iah    = (const float*)d_in[11];
    const float* b_oah    = (const float*)d_in[12];
    const float* ei_w     = (const float*)d_in[13];
    const float* ei_b     = (const float*)d_in[14];
    const float* eo_w     = (const float*)d_in[15];
    const float* eo_b     = (const float*)d_in[16];
    const float* q1_w     = (const float*)d_in[17];
    const float* q2_w     = (const float*)d_in[18];
    const float* att_w    = (const float*)d_in[19];
    const float* fuse_w   = (const float*)d_in[20];
    const float* fuse_b   = (const float*)d_in[21];
    const int*  rel_rows  = (const int*)d_in[22];
    const int*  rel_cols  = (const int*)d_in[23];
    const float* rel_vals = (const float*)d_in[24];
    const int*  ids       = (const int*)d_in[25];
    const int*  uid       = (const int*)d_in[26];
    const float* u_type   = (const float*)d_in[27];
    float* out = (float*)d_out;   // reps[131072] | target[1024] | u_type[1024]

    // ---- workspace layout (u32 units) ----
    uint32* W32    = (uint32*)d_ws;
    uint32* hab    = W32;                                 //  4,480,000 (bf16 nodes)
    uint32* T      = W32 + 4480000;                       // 13,440,000 (bf16, stride 192)
    uint32* edges  = W32 + 17920000;                      //  2,400,000 (4B records)
    int2*   tmp    = (int2*)(W32 + 20320000);             //  2,400,000 int2
    int*    offs   = (int*)(W32 + 25120000);              //  3 x 70001 (pad 210,004)
    int*    bhist  = (int*)(W32 + 25330004);              //  3 x 137
    int*    cursor = (int*)(W32 + 25330415);              //  3 x 137
    int*    bbase  = (int*)(W32 + 25330826);              //  3 x 138
    uint32* Wcat   = W32 + 25331240;                      //  2 x 32768
    float*  q1h    = (float*)(W32 + 25396776);            //  131,072
    float*  chist  = (float*)(W32 + 25527848);            //  131,072
    int*    lens   = (int*)(W32 + 25658920);              //  1024
    int*    rowmap = (int*)(W32 + 25659944);              //  1024
    float*  alG    = (float*)(W32 + 25660968);            //  50,176 (end 25,711,144)
    // session overlays (live only after HGNN):
    uint32* sess_hb = W32;                                // 3,211,264 u32 (bf16 h, over hab)
    float* q2h      = (float*)(W32 + 4480000);            // 6,422,528 f (in T region)
    unsigned short* hb2 = (unsigned short*)(W32 + 10902528); // [NTOK][128] bf16 h' (in T region)
    uint32* wpk     = W32 + 17920000;                     // packed session wts (over edges)
    uint32* wihb = wpk;              // 49,152
    uint32* whhb = wpk + 49152;      // 24,576
    uint32* eiwb = wpk + 73728;      //  8,192
    uint32* eowb = wpk + 81920;      //  8,192
    uint32* q2wb = wpk + 90112;      //  8,192
    uint32* q1wb = wpk + 98304;      //  8,192
    float*  ftwf = (float*)(wpk + 106496); // 32,768 f32 (fuse_w transposed, k-major)
    if (ws_size < (size_t)27144192 * 4 + 4096) return;

    // ---- init + bucket-sort CSR build (coalesced writes, no 70001-scan) ----
    init_hab_kernel<<<8750, 256, 0, stream>>>((const float4*)id_emb, (const float4*)user_emb, hab);
    hipMemsetAsync(bhist, 0, (size_t)822 * 4, stream);    // bhist + cursor
    bucket_hist_kernel<<<dim3(196, 3), 256, 0, stream>>>(rel_rows, bhist);
    bucket_scan_kernel<<<1, 256, 0, stream>>>(bhist, bbase);
    bucket_scatter_kernel<<<dim3(196, 3), 256, 0, stream>>>(rel_rows, rel_cols, rel_vals,
                                                            bbase, cursor, tmp);
    bucket_refine_kernel<<<dim3(NBK, 3), 256, 0, stream>>>(tmp, bbase, offs, edges);

    // ---- HGNN: 2 layers, MFMA update, no atomics ----
    for (int k = 0; k < 2; ++k) {
        wprep_kernel<<<dim3(2, 6), 256, 0, stream>>>(upi_w, upu_w, lin_r_w, k, Wcat);
        upack_kernel<<<64, 256, 0, stream>>>(upi_w, upu_w, k, Wcat);
        gather_kernel<<<17500, 256, 0, stream>>>(hab, edges, offs, T);
        hgnn_update_mfma_kernel<<<548, 256, 0, stream>>>((const bf16*)T, hab,
            (const bf16*)Wcat, upi_b, upu_b, k);
    }

    // ---- session branch ----
    session_prep_kernel<<<4, 256, 0, stream>>>(ids, uid, u_type, lens, rowmap,
        out + 131072, out + 132096);
    chist_kernel<<<NSESS, 128, 0, stream>>>(hab, uid, chist);   // before sess_hb overwrites hab
    epack_kernel<<<544, 256, 0, stream>>>(w_ih, w_hh, ei_w, eo_w, q2_w, q1_w, fuse_w, wpk);
    h0_gather_kernel<<<NTOK / 4, 256, 0, stream>>>(id_emb, ids, lens, sess_hb);
    gru_fused_kernel<<<1568, 256, 0, stream>>>(sess_hb, hb2,
        (const bf16*)eiwb, (const bf16*)eowb,
        (const bf16*)wihb, (const bf16*)whhb,
        ei_b, eo_b, b_iah, b_oah, b_ih, b_hh, lens);
    mfma_nt_kernel<<<392, 256, 0, stream>>>((const bf16*)hb2, nullptr,
        (const bf16*)q2wb, nullptr, q2h, NTOK);
    mfma_nt_kernel<<<8, 256, 0, stream>>>((const bf16*)hb2, rowmap,
        (const bf16*)q1wb, nullptr, q1h, NSESS);
    alpha_kernel<<<NTOK / 4, 256, 0, stream>>>(q1h, q2h, att_w, lens, alG);
    attn_fuse_kernel<<<NSESS, 128, 0, stream>>>(alG, (const unsigned short*)hb2,
        chist, lens, ftwf, fuse_b, out);
}

// Round 13
// 710.146 us; speedup vs baseline: 1.0839x; 1.0535x over previous
//
#include <hip/hip_runtime.h>
#include <hip/hip_bf16.h>

typedef __hip_bfloat16 bf16;
typedef unsigned int uint32;
typedef __attribute__((ext_vector_type(8))) short short8;   // 8 bf16 (4 VGPRs)
typedef __attribute__((ext_vector_type(4))) float f32x4;
typedef __attribute__((ext_vector_type(2))) float f32x2;
typedef __attribute__((ext_vector_type(4))) uint32 u32x4;   // clang vector: ok for nontemporal

#define N_ITEMS_C 50000
#define N_USERS_C 20000
#define N_NODES_C 70000
#define NNZ_C 800000
#define NSESS 1024
#define LP 49
#define NTOK (NSESS * LP)   // 50176
#define NBK 137             // coarse buckets: row >> 9

__device__ __forceinline__ float bflo(uint32 u) { return __uint_as_float(u << 16); }
__device__ __forceinline__ float bfhi(uint32 u) { return __uint_as_float(u & 0xffff0000u); }
// hi bf16 with low-16 garbage bits: relative error <= 2^-17, far below bf16 rounding.
__device__ __forceinline__ float bfhi_fast(uint32 u) { return __uint_as_float(u); }
__device__ __forceinline__ uint32 packbf(float a, float b) {
    return (uint32)__bfloat16_as_ushort(__float2bfloat16(a)) |
           ((uint32)__bfloat16_as_ushort(__float2bfloat16(b)) << 16);
}

// ===== FUSED: init hab (blocks [0,8750)) + bucket hist (blocks [8750,9338)) =====
__global__ __launch_bounds__(256) void init_hist_kernel(
    const float4* __restrict__ idp, const float4* __restrict__ usp,
    uint32* __restrict__ hab, const int* __restrict__ rel_rows, int* __restrict__ bhist)
{
    __shared__ int hist[NBK];
    const int tid = threadIdx.x;
    if (blockIdx.x < 8750) {
        int i = blockIdx.x * 256 + tid;           // quad index, 2,240,000 total
        float4 w = (i < 1600000) ? idp[i] : usp[i - 1600000];
        uint2 o = make_uint2(packbf(w.x, w.y), packbf(w.z, w.w));
        *(uint2*)&hab[(size_t)i * 2] = o;
        return;
    }
    const int hb = blockIdx.x - 8750;             // 588 hist blocks: 196 x 3
    const int r = hb / 196, xb = hb - r * 196;
    if (tid < NBK) hist[tid] = 0;
    __syncthreads();
    const int* rr = rel_rows + (size_t)r * NNZ_C;
#pragma unroll
    for (int i = 0; i < 16; ++i) {
        int e = xb * 4096 + i * 256 + tid;
        if (e < NNZ_C) atomicAdd(&hist[rr[e] >> 9], 1);
    }
    __syncthreads();
    if (tid < NBK && hist[tid]) atomicAdd(&bhist[r * NBK + tid], hist[tid]);
}

// A2: scan bucket totals -> bbase[r][0..NBK]
__global__ __launch_bounds__(256) void bucket_scan_kernel(
    const int* __restrict__ bhist, int* __restrict__ bbase)
{
    __shared__ int s[256];
    const int tid = threadIdx.x;
    for (int r = 0; r < 3; ++r) {
        s[tid] = (tid < NBK) ? bhist[r * NBK + tid] : 0;
        __syncthreads();
        for (int d = 1; d < 256; d <<= 1) {
            int t = (tid >= d) ? s[tid - d] : 0;
            __syncthreads();
            s[tid] += t;
            __syncthreads();
        }
        if (tid < NBK) bbase[r * (NBK + 1) + tid + 1] = s[tid];
        if (tid == 0) bbase[r * (NBK + 1)] = 0;
        __syncthreads();
    }
}

// A3: scatter edges into bucket-contiguous tmp (int2: packed(col|v15), row)
__global__ __launch_bounds__(256) void bucket_scatter_kernel(
    const int* __restrict__ rel_rows, const int* __restrict__ rel_cols,
    const float* __restrict__ rel_vals, const int* __restrict__ bbase,
    int* __restrict__ cursor, int2* __restrict__ tmp)
{
    __shared__ int hist[NBK], gbase[NBK], cur2[NBK];
    const int r = blockIdx.y, tid = threadIdx.x;
    if (tid < NBK) { hist[tid] = 0; cur2[tid] = 0; }
    __syncthreads();
    const int* rr = rel_rows + (size_t)r * NNZ_C;
    const int* rc = rel_cols + (size_t)r * NNZ_C;
    const float* rv = rel_vals + (size_t)r * NNZ_C;
    int rows[16];
#pragma unroll
    for (int i = 0; i < 16; ++i) {
        int e = blockIdx.x * 4096 + i * 256 + tid;
        rows[i] = (e < NNZ_C) ? rr[e] : -1;
        if (rows[i] >= 0) atomicAdd(&hist[rows[i] >> 9], 1);
    }
    __syncthreads();
    if (tid < NBK)
        gbase[tid] = bbase[r * (NBK + 1) + tid] +
                     (hist[tid] ? atomicAdd(&cursor[r * NBK + tid], hist[tid]) : 0);
    __syncthreads();
    int2* tp = tmp + (size_t)r * NNZ_C;
#pragma unroll
    for (int i = 0; i < 16; ++i) {
        int e = blockIdx.x * 4096 + i * 256 + tid;
        if (rows[i] >= 0) {
            int bk = rows[i] >> 9;
            int rank = atomicAdd(&cur2[bk], 1);
            uint32 fb = __float_as_uint(rv[e]);
            uint32 pk = (uint32)rc[e] | (((fb >> 16) & 0x7FFFu) << 17);
            tp[gbase[bk] + rank] = make_int2((int)pk, rows[i]);
        }
    }
}

// B: refine one bucket: per-row offsets + row-sorted 4B records, all writes coalesced
__global__ __launch_bounds__(256) void bucket_refine_kernel(
    const int2* __restrict__ tmp, const int* __restrict__ bbase,
    int* __restrict__ offs, uint32* __restrict__ edges)
{
    __shared__ int cnt[512], offsL[512], cur[512];
    __shared__ uint32 outb[6656];
    const int b = blockIdx.x, r = blockIdx.y, tid = threadIdx.x;
    const int lane = tid & 63, wid = tid >> 6;
    const int row0 = b << 9;
    const int e0 = bbase[r * (NBK + 1) + b];
    const int e1 = bbase[r * (NBK + 1) + b + 1];
    cnt[tid] = 0; cnt[256 + tid] = 0; cur[tid] = 0; cur[256 + tid] = 0;
    __syncthreads();
    const int2* tp = tmp + (size_t)r * NNZ_C;
    for (int e = e0 + tid; e < e1; e += 256)
        atomicAdd(&cnt[tp[e].y - row0], 1);
    __syncthreads();
    if (wid == 0) {   // wave 0: exclusive scan of 512 counters
        int carry = 0;
        for (int c = 0; c < 8; ++c) {
            int x = cnt[c * 64 + lane];
            int inc = x;
#pragma unroll
            for (int d = 1; d < 64; d <<= 1) {
                int y = __shfl_up(inc, d, 64);
                if (lane >= d) inc += y;
            }
            offsL[c * 64 + lane] = inc - x + carry;
            carry += __shfl(inc, 63, 64);
        }
    }
    __syncthreads();
    // per-row global offsets (covers offs[70000] terminator via bucket 136)
    for (int i = tid; i < 512; i += 256) {
        int row = row0 + i;
        if (row < 70001) offs[(size_t)r * 70001 + row] = e0 + offsL[i];
    }
    for (int e = e0 + tid; e < e1; e += 256) {
        int2 E = tp[e];
        int lr_ = E.y - row0;
        int slot = offsL[lr_] + atomicAdd(&cur[lr_], 1);
        if (slot < 6656) outb[slot] = (uint32)E.x;
    }
    __syncthreads();
    uint32* eo = edges + (size_t)r * NNZ_C + e0;
    for (int i = tid; i < e1 - e0; i += 256) eo[i] = outb[i];
}

// ---------------- gather: T[row][r] = sum_e val * hab[col], all 3 relations fused --------
__global__ __launch_bounds__(256) void gather_kernel(
    const uint32* __restrict__ hab, const uint32* __restrict__ edges,
    const int* __restrict__ offs, uint32* __restrict__ T)
{
    const int row = blockIdx.x * 4 + (threadIdx.x >> 6);
    const int lane = threadIdx.x & 63;
    const int grp = lane >> 4;       // which edge-slot group of the quad
    const int ql  = lane & 15;       // 4 u32 (8 dims) per lane
    const char* __restrict__ habB = (const char*)hab + ql * 16;
    f32x2 acc[3][4];
#pragma unroll
    for (int r = 0; r < 3; ++r)
#pragma unroll
        for (int j = 0; j < 4; ++j) acc[r][j] = (f32x2){0.f, 0.f};
#pragma unroll
    for (int r = 0; r < 3; ++r) {
        const uint32* __restrict__ ed = edges + (size_t)r * NNZ_C;
        const int* __restrict__ of = offs + (size_t)r * 70001;
        const int e0 = of[row], e1 = of[row + 1];
        if (e0 >= e1) continue;
        const uint32 span = (uint32)(e1 - e0);
        const int s0 = e0 & ~3;                      // 16B-aligned edge-record base
        for (int eb = s0; eb < e1; eb += 16) {
            const int base = eb + grp * 4;
            uint4 E4 = *(const uint4*)&ed[base];
            uint32 Ej0 = ((uint32)(base + 0 - e0) < span) ? E4.x : 0u;
            uint32 Ej1 = ((uint32)(base + 1 - e0) < span) ? E4.y : 0u;
            uint32 Ej2 = ((uint32)(base + 2 - e0) < span) ? E4.z : 0u;
            uint32 Ej3 = ((uint32)(base + 3 - e0) < span) ? E4.w : 0u;
            uint4 u0 = *(const uint4*)(habB + ((Ej0 & 0x1FFFFu) << 8));
            uint4 u1 = *(const uint4*)(habB + ((Ej1 & 0x1FFFFu) << 8));
            uint4 u2 = *(const uint4*)(habB + ((Ej2 & 0x1FFFFu) << 8));
            uint4 u3 = *(const uint4*)(habB + ((Ej3 & 0x1FFFFu) << 8));
            float v0 = __uint_as_float((Ej0 >> 1) & 0x7FFF0000u);
            float v1 = __uint_as_float((Ej1 >> 1) & 0x7FFF0000u);
            float v2 = __uint_as_float((Ej2 >> 1) & 0x7FFF0000u);
            float v3 = __uint_as_float((Ej3 >> 1) & 0x7FFF0000u);
            f32x2 vv;
            vv = (f32x2){v0, v0};
            acc[r][0] += vv * (f32x2){bflo(u0.x), bfhi_fast(u0.x)};
            acc[r][1] += vv * (f32x2){bflo(u0.y), bfhi_fast(u0.y)};
            acc[r][2] += vv * (f32x2){bflo(u0.z), bfhi_fast(u0.z)};
            acc[r][3] += vv * (f32x2){bflo(u0.w), bfhi_fast(u0.w)};
            vv = (f32x2){v1, v1};
            acc[r][0] += vv * (f32x2){bflo(u1.x), bfhi_fast(u1.x)};
            acc[r][1] += vv * (f32x2){bflo(u1.y), bfhi_fast(u1.y)};
            acc[r][2] += vv * (f32x2){bflo(u1.z), bfhi_fast(u1.z)};
            acc[r][3] += vv * (f32x2){bflo(u1.w), bfhi_fast(u1.w)};
            vv = (f32x2){v2, v2};
            acc[r][0] += vv * (f32x2){bflo(u2.x), bfhi_fast(u2.x)};
            acc[r][1] += vv * (f32x2){bflo(u2.y), bfhi_fast(u2.y)};
            acc[r][2] += vv * (f32x2){bflo(u2.z), bfhi_fast(u2.z)};
            acc[r][3] += vv * (f32x2){bflo(u2.w), bfhi_fast(u2.w)};
            vv = (f32x2){v3, v3};
            acc[r][0] += vv * (f32x2){bflo(u3.x), bfhi_fast(u3.x)};
            acc[r][1] += vv * (f32x2){bflo(u3.y), bfhi_fast(u3.y)};
            acc[r][2] += vv * (f32x2){bflo(u3.z), bfhi_fast(u3.z)};
            acc[r][3] += vv * (f32x2){bflo(u3.w), bfhi_fast(u3.w)};
        }
    }
    float* af = (float*)acc;
#pragma unroll
    for (int off = 16; off < 64; off <<= 1)
#pragma unroll
        for (int j = 0; j < 24; ++j) af[j] += __shfl_xor(af[j], off, 64);
    if (grp == 0) {
#pragma unroll
        for (int r = 0; r < 3; ++r) {
            u32x4 o;
            o.x = packbf(acc[r][0].x, acc[r][0].y);
            o.y = packbf(acc[r][1].x, acc[r][1].y);
            o.z = packbf(acc[r][2].x, acc[r][2].y);
            o.w = packbf(acc[r][3].x, acc[r][3].y);
            __builtin_nontemporal_store(o, (u32x4*)&T[(size_t)row * 192 + r * 64 + ql * 4]);
        }
    }
}

// ------- weight prep (both k in one launch, z = k): Wcat[k][seg][n][r*128+c] -------
__global__ __launch_bounds__(256, 3) void wprep_kernel(
    const float* __restrict__ upi_w, const float* __restrict__ upu_w,
    const float* __restrict__ lin_r_w, uint32* __restrict__ Wcat)
{
    __shared__ float As[128][65];
    __shared__ __align__(8) bf16 Ws[128][66];
    const int which = blockIdx.y, seg = which / 3, r = which % 3;
    const int k = blockIdx.z;
    const float* U  = (seg == 0 ? upi_w : upu_w) + (size_t)k * 16384;
    const float* Wr = lin_r_w + (size_t)(k * 3 + r) * 16384;
    uint32* out = Wcat + (size_t)(k * 2 + seg) * 32768;   // u32 row stride 256
    const int tid = threadIdx.x;
    const int row0 = blockIdx.x * 64;
#pragma unroll
    for (int i = 0; i < 8; ++i) {
        int id = i * 256 + tid;
        int rr = id >> 5, c4 = (id & 31) << 2;
        float4 v = *(const float4*)&U[(size_t)(row0 + rr) * 128 + c4];
        As[c4][rr] = v.x; As[c4+1][rr] = v.y; As[c4+2][rr] = v.z; As[c4+3][rr] = v.w;
    }
    const int m0 = (tid & 15) * 4;
    const int n0 = (tid >> 4) * 8;
    float acc[4][8];
#pragma unroll
    for (int i = 0; i < 4; ++i)
#pragma unroll
        for (int j = 0; j < 8; ++j) acc[i][j] = 0.f;
    for (int p = 0; p < 2; ++p) {
        if (p) __syncthreads();
        for (int i = 0; i < 32; ++i) {       // Ws[c][kf] = Wr[p*64+kf][c] (transposed)
            int id = i * 256 + tid;
            int c = id >> 6, kf = id & 63;
            Ws[c][kf] = __float2bfloat16(Wr[(size_t)(p * 64 + kf) * 128 + c]);
        }
        __syncthreads();
        for (int k2 = 0; k2 < 32; ++k2) {
            int kk = p * 64 + 2 * k2;
            float av0[4], av1[4];
#pragma unroll
            for (int i = 0; i < 4; ++i) { av0[i] = As[kk][m0 + i]; av1[i] = As[kk + 1][m0 + i]; }
#pragma unroll
            for (int j = 0; j < 8; ++j) {
                uint32 wp = *(const uint32*)&Ws[n0 + j][2 * k2];
                float w0 = bflo(wp), w1 = bfhi(wp);
#pragma unroll
                for (int i = 0; i < 4; ++i)
                    acc[i][j] = fmaf(av1[i], w1, fmaf(av0[i], w0, acc[i][j]));
            }
        }
    }
#pragma unroll
    for (int i = 0; i < 4; ++i) {
        int n = row0 + m0 + i;
#pragma unroll
        for (int j = 0; j < 8; j += 2)
            out[(size_t)n * 256 + (r * 128 + n0 + j) / 2] = packbf(acc[i][j], acc[i][j + 1]);
    }
}

// ---------------- U pack (both k): Wcat[k][seg][n][384+j] = bf16(U[n][j]) ----------------
__global__ __launch_bounds__(256) void upack_kernel(
    const float* __restrict__ upi_w, const float* __restrict__ upu_w,
    uint32* __restrict__ Wcat)
{
    int id = blockIdx.x * 256 + threadIdx.x;   // 32768 pairs (2k x 2seg x 8192)
    int k = id >> 14, rest = id & 16383;
    int seg = rest >> 13, p = rest & 8191;
    int n = p >> 6, j2 = (p & 63);
    const float* U = (seg ? upu_w : upi_w) + (size_t)k * 16384;
    float2 w = *(const float2*)&U[(size_t)n * 128 + j2 * 2];
    Wcat[(size_t)(k * 2 + seg) * 32768 + (size_t)n * 256 + 192 + j2] = packbf(w.x, w.y);
}

// ---------- HGNN update (MFMA, LDS-free, 128-row tiles, items+users in one grid) ----------
#define HGNN_ITEM_BLOCKS 391
__global__ __launch_bounds__(256) void hgnn_update_mfma_kernel(
    const bf16* __restrict__ T, uint32* __restrict__ hab,
    const bf16* __restrict__ Wcat, const float* __restrict__ upi_b,
    const float* __restrict__ upu_b, int k)
{
    const int tid = threadIdx.x;
    const int wv = tid >> 6, lane = tid & 63, quad = lane >> 4, lr = lane & 15;
    const int bid = blockIdx.x;
    const int seg = (bid >= HGNN_ITEM_BLOCKS) ? 1 : 0;
    const int row0 = seg ? N_ITEMS_C : 0;
    const int M = seg ? N_USERS_C : N_ITEMS_C;
    const int rbase = (seg ? bid - HGNN_ITEM_BLOCKS : bid) * 128;
    const bf16* __restrict__ Wc = Wcat + (size_t)(k * 2 + seg) * 65536;
    const float* __restrict__ bias = (seg ? upu_b : upi_b) + k * 128;
    const bf16* hb = (const bf16*)hab;
    f32x4 acc[8][2];
#pragma unroll
    for (int mt = 0; mt < 8; ++mt) { acc[mt][0] = (f32x4){0,0,0,0}; acc[mt][1] = (f32x4){0,0,0,0}; }
    int arow[8];
#pragma unroll
    for (int mt = 0; mt < 8; ++mt) {
        int rr = rbase + mt * 16 + lr;
        arow[mt] = row0 + (rr < M ? rr : M - 1);
    }
#pragma unroll
    for (int ks = 0; ks < 16; ++ks) {
        short8 b0 = *(const short8*)&Wc[(size_t)(wv * 32 + lr) * 512 + ks * 32 + quad * 8];
        short8 b1 = *(const short8*)&Wc[(size_t)(wv * 32 + 16 + lr) * 512 + ks * 32 + quad * 8];
#pragma unroll
        for (int mt = 0; mt < 8; ++mt) {
            short8 a;
            if (ks < 12) a = *(const short8*)&T[(size_t)arow[mt] * 384 + ks * 32 + quad * 8];
            else         a = *(const short8*)&hb[(size_t)arow[mt] * 128 + (ks - 12) * 32 + quad * 8];
            acc[mt][0] = __builtin_amdgcn_mfma_f32_16x16x32_bf16(a, b0, acc[mt][0], 0, 0, 0);
            acc[mt][1] = __builtin_amdgcn_mfma_f32_16x16x32_bf16(a, b1, acc[mt][1], 0, 0, 0);
        }
    }
    __syncthreads();   // drain loads: all hab reads done before in-place writes
    unsigned short* hw = (unsigned short*)hab;
#pragma unroll
    for (int s = 0; s < 2; ++s) {
        int col = wv * 32 + s * 16 + lr;
        float bv = bias[col];
#pragma unroll
        for (int mt = 0; mt < 8; ++mt)
#pragma unroll
            for (int reg = 0; reg < 4; ++reg) {
                int rr = rbase + mt * 16 + quad * 4 + reg;
                if (rr < M) {
                    float v = fmaxf(acc[mt][s][reg] + bv, 0.f);
                    hw[(size_t)(row0 + rr) * 128 + col] = __bfloat16_as_ushort(__float2bfloat16(v));
                }
            }
    }
}

// ------- generic MFMA NT gemm (LDS-free, 128-row tiles, single output) -------
__global__ __launch_bounds__(256) void mfma_nt_kernel(
    const bf16* __restrict__ A, const int* __restrict__ rowmap,
    const bf16* __restrict__ W0, const float* __restrict__ b0,
    float* __restrict__ O0, int M)
{
    const int tid = threadIdx.x;
    const int wv = tid >> 6, lane = tid & 63, quad = lane >> 4, lr = lane & 15;
    const int rbase = blockIdx.x * 128;
    int arow[8];
#pragma unroll
    for (int mt = 0; mt < 8; ++mt) {
        int rr = rbase + mt * 16 + lr;
        rr = rr < M ? rr : M - 1;
        arow[mt] = rowmap ? rowmap[rr] : rr;
    }
    f32x4 acc0[8][2];
#pragma unroll
    for (int mt = 0; mt < 8; ++mt) { acc0[mt][0] = (f32x4){0,0,0,0}; acc0[mt][1] = (f32x4){0,0,0,0}; }
#pragma unroll
    for (int ks = 0; ks < 4; ++ks) {
        short8 b00 = *(const short8*)&W0[(size_t)(wv * 32 + lr) * 128 + ks * 32 + quad * 8];
        short8 b01 = *(const short8*)&W0[(size_t)(wv * 32 + 16 + lr) * 128 + ks * 32 + quad * 8];
#pragma unroll
        for (int mt = 0; mt < 8; ++mt) {
            short8 a = *(const short8*)&A[(size_t)arow[mt] * 128 + ks * 32 + quad * 8];
            acc0[mt][0] = __builtin_amdgcn_mfma_f32_16x16x32_bf16(a, b00, acc0[mt][0], 0, 0, 0);
            acc0[mt][1] = __builtin_amdgcn_mfma_f32_16x16x32_bf16(a, b01, acc0[mt][1], 0, 0, 0);
        }
    }
#pragma unroll
    for (int s = 0; s < 2; ++s) {
        int col = wv * 32 + s * 16 + lr;
        float bv0 = b0 ? b0[col] : 0.f;
#pragma unroll
        for (int mt = 0; mt < 8; ++mt)
#pragma unroll
            for (int reg = 0; reg < 4; ++reg) {
                int rr = rbase + mt * 16 + quad * 4 + reg;
                if (rr < M) O0[(size_t)rr * 128 + col] = acc0[mt][s][reg] + bv0;
            }
    }
}

// ===== FUSED misc prep: session_prep [0,4) | chist [4,516) | epack [516,1060) |
//       h0 gather [1060,13604) (computes session length inline via ballot) =====
__global__ __launch_bounds__(256) void misc_prep_kernel(
    const int* __restrict__ ids, const int* __restrict__ uid,
    const float* __restrict__ u_type, const float* __restrict__ id_emb,
    const uint32* __restrict__ hab,
    const float* __restrict__ w_ih, const float* __restrict__ w_hh,
    const float* __restrict__ ei_w, const float* __restrict__ eo_w,
    const float* __restrict__ q2_w, const float* __restrict__ q1_w,
    const float* __restrict__ fuse_w,
    int* __restrict__ lens, int* __restrict__ rowmap,
    float* __restrict__ out_target, float* __restrict__ out_utype,
    float* __restrict__ chist, uint32* __restrict__ wdst,
    uint32* __restrict__ hb)
{
    const int bid = blockIdx.x, tid = threadIdx.x;
    if (bid < 4) {                       // ---- session prep ----
        int n = bid * 256 + tid;
        if (n >= NSESS) return;
        int b = n & 255, s = n >> 8;
        const int* row = ids + (size_t)(b * 4 + s) * 50;
        int len = 0;
#pragma unroll
        for (int l = 0; l < 50; ++l) len += (row[l] != 0) ? 1 : 0;
        lens[n] = len;
        rowmap[n] = n * LP + (len - 2);
        out_target[n] = (float)row[len - 1];
        out_utype[n] = u_type[b];
        return;
    }
    if (bid < 516) {                     // ---- chist (2 sessions/block) ----
        int n = (bid - 4) * 2 + (tid >> 7);
        int d = tid & 127;
        uint32 u = hab[(size_t)(N_ITEMS_C + uid[n & 255]) * 64 + (d >> 1)];
        chist[(size_t)n * 128 + d] = (d & 1) ? bfhi(u) : bflo(u);
        return;
    }
    if (bid < 1060) {                    // ---- epack + fuse_w transpose ----
        int id = (bid - 516) * 256 + tid;
        if (id >= 106496) {
            if (id >= 139264) return;
            int f = id - 106496;
            int kk = f >> 7, n = f & 127;
            ((float*)wdst)[id] = fuse_w[(size_t)n * 256 + kk];
            return;
        }
        const float* src; int off;
        if      (id <  49152) { src = w_ih; off = id; }
        else if (id <  73728) { src = w_hh; off = id - 49152; }
        else if (id <  81920) { src = ei_w; off = id - 73728; }
        else if (id <  90112) { src = eo_w; off = id - 81920; }
        else if (id <  98304) { src = q2_w; off = id - 90112; }
        else                  { src = q1_w; off = id - 98304; }
        float2 w = *(const float2*)&src[(size_t)off * 2];
        wdst[id] = packbf(w.x, w.y);
        return;
    }
    // ---- h0 gather (4 tokens/block, inline length via ballot) ----
    int g = (bid - 1060) * 4 + (tid >> 6);
    int d = tid & 63;
    int n = g / LP;
    int tt = g - n * LP;
    int b = n & 255, s = n >> 8;
    const int* row = ids + (size_t)(b * 4 + s) * 50;
    int v = (d < 50) ? row[d] : 0;
    unsigned long long bal = __ballot(v != 0);
    int len = __popcll(bal);
    int id0 = (tt < len - 1) ? row[tt] : 0;
    float2 e = *(const float2*)&id_emb[(size_t)id0 * 128 + d * 2];
    hb[(size_t)g * 64 + d] = packbf(e.x, e.y);
}

// ======== FUSED Ei/Eo + GRU (32 rows/block, grid 1568) ========
__global__ __launch_bounds__(256) void gru_fused_kernel(
    const uint32* __restrict__ hb,          // [NTOK][64] u32 (bf16 h in)
    unsigned short* __restrict__ hb2,       // [NTOK][128] bf16 h out
    const bf16* __restrict__ Wi, const bf16* __restrict__ Wo,   // [128][128] bf16
    const bf16* __restrict__ wihb,   // [384][256] bf16
    const bf16* __restrict__ whhb,   // [384][128] bf16
    const float* __restrict__ ei_b, const float* __restrict__ eo_b,
    const float* __restrict__ b_iah, const float* __restrict__ b_oah,
    const float* __restrict__ b_ih, const float* __restrict__ b_hh,
    const int* __restrict__ lens)
{
    __shared__ __align__(16) bf16 Agi[32][264];   // 528B pitch (16B-aligned rows)
    const int tid = threadIdx.x;
    const int wv = tid >> 6;
    const int lane = tid & 63;
    const int quad = lane >> 4;
    const int lr = lane & 15;
    const int c0 = wv * 32;
    const int g0 = blockIdx.x * 32;
    const bf16* hbb = (const bf16*)hb;

    // ---- phase 1: halo Ei/Eo GEMMs over 4 src tiles [g0-16, g0+48) ----
    int arows[4];
#pragma unroll
    for (int t = 0; t < 4; ++t) {
        int r = g0 + (t - 1) * 16 + lr;
        arows[t] = (r < 0) ? r + NTOK : (r >= NTOK ? r - NTOK : r);
    }
    f32x4 aEi[3][2], aEo[3][2];
#pragma unroll
    for (int t = 0; t < 3; ++t) {
        aEi[t][0] = (f32x4){0,0,0,0}; aEi[t][1] = (f32x4){0,0,0,0};
        aEo[t][0] = (f32x4){0,0,0,0}; aEo[t][1] = (f32x4){0,0,0,0};
    }
#pragma unroll
    for (int ks = 0; ks < 4; ++ks) {
        short8 bi0 = *(const short8*)&Wi[(size_t)(wv * 32 + lr) * 128 + ks * 32 + quad * 8];
        short8 bi1 = *(const short8*)&Wi[(size_t)(wv * 32 + 16 + lr) * 128 + ks * 32 + quad * 8];
        short8 bo0 = *(const short8*)&Wo[(size_t)(wv * 32 + lr) * 128 + ks * 32 + quad * 8];
        short8 bo1 = *(const short8*)&Wo[(size_t)(wv * 32 + 16 + lr) * 128 + ks * 32 + quad * 8];
        short8 a[4];
#pragma unroll
        for (int t = 0; t < 4; ++t)
            a[t] = *(const short8*)&hbb[(size_t)arows[t] * 128 + ks * 32 + quad * 8];
#pragma unroll
        for (int t = 0; t < 3; ++t) {
            aEi[t][0] = __builtin_amdgcn_mfma_f32_16x16x32_bf16(a[t], bi0, aEi[t][0], 0, 0, 0);
            aEi[t][1] = __builtin_amdgcn_mfma_f32_16x16x32_bf16(a[t], bi1, aEi[t][1], 0, 0, 0);
            aEo[t][0] = __builtin_amdgcn_mfma_f32_16x16x32_bf16(a[t + 1], bo0, aEo[t][0], 0, 0, 0);
            aEo[t][1] = __builtin_amdgcn_mfma_f32_16x16x32_bf16(a[t + 1], bo1, aEo[t][1], 0, 0, 0);
        }
    }
    // ---- phase 2: shifted/masked epilogue into LDS ----
#pragma unroll
    for (int s = 0; s < 2; ++s) {
        int col = c0 + s * 16 + lr;
        float bei = ei_b[col], beo = eo_b[col];
        float bia = b_iah[col], boa = b_oah[col];
#pragma unroll
        for (int t = 0; t < 3; ++t)
#pragma unroll
            for (int reg = 0; reg < 4; ++reg) {
                int src = g0 + (t - 1) * 16 + quad * 4 + reg;
                int ssrc = (src < 0) ? src + NTOK : (src >= NTOK ? src - NTOK : src);
                int d1 = ssrc + 1; if (d1 == NTOK) d1 = 0;
                int ld = d1 - g0;
                if ((unsigned)ld < 32u) {
                    int n1 = d1 / LP, t1 = d1 - n1 * LP, l1 = lens[n1];
                    float v = bia + ((t1 >= 1 && t1 < l1 - 1) ? aEi[t][s][reg] + bei : 0.f);
                    Agi[ld][col] = __float2bfloat16(v);
                }
                int src2 = g0 + t * 16 + quad * 4 + reg;
                int ssrc2 = (src2 >= NTOK) ? src2 - NTOK : src2;
                int d2 = (ssrc2 == 0) ? NTOK - 1 : ssrc2 - 1;
                int ld2 = d2 - g0;
                if ((unsigned)ld2 < 32u) {
                    int n2 = d2 / LP, t2 = d2 - n2 * LP, l2 = lens[n2];
                    float v = boa + ((t2 < l2 - 2) ? aEo[t][s][reg] + beo : 0.f);
                    Agi[ld2][128 + col] = __float2bfloat16(v);
                }
            }
    }
    __syncthreads();

    // ---- phase 3: GRU GEMMs. gi from LDS Agi, gh from global h ----
    int arow[2];
#pragma unroll
    for (int mt = 0; mt < 2; ++mt) arow[mt] = g0 + mt * 16 + lr;
    f32x4 acc[2][2][4];
#pragma unroll
    for (int mt = 0; mt < 2; ++mt)
#pragma unroll
        for (int s = 0; s < 2; ++s)
#pragma unroll
            for (int j = 0; j < 4; ++j) acc[mt][s][j] = (f32x4){0.f, 0.f, 0.f, 0.f};

#pragma unroll 2
    for (int ks = 0; ks < 8; ++ks) {
        short8 bfr[2][3];
#pragma unroll
        for (int s = 0; s < 2; ++s)
#pragma unroll
            for (int gte = 0; gte < 3; ++gte) {
                int n0 = gte * 128 + c0 + s * 16 + lr;
                bfr[s][gte] = *(const short8*)&wihb[(size_t)n0 * 256 + ks * 32 + quad * 8];
            }
#pragma unroll
        for (int mt = 0; mt < 2; ++mt) {
            short8 a = *(const short8*)&Agi[mt * 16 + lr][ks * 32 + quad * 8];
#pragma unroll
            for (int s = 0; s < 2; ++s) {
                acc[mt][s][0] = __builtin_amdgcn_mfma_f32_16x16x32_bf16(a, bfr[s][0], acc[mt][s][0], 0, 0, 0);
                acc[mt][s][1] = __builtin_amdgcn_mfma_f32_16x16x32_bf16(a, bfr[s][1], acc[mt][s][1], 0, 0, 0);
                acc[mt][s][2] = __builtin_amdgcn_mfma_f32_16x16x32_bf16(a, bfr[s][2], acc[mt][s][2], 0, 0, 0);
            }
        }
    }
#pragma unroll 2
    for (int ks = 0; ks < 4; ++ks) {
        short8 bfr[2][3];
#pragma unroll
        for (int s = 0; s < 2; ++s)
#pragma unroll
            for (int gte = 0; gte < 3; ++gte) {
                int n0 = gte * 128 + c0 + s * 16 + lr;
                bfr[s][gte] = *(const short8*)&whhb[(size_t)n0 * 128 + ks * 32 + quad * 8];
            }
#pragma unroll
        for (int mt = 0; mt < 2; ++mt) {
            short8 a = *(const short8*)&hbb[(size_t)arow[mt] * 128 + ks * 32 + quad * 8];
#pragma unroll
            for (int s = 0; s < 2; ++s) {
                acc[mt][s][0] = __builtin_amdgcn_mfma_f32_16x16x32_bf16(a, bfr[s][0], acc[mt][s][0], 0, 0, 0);
                acc[mt][s][1] = __builtin_amdgcn_mfma_f32_16x16x32_bf16(a, bfr[s][1], acc[mt][s][1], 0, 0, 0);
                acc[mt][s][3] = __builtin_amdgcn_mfma_f32_16x16x32_bf16(a, bfr[s][2], acc[mt][s][3], 0, 0, 0);
            }
        }
    }

    const unsigned short* hold = (const unsigned short*)hb;
#pragma unroll
    for (int s = 0; s < 2; ++s) {
        int col = c0 + s * 16 + lr;
        float brz = b_ih[col] + b_hh[col];
        float bzz = b_ih[col + 128] + b_hh[col + 128];
        float bin = b_ih[col + 256];
        float bhn = b_hh[col + 256];
#pragma unroll
        for (int mt = 0; mt < 2; ++mt)
#pragma unroll
            for (int reg = 0; reg < 4; ++reg) {
                int row = g0 + mt * 16 + quad * 4 + reg;
                float rg = 1.f / (1.f + expf(-(acc[mt][s][0][reg] + brz)));
                float zg = 1.f / (1.f + expf(-(acc[mt][s][1][reg] + bzz)));
                float ng = tanhf(acc[mt][s][2][reg] + bin + rg * (acc[mt][s][3][reg] + bhn));
                size_t idx = (size_t)row * 128 + col;
                float ho = __uint_as_float((uint32)hold[idx] << 16);
                hb2[idx] = __bfloat16_as_ushort(__float2bfloat16(ng + zg * (ho - ng)));
            }
    }
}

// ======== FUSED q2 GEMM + alpha (q2 never hits memory) ========
// alpha[row] = sum_d att_w[d]*sigmoid(q1[n][d] + q2[row][d]), masked by t < len-1.
__global__ __launch_bounds__(256) void q2alpha_kernel(
    const bf16* __restrict__ A,      // hb2
    const bf16* __restrict__ W0,     // q2 weights [128][128] bf16
    const float* __restrict__ q1h, const float* __restrict__ att_w,
    const int* __restrict__ lens, float* __restrict__ alG)
{
    __shared__ float red[4][128];
    const int tid = threadIdx.x;
    const int wv = tid >> 6, lane = tid & 63, quad = lane >> 4, lr = lane & 15;
    const int rbase = blockIdx.x * 128;
    f32x4 acc0[8][2];
#pragma unroll
    for (int mt = 0; mt < 8; ++mt) { acc0[mt][0] = (f32x4){0,0,0,0}; acc0[mt][1] = (f32x4){0,0,0,0}; }
#pragma unroll
    for (int ks = 0; ks < 4; ++ks) {
        short8 b00 = *(const short8*)&W0[(size_t)(wv * 32 + lr) * 128 + ks * 32 + quad * 8];
        short8 b01 = *(const short8*)&W0[(size_t)(wv * 32 + 16 + lr) * 128 + ks * 32 + quad * 8];
#pragma unroll
        for (int mt = 0; mt < 8; ++mt) {
            short8 a = *(const short8*)&A[(size_t)(rbase + mt * 16 + lr) * 128 + ks * 32 + quad * 8];
            acc0[mt][0] = __builtin_amdgcn_mfma_f32_16x16x32_bf16(a, b00, acc0[mt][0], 0, 0, 0);
            acc0[mt][1] = __builtin_amdgcn_mfma_f32_16x16x32_bf16(a, b01, acc0[mt][1], 0, 0, 0);
        }
    }
    const int colA = wv * 32 + lr, colB = colA + 16;
    const float awA = att_w[colA], awB = att_w[colB];
#pragma unroll
    for (int mt = 0; mt < 8; ++mt)
#pragma unroll
        for (int reg = 0; reg < 4; ++reg) {
            int row = rbase + mt * 16 + quad * 4 + reg;
            int n = row / LP;
            float q1A = q1h[(size_t)n * 128 + colA];
            float q1B = q1h[(size_t)n * 128 + colB];
            float p = awA / (1.f + expf(-(q1A + acc0[mt][0][reg])))
                    + awB / (1.f + expf(-(q1B + acc0[mt][1][reg])));
            p += __shfl_xor(p, 1, 64);
            p += __shfl_xor(p, 2, 64);
            p += __shfl_xor(p, 4, 64);
            p += __shfl_xor(p, 8, 64);
            if (lr == 0) red[wv][mt * 16 + quad * 4 + reg] = p;
        }
    __syncthreads();
    if (tid < 128) {
        int row = rbase + tid;
        int n = row / LP, t = row - n * LP;
        float s = red[0][tid] + red[1][tid] + red[2][tid] + red[3][tid];
        alG[row] = (t < lens[n] - 1) ? s : 0.f;
    }
}

// ---------------- attention readout + fuse layer -> reps (f32 out) ----------------
__global__ __launch_bounds__(128) void attn_fuse_kernel(
    const float* __restrict__ alG, const unsigned short* __restrict__ hu,
    const float* __restrict__ chist, const int* __restrict__ lens,
    const float* __restrict__ ftwf, const float* __restrict__ fuse_b,
    float* __restrict__ out)
{
    __shared__ float al[64], cv[256];
    const int n = blockIdx.x, tid = threadIdx.x;
    if (tid < 64) al[tid] = (tid < LP) ? alG[(size_t)n * LP + tid] : 0.f;
    __syncthreads();
    const int len = lens[n];
    float ssum = 0.f;
    for (int t = 0; t < len - 1; ++t) ssum += al[t];
    float inv = 1.f / (ssum + 1e-8f);
    float c = 0.f;
    for (int t = 0; t < len - 1; ++t) {
        float hv = __uint_as_float((uint32)hu[(size_t)(n * LP + t) * 128 + tid] << 16);
        c += al[t] * inv * hv;
    }
    cv[tid] = c;
    cv[128 + tid] = chist[(size_t)n * 128 + tid];
    __syncthreads();
    float s = fuse_b[tid];
    for (int kk = 0; kk < 256; ++kk)
        s += cv[kk] * ftwf[(size_t)kk * 128 + tid];
    out[(size_t)n * 128 + tid] = s;
}

// ============================================================================
extern "C" void kernel_launch(void* const* d_in, const int* in_sizes, int n_in,
                              void* d_out, int out_size, void* d_ws, size_t ws_size,
                              hipStream_t stream)
{
    const float* id_emb   = (const float*)d_in[0];
    const float* user_emb = (const float*)d_in[1];
    const float* lin_r_w  = (const float*)d_in[2];
    const float* upi_w    = (const float*)d_in[3];
    const float* upi_b    = (const float*)d_in[4];
    const float* upu_w    = (const float*)d_in[5];
    const float* upu_b    = (const float*)d_in[6];
    const float* w_ih     = (const float*)d_in[7];
    const float* w_hh     = (const float*)d_in[8];
    const float* b_ih     = (const float*)d_in[9];
    const float* b_hh     = (const float*)d_in[10];
    const float* b_iah    = (const float*)d_in[11];
    const float* b_oah    = (const float*)d_in[12];
    const float* ei_w     = (const float*)d_in[13];
    const float* ei_b     = (const float*)d_in[14];
    const float* eo_w     = (const float*)d_in[15];
    const float* eo_b     = (const float*)d_in[16];
    const float* q1_w     = (const float*)d_in[17];
    const float* q2_w     = (const float*)d_in[18];
    const float* att_w    = (const float*)d_in[19];
    const float* fuse_w   = (const float*)d_in[20];
    const float* fuse_b   = (const float*)d_in[21];
    const int*  rel_rows  = (const int*)d_in[22];
    const int*  rel_cols  = (const int*)d_in[23];
    const float* rel_vals = (const float*)d_in[24];
    const int*  ids       = (const int*)d_in[25];
    const int*  uid       = (const int*)d_in[26];
    const float* u_type   = (const float*)d_in[27];
    float* out = (float*)d_out;   // reps[131072] | target[1024] | u_type[1024]

    // ---- workspace layout (u32 units) ----
    uint32* W32    = (uint32*)d_ws;
    uint32* hab    = W32;                                 //  4,480,000 (bf16 nodes)
    uint32* T      = W32 + 4480000;                       // 13,440,000 (bf16, stride 192)
    uint32* edges  = W32 + 17920000;                      //  2,400,000 (4B records)
    int2*   tmp    = (int2*)(W32 + 20320000);             //  2,400,000 int2
    int*    offs   = (int*)(W32 + 25120000);              //  3 x 70001
    int*    bhist  = (int*)(W32 + 25330004);              //  3 x 137
    int*    cursor = (int*)(W32 + 25330415);              //  3 x 137
    int*    bbase  = (int*)(W32 + 25330826);              //  3 x 138
    float*  q1h    = (float*)(W32 + 25396776);            //  131,072
    float*  chist  = (float*)(W32 + 25527848);            //  131,072
    int*    lens   = (int*)(W32 + 25658920);              //  1024
    int*    rowmap = (int*)(W32 + 25659944);              //  1024
    float*  alG    = (float*)(W32 + 25660968);            //  50,176
    uint32* Wcat   = W32 + 25711144;                      //  4 x 32768 (k,seg)  end 25,842,216
    // session overlays:
    uint32* sess_hb = W32 + 20320000;                     // over tmp (dead after refine)
    unsigned short* hb2 = (unsigned short*)(W32 + 10902528); // [NTOK][128] bf16 (in T region)
    uint32* wpk     = W32 + 17920000;                     // packed session wts (over edges)
    uint32* wihb = wpk;              // 49,152
    uint32* whhb = wpk + 49152;      // 24,576
    uint32* eiwb = wpk + 73728;      //  8,192
    uint32* eowb = wpk + 81920;      //  8,192
    uint32* q2wb = wpk + 90112;      //  8,192
    uint32* q1wb = wpk + 98304;      //  8,192
    float*  ftwf = (float*)(wpk + 106496); // 32,768 f32 (fuse_w transposed, k-major)
    if (ws_size < (size_t)27144192 * 4 + 4096) return;

    // ---- init + CSR build ----
    hipMemsetAsync(bhist, 0, (size_t)822 * 4, stream);    // bhist + cursor
    init_hist_kernel<<<9338, 256, 0, stream>>>((const float4*)id_emb, (const float4*)user_emb,
                                               hab, rel_rows, bhist);
    bucket_scan_kernel<<<1, 256, 0, stream>>>(bhist, bbase);
    bucket_scatter_kernel<<<dim3(196, 3), 256, 0, stream>>>(rel_rows, rel_cols, rel_vals,
                                                            bbase, cursor, tmp);
    bucket_refine_kernel<<<dim3(NBK, 3), 256, 0, stream>>>(tmp, bbase, offs, edges);

    // ---- weight prep for both HGNN layers (hoisted out of k-loop) ----
    wprep_kernel<<<dim3(2, 6, 2), 256, 0, stream>>>(upi_w, upu_w, lin_r_w, Wcat);
    upack_kernel<<<128, 256, 0, stream>>>(upi_w, upu_w, Wcat);

    // ---- HGNN: 2 layers ----
    for (int k = 0; k < 2; ++k) {
        gather_kernel<<<17500, 256, 0, stream>>>(hab, edges, offs, T);
        hgnn_update_mfma_kernel<<<548, 256, 0, stream>>>((const bf16*)T, hab,
            (const bf16*)Wcat, upi_b, upu_b, k);
    }

    // ---- session branch ----
    misc_prep_kernel<<<13604, 256, 0, stream>>>(ids, uid, u_type, id_emb, hab,
        w_ih, w_hh, ei_w, eo_w, q2_w, q1_w, fuse_w,
        lens, rowmap, out + 131072, out + 132096, chist, wpk, sess_hb);
    gru_fused_kernel<<<1568, 256, 0, stream>>>(sess_hb, hb2,
        (const bf16*)eiwb, (const bf16*)eowb,
        (const bf16*)wihb, (const bf16*)whhb,
        ei_b, eo_b, b_iah, b_oah, b_ih, b_hh, lens);
    mfma_nt_kernel<<<8, 256, 0, stream>>>((const bf16*)hb2, rowmap,
        (const bf16*)q1wb, nullptr, q1h, NSESS);
    q2alpha_kernel<<<392, 256, 0, stream>>>((const bf16*)hb2, (const bf16*)q2wb,
        q1h, att_w, lens, alG);
    attn_fuse_kernel<<<NSESS, 128, 0, stream>>>(alG, (const unsigned short*)hb2,
        chist, lens, ftwf, fuse_b, out);
}

// Round 14
// 696.268 us; speedup vs baseline: 1.1055x; 1.0199x over previous
//
#include <hip/hip_runtime.h>
#include <hip/hip_bf16.h>

typedef __hip_bfloat16 bf16;
typedef unsigned int uint32;
typedef __attribute__((ext_vector_type(8))) short short8;   // 8 bf16 (4 VGPRs)
typedef __attribute__((ext_vector_type(4))) float f32x4;
typedef __attribute__((ext_vector_type(2))) float f32x2;
typedef __attribute__((ext_vector_type(4))) uint32 u32x4;   // clang vector: ok for nontemporal

#define N_ITEMS_C 50000
#define N_USERS_C 20000
#define N_NODES_C 70000
#define NNZ_C 800000
#define NSESS 1024
#define LP 49
#define NTOK (NSESS * LP)   // 50176
#define NBK 137             // coarse buckets: row >> 9

__device__ __forceinline__ float bflo(uint32 u) { return __uint_as_float(u << 16); }
__device__ __forceinline__ float bfhi(uint32 u) { return __uint_as_float(u & 0xffff0000u); }
// hi bf16 with low-16 garbage bits: relative error <= 2^-17, far below bf16 rounding.
__device__ __forceinline__ float bfhi_fast(uint32 u) { return __uint_as_float(u); }
__device__ __forceinline__ uint32 packbf(float a, float b) {
    return (uint32)__bfloat16_as_ushort(__float2bfloat16(a)) |
           ((uint32)__bfloat16_as_ushort(__float2bfloat16(b)) << 16);
}

// ===== FUSED: init hab (blocks [0,8750)) + bucket hist (blocks [8750,9338)) =====
__global__ __launch_bounds__(256) void init_hist_kernel(
    const float4* __restrict__ idp, const float4* __restrict__ usp,
    uint32* __restrict__ hab, const int* __restrict__ rel_rows, int* __restrict__ bhist)
{
    __shared__ int hist[NBK];
    const int tid = threadIdx.x;
    if (blockIdx.x < 8750) {
        int i = blockIdx.x * 256 + tid;           // quad index, 2,240,000 total
        float4 w = (i < 1600000) ? idp[i] : usp[i - 1600000];
        uint2 o = make_uint2(packbf(w.x, w.y), packbf(w.z, w.w));
        *(uint2*)&hab[(size_t)i * 2] = o;
        return;
    }
    const int hb = blockIdx.x - 8750;             // 588 hist blocks: 196 x 3
    const int r = hb / 196, xb = hb - r * 196;
    if (tid < NBK) hist[tid] = 0;
    __syncthreads();
    const int* rr = rel_rows + (size_t)r * NNZ_C;
#pragma unroll
    for (int i = 0; i < 16; ++i) {
        int e = xb * 4096 + i * 256 + tid;
        if (e < NNZ_C) atomicAdd(&hist[rr[e] >> 9], 1);
    }
    __syncthreads();
    if (tid < NBK && hist[tid]) atomicAdd(&bhist[r * NBK + tid], hist[tid]);
}

// A2: scan bucket totals -> bbase[r][0..NBK]
__global__ __launch_bounds__(256) void bucket_scan_kernel(
    const int* __restrict__ bhist, int* __restrict__ bbase)
{
    __shared__ int s[256];
    const int tid = threadIdx.x;
    for (int r = 0; r < 3; ++r) {
        s[tid] = (tid < NBK) ? bhist[r * NBK + tid] : 0;
        __syncthreads();
        for (int d = 1; d < 256; d <<= 1) {
            int t = (tid >= d) ? s[tid - d] : 0;
            __syncthreads();
            s[tid] += t;
            __syncthreads();
        }
        if (tid < NBK) bbase[r * (NBK + 1) + tid + 1] = s[tid];
        if (tid == 0) bbase[r * (NBK + 1)] = 0;
        __syncthreads();
    }
}

// A3: scatter edges into bucket-contiguous tmp (int2: packed(col|v15), row)
__global__ __launch_bounds__(256) void bucket_scatter_kernel(
    const int* __restrict__ rel_rows, const int* __restrict__ rel_cols,
    const float* __restrict__ rel_vals, const int* __restrict__ bbase,
    int* __restrict__ cursor, int2* __restrict__ tmp)
{
    __shared__ int hist[NBK], gbase[NBK], cur2[NBK];
    const int r = blockIdx.y, tid = threadIdx.x;
    if (tid < NBK) { hist[tid] = 0; cur2[tid] = 0; }
    __syncthreads();
    const int* rr = rel_rows + (size_t)r * NNZ_C;
    const int* rc = rel_cols + (size_t)r * NNZ_C;
    const float* rv = rel_vals + (size_t)r * NNZ_C;
    int rows[16];
#pragma unroll
    for (int i = 0; i < 16; ++i) {
        int e = blockIdx.x * 4096 + i * 256 + tid;
        rows[i] = (e < NNZ_C) ? rr[e] : -1;
        if (rows[i] >= 0) atomicAdd(&hist[rows[i] >> 9], 1);
    }
    __syncthreads();
    if (tid < NBK)
        gbase[tid] = bbase[r * (NBK + 1) + tid] +
                     (hist[tid] ? atomicAdd(&cursor[r * NBK + tid], hist[tid]) : 0);
    __syncthreads();
    int2* tp = tmp + (size_t)r * NNZ_C;
#pragma unroll
    for (int i = 0; i < 16; ++i) {
        int e = blockIdx.x * 4096 + i * 256 + tid;
        if (rows[i] >= 0) {
            int bk = rows[i] >> 9;
            int rank = atomicAdd(&cur2[bk], 1);
            uint32 fb = __float_as_uint(rv[e]);
            uint32 pk = (uint32)rc[e] | (((fb >> 16) & 0x7FFFu) << 17);
            tp[gbase[bk] + rank] = make_int2((int)pk, rows[i]);
        }
    }
}

// B: refine one bucket: per-row offsets + row-sorted 4B records, all writes coalesced
__global__ __launch_bounds__(256) void bucket_refine_kernel(
    const int2* __restrict__ tmp, const int* __restrict__ bbase,
    int* __restrict__ offs, uint32* __restrict__ edges)
{
    __shared__ int cnt[512], offsL[512], cur[512];
    __shared__ uint32 outb[6656];
    const int b = blockIdx.x, r = blockIdx.y, tid = threadIdx.x;
    const int lane = tid & 63, wid = tid >> 6;
    const int row0 = b << 9;
    const int e0 = bbase[r * (NBK + 1) + b];
    const int e1 = bbase[r * (NBK + 1) + b + 1];
    cnt[tid] = 0; cnt[256 + tid] = 0; cur[tid] = 0; cur[256 + tid] = 0;
    __syncthreads();
    const int2* tp = tmp + (size_t)r * NNZ_C;
    for (int e = e0 + tid; e < e1; e += 256)
        atomicAdd(&cnt[tp[e].y - row0], 1);
    __syncthreads();
    if (wid == 0) {   // wave 0: exclusive scan of 512 counters
        int carry = 0;
        for (int c = 0; c < 8; ++c) {
            int x = cnt[c * 64 + lane];
            int inc = x;
#pragma unroll
            for (int d = 1; d < 64; d <<= 1) {
                int y = __shfl_up(inc, d, 64);
                if (lane >= d) inc += y;
            }
            offsL[c * 64 + lane] = inc - x + carry;
            carry += __shfl(inc, 63, 64);
        }
    }
    __syncthreads();
    // per-row global offsets (covers offs[70000] terminator via bucket 136)
    for (int i = tid; i < 512; i += 256) {
        int row = row0 + i;
        if (row < 70001) offs[(size_t)r * 70001 + row] = e0 + offsL[i];
    }
    for (int e = e0 + tid; e < e1; e += 256) {
        int2 E = tp[e];
        int lr_ = E.y - row0;
        int slot = offsL[lr_] + atomicAdd(&cur[lr_], 1);
        if (slot < 6656) outb[slot] = (uint32)E.x;
    }
    __syncthreads();
    uint32* eo = edges + (size_t)r * NNZ_C + e0;
    for (int i = tid; i < e1 - e0; i += 256) eo[i] = outb[i];
}

// ---------------- gather: T[row][r] = sum_e val * hab[col], all 3 relations fused --------
__global__ __launch_bounds__(256) void gather_kernel(
    const uint32* __restrict__ hab, const uint32* __restrict__ edges,
    const int* __restrict__ offs, uint32* __restrict__ T)
{
    const int row = blockIdx.x * 4 + (threadIdx.x >> 6);
    const int lane = threadIdx.x & 63;
    const int grp = lane >> 4;       // which edge-slot group of the quad
    const int ql  = lane & 15;       // 4 u32 (8 dims) per lane
    const char* __restrict__ habB = (const char*)hab + ql * 16;
    f32x2 acc[3][4];
#pragma unroll
    for (int r = 0; r < 3; ++r)
#pragma unroll
        for (int j = 0; j < 4; ++j) acc[r][j] = (f32x2){0.f, 0.f};
#pragma unroll
    for (int r = 0; r < 3; ++r) {
        const uint32* __restrict__ ed = edges + (size_t)r * NNZ_C;
        const int* __restrict__ of = offs + (size_t)r * 70001;
        const int e0 = of[row], e1 = of[row + 1];
        if (e0 >= e1) continue;
        const uint32 span = (uint32)(e1 - e0);
        const int s0 = e0 & ~3;                      // 16B-aligned edge-record base
        for (int eb = s0; eb < e1; eb += 16) {
            const int base = eb + grp * 4;
            uint4 E4 = *(const uint4*)&ed[base];
            uint32 Ej0 = ((uint32)(base + 0 - e0) < span) ? E4.x : 0u;
            uint32 Ej1 = ((uint32)(base + 1 - e0) < span) ? E4.y : 0u;
            uint32 Ej2 = ((uint32)(base + 2 - e0) < span) ? E4.z : 0u;
            uint32 Ej3 = ((uint32)(base + 3 - e0) < span) ? E4.w : 0u;
            uint4 u0 = *(const uint4*)(habB + ((Ej0 & 0x1FFFFu) << 8));
            uint4 u1 = *(const uint4*)(habB + ((Ej1 & 0x1FFFFu) << 8));
            uint4 u2 = *(const uint4*)(habB + ((Ej2 & 0x1FFFFu) << 8));
            uint4 u3 = *(const uint4*)(habB + ((Ej3 & 0x1FFFFu) << 8));
            float v0 = __uint_as_float((Ej0 >> 1) & 0x7FFF0000u);
            float v1 = __uint_as_float((Ej1 >> 1) & 0x7FFF0000u);
            float v2 = __uint_as_float((Ej2 >> 1) & 0x7FFF0000u);
            float v3 = __uint_as_float((Ej3 >> 1) & 0x7FFF0000u);
            f32x2 vv;
            vv = (f32x2){v0, v0};
            acc[r][0] += vv * (f32x2){bflo(u0.x), bfhi_fast(u0.x)};
            acc[r][1] += vv * (f32x2){bflo(u0.y), bfhi_fast(u0.y)};
            acc[r][2] += vv * (f32x2){bflo(u0.z), bfhi_fast(u0.z)};
            acc[r][3] += vv * (f32x2){bflo(u0.w), bfhi_fast(u0.w)};
            vv = (f32x2){v1, v1};
            acc[r][0] += vv * (f32x2){bflo(u1.x), bfhi_fast(u1.x)};
            acc[r][1] += vv * (f32x2){bflo(u1.y), bfhi_fast(u1.y)};
            acc[r][2] += vv * (f32x2){bflo(u1.z), bfhi_fast(u1.z)};
            acc[r][3] += vv * (f32x2){bflo(u1.w), bfhi_fast(u1.w)};
            vv = (f32x2){v2, v2};
            acc[r][0] += vv * (f32x2){bflo(u2.x), bfhi_fast(u2.x)};
            acc[r][1] += vv * (f32x2){bflo(u2.y), bfhi_fast(u2.y)};
            acc[r][2] += vv * (f32x2){bflo(u2.z), bfhi_fast(u2.z)};
            acc[r][3] += vv * (f32x2){bflo(u2.w), bfhi_fast(u2.w)};
            vv = (f32x2){v3, v3};
            acc[r][0] += vv * (f32x2){bflo(u3.x), bfhi_fast(u3.x)};
            acc[r][1] += vv * (f32x2){bflo(u3.y), bfhi_fast(u3.y)};
            acc[r][2] += vv * (f32x2){bflo(u3.z), bfhi_fast(u3.z)};
            acc[r][3] += vv * (f32x2){bflo(u3.w), bfhi_fast(u3.w)};
        }
    }
    float* af = (float*)acc;
#pragma unroll
    for (int off = 16; off < 64; off <<= 1)
#pragma unroll
        for (int j = 0; j < 24; ++j) af[j] += __shfl_xor(af[j], off, 64);
    if (grp == 0) {
#pragma unroll
        for (int r = 0; r < 3; ++r) {
            u32x4 o;
            o.x = packbf(acc[r][0].x, acc[r][0].y);
            o.y = packbf(acc[r][1].x, acc[r][1].y);
            o.z = packbf(acc[r][2].x, acc[r][2].y);
            o.w = packbf(acc[r][3].x, acc[r][3].y);
            __builtin_nontemporal_store(o, (u32x4*)&T[(size_t)row * 192 + r * 64 + ql * 4]);
        }
    }
}

// ===== FUSED weight prep: wprep (blocks [0,24)) + upack (blocks [24,152)) =====
__global__ __launch_bounds__(256, 3) void wprep_upack_kernel(
    const float* __restrict__ upi_w, const float* __restrict__ upu_w,
    const float* __restrict__ lin_r_w, uint32* __restrict__ Wcat)
{
    __shared__ float As[128][65];
    __shared__ __align__(8) bf16 Ws[128][66];
    const int tid = threadIdx.x;
    if (blockIdx.x >= 24) {              // ---- upack ----
        int id = (blockIdx.x - 24) * 256 + tid;   // 32768 pairs (2k x 2seg x 8192)
        int k = id >> 14, rest = id & 16383;
        int seg = rest >> 13, p = rest & 8191;
        int n = p >> 6, j2 = (p & 63);
        const float* U = (seg ? upu_w : upi_w) + (size_t)k * 16384;
        float2 w = *(const float2*)&U[(size_t)n * 128 + j2 * 2];
        Wcat[(size_t)(k * 2 + seg) * 32768 + (size_t)n * 256 + 192 + j2] = packbf(w.x, w.y);
        return;
    }
    // ---- wprep ----
    const int xb = blockIdx.x & 1, rest = blockIdx.x >> 1;
    const int which = rest % 6, k = rest / 6;
    const int seg = which / 3, r = which % 3;
    const float* U  = (seg == 0 ? upi_w : upu_w) + (size_t)k * 16384;
    const float* Wr = lin_r_w + (size_t)(k * 3 + r) * 16384;
    uint32* out = Wcat + (size_t)(k * 2 + seg) * 32768;   // u32 row stride 256
    const int row0 = xb * 64;
#pragma unroll
    for (int i = 0; i < 8; ++i) {
        int id = i * 256 + tid;
        int rr = id >> 5, c4 = (id & 31) << 2;
        float4 v = *(const float4*)&U[(size_t)(row0 + rr) * 128 + c4];
        As[c4][rr] = v.x; As[c4+1][rr] = v.y; As[c4+2][rr] = v.z; As[c4+3][rr] = v.w;
    }
    const int m0 = (tid & 15) * 4;
    const int n0 = (tid >> 4) * 8;
    float acc[4][8];
#pragma unroll
    for (int i = 0; i < 4; ++i)
#pragma unroll
        for (int j = 0; j < 8; ++j) acc[i][j] = 0.f;
    for (int p = 0; p < 2; ++p) {
        if (p) __syncthreads();
        for (int i = 0; i < 32; ++i) {       // Ws[c][kf] = Wr[p*64+kf][c] (transposed)
            int id = i * 256 + tid;
            int c = id >> 6, kf = id & 63;
            Ws[c][kf] = __float2bfloat16(Wr[(size_t)(p * 64 + kf) * 128 + c]);
        }
        __syncthreads();
        for (int k2 = 0; k2 < 32; ++k2) {
            int kk = p * 64 + 2 * k2;
            float av0[4], av1[4];
#pragma unroll
            for (int i = 0; i < 4; ++i) { av0[i] = As[kk][m0 + i]; av1[i] = As[kk + 1][m0 + i]; }
#pragma unroll
            for (int j = 0; j < 8; ++j) {
                uint32 wp = *(const uint32*)&Ws[n0 + j][2 * k2];
                float w0 = bflo(wp), w1 = bfhi(wp);
#pragma unroll
                for (int i = 0; i < 4; ++i)
                    acc[i][j] = fmaf(av1[i], w1, fmaf(av0[i], w0, acc[i][j]));
            }
        }
    }
#pragma unroll
    for (int i = 0; i < 4; ++i) {
        int n = row0 + m0 + i;
#pragma unroll
        for (int j = 0; j < 8; j += 2)
            out[(size_t)n * 256 + (r * 128 + n0 + j) / 2] = packbf(acc[i][j], acc[i][j + 1]);
    }
}

// ---------- HGNN update (MFMA, LDS-free, 128-row tiles, items+users in one grid) ----------
#define HGNN_ITEM_BLOCKS 391
__global__ __launch_bounds__(256) void hgnn_update_mfma_kernel(
    const bf16* __restrict__ T, uint32* __restrict__ hab,
    const bf16* __restrict__ Wcat, const float* __restrict__ upi_b,
    const float* __restrict__ upu_b, int k)
{
    const int tid = threadIdx.x;
    const int wv = tid >> 6, lane = tid & 63, quad = lane >> 4, lr = lane & 15;
    const int bid = blockIdx.x;
    const int seg = (bid >= HGNN_ITEM_BLOCKS) ? 1 : 0;
    const int row0 = seg ? N_ITEMS_C : 0;
    const int M = seg ? N_USERS_C : N_ITEMS_C;
    const int rbase = (seg ? bid - HGNN_ITEM_BLOCKS : bid) * 128;
    const bf16* __restrict__ Wc = Wcat + (size_t)(k * 2 + seg) * 65536;
    const float* __restrict__ bias = (seg ? upu_b : upi_b) + k * 128;
    const bf16* hb = (const bf16*)hab;
    f32x4 acc[8][2];
#pragma unroll
    for (int mt = 0; mt < 8; ++mt) { acc[mt][0] = (f32x4){0,0,0,0}; acc[mt][1] = (f32x4){0,0,0,0}; }
    int arow[8];
#pragma unroll
    for (int mt = 0; mt < 8; ++mt) {
        int rr = rbase + mt * 16 + lr;
        arow[mt] = row0 + (rr < M ? rr : M - 1);
    }
#pragma unroll
    for (int ks = 0; ks < 16; ++ks) {
        short8 b0 = *(const short8*)&Wc[(size_t)(wv * 32 + lr) * 512 + ks * 32 + quad * 8];
        short8 b1 = *(const short8*)&Wc[(size_t)(wv * 32 + 16 + lr) * 512 + ks * 32 + quad * 8];
#pragma unroll
        for (int mt = 0; mt < 8; ++mt) {
            short8 a;
            if (ks < 12) a = *(const short8*)&T[(size_t)arow[mt] * 384 + ks * 32 + quad * 8];
            else         a = *(const short8*)&hb[(size_t)arow[mt] * 128 + (ks - 12) * 32 + quad * 8];
            acc[mt][0] = __builtin_amdgcn_mfma_f32_16x16x32_bf16(a, b0, acc[mt][0], 0, 0, 0);
            acc[mt][1] = __builtin_amdgcn_mfma_f32_16x16x32_bf16(a, b1, acc[mt][1], 0, 0, 0);
        }
    }
    __syncthreads();   // drain loads: all hab reads done before in-place writes
    unsigned short* hw = (unsigned short*)hab;
#pragma unroll
    for (int s = 0; s < 2; ++s) {
        int col = wv * 32 + s * 16 + lr;
        float bv = bias[col];
#pragma unroll
        for (int mt = 0; mt < 8; ++mt)
#pragma unroll
            for (int reg = 0; reg < 4; ++reg) {
                int rr = rbase + mt * 16 + quad * 4 + reg;
                if (rr < M) {
                    float v = fmaxf(acc[mt][s][reg] + bv, 0.f);
                    hw[(size_t)(row0 + rr) * 128 + col] = __bfloat16_as_ushort(__float2bfloat16(v));
                }
            }
    }
}

// ===== FUSED misc prep: session_prep [0,4) | epack [4,548) | h0+mask [548,13092) =====
__global__ __launch_bounds__(256) void misc_prep_kernel(
    const int* __restrict__ ids, const float* __restrict__ u_type,
    const float* __restrict__ id_emb,
    const float* __restrict__ w_ih, const float* __restrict__ w_hh,
    const float* __restrict__ ei_w, const float* __restrict__ eo_w,
    const float* __restrict__ q2_w, const float* __restrict__ q1_w,
    const float* __restrict__ fuse_w,
    int* __restrict__ lens, int* __restrict__ rowmap,
    float* __restrict__ out_target, float* __restrict__ out_utype,
    uint32* __restrict__ wdst, uint32* __restrict__ hb,
    unsigned char* __restrict__ maskG)
{
    const int bid = blockIdx.x, tid = threadIdx.x;
    if (bid < 4) {                       // ---- session prep ----
        int n = bid * 256 + tid;
        if (n >= NSESS) return;
        int b = n & 255, s = n >> 8;
        const int* row = ids + (size_t)(b * 4 + s) * 50;
        int len = 0;
#pragma unroll
        for (int l = 0; l < 50; ++l) len += (row[l] != 0) ? 1 : 0;
        lens[n] = len;
        rowmap[n] = n * LP + (len - 2);
        out_target[n] = (float)row[len - 1];
        out_utype[n] = u_type[b];
        return;
    }
    if (bid < 548) {                     // ---- epack + fuse_w transpose ----
        int id = (bid - 4) * 256 + tid;
        if (id >= 106496) {
            if (id >= 139264) return;
            int f = id - 106496;
            int kk = f >> 7, n = f & 127;
            ((float*)wdst)[id] = fuse_w[(size_t)n * 256 + kk];
            return;
        }
        const float* src; int off;
        if      (id <  49152) { src = w_ih; off = id; }
        else if (id <  73728) { src = w_hh; off = id - 49152; }
        else if (id <  81920) { src = ei_w; off = id - 73728; }
        else if (id <  90112) { src = eo_w; off = id - 81920; }
        else if (id <  98304) { src = q2_w; off = id - 90112; }
        else                  { src = q1_w; off = id - 98304; }
        float2 w = *(const float2*)&src[(size_t)off * 2];
        wdst[id] = packbf(w.x, w.y);
        return;
    }
    // ---- h0 gather (4 tokens/block, inline length via ballot) + mask byte ----
    int g = (bid - 548) * 4 + (tid >> 6);
    int d = tid & 63;
    int n = g / LP;
    int tt = g - n * LP;
    int b = n & 255, s = n >> 8;
    const int* row = ids + (size_t)(b * 4 + s) * 50;
    int v = (d < 50) ? row[d] : 0;
    unsigned long long bal = __ballot(v != 0);
    int len = __popcll(bal);
    int id0 = (tt < len - 1) ? row[tt] : 0;
    float2 e = *(const float2*)&id_emb[(size_t)id0 * 128 + d * 2];
    hb[(size_t)g * 64 + d] = packbf(e.x, e.y);
    if (d == 0) {
        unsigned char m = 0;
        if (tt >= 1 && tt < len - 1) m |= 1;   // Ei-valid at dest g
        if (tt < len - 2) m |= 2;              // Eo-valid at dest g
        if (tt < len - 1) m |= 4;              // in-seq
        maskG[g] = m;
    }
}

// ======== FUSED Ei/Eo + GRU (32 rows/block, grid 1568; mask byte replaces div/lens) ========
__global__ __launch_bounds__(256) void gru_fused_kernel(
    const uint32* __restrict__ hb,          // [NTOK][64] u32 (bf16 h in)
    unsigned short* __restrict__ hb2,       // [NTOK][128] bf16 h out
    const bf16* __restrict__ Wi, const bf16* __restrict__ Wo,   // [128][128] bf16
    const bf16* __restrict__ wihb,   // [384][256] bf16
    const bf16* __restrict__ whhb,   // [384][128] bf16
    const float* __restrict__ ei_b, const float* __restrict__ eo_b,
    const float* __restrict__ b_iah, const float* __restrict__ b_oah,
    const float* __restrict__ b_ih, const float* __restrict__ b_hh,
    const unsigned char* __restrict__ maskG)
{
    __shared__ __align__(16) bf16 Agi[32][264];   // 528B pitch (16B-aligned rows)
    const int tid = threadIdx.x;
    const int wv = tid >> 6;
    const int lane = tid & 63;
    const int quad = lane >> 4;
    const int lr = lane & 15;
    const int c0 = wv * 32;
    const int g0 = blockIdx.x * 32;
    const bf16* hbb = (const bf16*)hb;

    // ---- phase 1: halo Ei/Eo GEMMs over 4 src tiles [g0-16, g0+48) ----
    int arows[4];
#pragma unroll
    for (int t = 0; t < 4; ++t) {
        int r = g0 + (t - 1) * 16 + lr;
        arows[t] = (r < 0) ? r + NTOK : (r >= NTOK ? r - NTOK : r);
    }
    f32x4 aEi[3][2], aEo[3][2];
#pragma unroll
    for (int t = 0; t < 3; ++t) {
        aEi[t][0] = (f32x4){0,0,0,0}; aEi[t][1] = (f32x4){0,0,0,0};
        aEo[t][0] = (f32x4){0,0,0,0}; aEo[t][1] = (f32x4){0,0,0,0};
    }
#pragma unroll
    for (int ks = 0; ks < 4; ++ks) {
        short8 bi0 = *(const short8*)&Wi[(size_t)(wv * 32 + lr) * 128 + ks * 32 + quad * 8];
        short8 bi1 = *(const short8*)&Wi[(size_t)(wv * 32 + 16 + lr) * 128 + ks * 32 + quad * 8];
        short8 bo0 = *(const short8*)&Wo[(size_t)(wv * 32 + lr) * 128 + ks * 32 + quad * 8];
        short8 bo1 = *(const short8*)&Wo[(size_t)(wv * 32 + 16 + lr) * 128 + ks * 32 + quad * 8];
        short8 a[4];
#pragma unroll
        for (int t = 0; t < 4; ++t)
            a[t] = *(const short8*)&hbb[(size_t)arows[t] * 128 + ks * 32 + quad * 8];
#pragma unroll
        for (int t = 0; t < 3; ++t) {
            aEi[t][0] = __builtin_amdgcn_mfma_f32_16x16x32_bf16(a[t], bi0, aEi[t][0], 0, 0, 0);
            aEi[t][1] = __builtin_amdgcn_mfma_f32_16x16x32_bf16(a[t], bi1, aEi[t][1], 0, 0, 0);
            aEo[t][0] = __builtin_amdgcn_mfma_f32_16x16x32_bf16(a[t + 1], bo0, aEo[t][0], 0, 0, 0);
            aEo[t][1] = __builtin_amdgcn_mfma_f32_16x16x32_bf16(a[t + 1], bo1, aEo[t][1], 0, 0, 0);
        }
    }
    // ---- phase 2: shifted/masked epilogue into LDS (mask byte, no div/lens) ----
#pragma unroll
    for (int s = 0; s < 2; ++s) {
        int col = c0 + s * 16 + lr;
        float bei = ei_b[col], beo = eo_b[col];
        float bia = b_iah[col], boa = b_oah[col];
#pragma unroll
        for (int t = 0; t < 3; ++t)
#pragma unroll
            for (int reg = 0; reg < 4; ++reg) {
                int src = g0 + (t - 1) * 16 + quad * 4 + reg;
                int ssrc = (src < 0) ? src + NTOK : (src >= NTOK ? src - NTOK : src);
                int d1 = ssrc + 1; if (d1 == NTOK) d1 = 0;
                int ld = d1 - g0;
                if ((unsigned)ld < 32u) {
                    float v = bia + ((maskG[d1] & 1) ? aEi[t][s][reg] + bei : 0.f);
                    Agi[ld][col] = __float2bfloat16(v);
                }
                int src2 = g0 + t * 16 + quad * 4 + reg;
                int ssrc2 = (src2 >= NTOK) ? src2 - NTOK : src2;
                int d2 = (ssrc2 == 0) ? NTOK - 1 : ssrc2 - 1;
                int ld2 = d2 - g0;
                if ((unsigned)ld2 < 32u) {
                    float v = boa + ((maskG[d2] & 2) ? aEo[t][s][reg] + beo : 0.f);
                    Agi[ld2][128 + col] = __float2bfloat16(v);
                }
            }
    }
    __syncthreads();

    // ---- phase 3: GRU GEMMs. gi from LDS Agi, gh from global h ----
    int arow[2];
#pragma unroll
    for (int mt = 0; mt < 2; ++mt) arow[mt] = g0 + mt * 16 + lr;
    f32x4 acc[2][2][4];
#pragma unroll
    for (int mt = 0; mt < 2; ++mt)
#pragma unroll
        for (int s = 0; s < 2; ++s)
#pragma unroll
            for (int j = 0; j < 4; ++j) acc[mt][s][j] = (f32x4){0.f, 0.f, 0.f, 0.f};

#pragma unroll 2
    for (int ks = 0; ks < 8; ++ks) {
        short8 bfr[2][3];
#pragma unroll
        for (int s = 0; s < 2; ++s)
#pragma unroll
            for (int gte = 0; gte < 3; ++gte) {
                int n0 = gte * 128 + c0 + s * 16 + lr;
                bfr[s][gte] = *(const short8*)&wihb[(size_t)n0 * 256 + ks * 32 + quad * 8];
            }
#pragma unroll
        for (int mt = 0; mt < 2; ++mt) {
            short8 a = *(const short8*)&Agi[mt * 16 + lr][ks * 32 + quad * 8];
#pragma unroll
            for (int s = 0; s < 2; ++s) {
                acc[mt][s][0] = __builtin_amdgcn_mfma_f32_16x16x32_bf16(a, bfr[s][0], acc[mt][s][0], 0, 0, 0);
                acc[mt][s][1] = __builtin_amdgcn_mfma_f32_16x16x32_bf16(a, bfr[s][1], acc[mt][s][1], 0, 0, 0);
                acc[mt][s][2] = __builtin_amdgcn_mfma_f32_16x16x32_bf16(a, bfr[s][2], acc[mt][s][2], 0, 0, 0);
            }
        }
    }
#pragma unroll 2
    for (int ks = 0; ks < 4; ++ks) {
        short8 bfr[2][3];
#pragma unroll
        for (int s = 0; s < 2; ++s)
#pragma unroll
            for (int gte = 0; gte < 3; ++gte) {
                int n0 = gte * 128 + c0 + s * 16 + lr;
                bfr[s][gte] = *(const short8*)&whhb[(size_t)n0 * 128 + ks * 32 + quad * 8];
            }
#pragma unroll
        for (int mt = 0; mt < 2; ++mt) {
            short8 a = *(const short8*)&hbb[(size_t)arow[mt] * 128 + ks * 32 + quad * 8];
#pragma unroll
            for (int s = 0; s < 2; ++s) {
                acc[mt][s][0] = __builtin_amdgcn_mfma_f32_16x16x32_bf16(a, bfr[s][0], acc[mt][s][0], 0, 0, 0);
                acc[mt][s][1] = __builtin_amdgcn_mfma_f32_16x16x32_bf16(a, bfr[s][1], acc[mt][s][1], 0, 0, 0);
                acc[mt][s][3] = __builtin_amdgcn_mfma_f32_16x16x32_bf16(a, bfr[s][2], acc[mt][s][3], 0, 0, 0);
            }
        }
    }

    const unsigned short* hold = (const unsigned short*)hb;
#pragma unroll
    for (int s = 0; s < 2; ++s) {
        int col = c0 + s * 16 + lr;
        float brz = b_ih[col] + b_hh[col];
        float bzz = b_ih[col + 128] + b_hh[col + 128];
        float bin = b_ih[col + 256];
        float bhn = b_hh[col + 256];
#pragma unroll
        for (int mt = 0; mt < 2; ++mt)
#pragma unroll
            for (int reg = 0; reg < 4; ++reg) {
                int row = g0 + mt * 16 + quad * 4 + reg;
                float rg = 1.f / (1.f + expf(-(acc[mt][s][0][reg] + brz)));
                float zg = 1.f / (1.f + expf(-(acc[mt][s][1][reg] + bzz)));
                float ng = tanhf(acc[mt][s][2][reg] + bin + rg * (acc[mt][s][3][reg] + bhn));
                size_t idx = (size_t)row * 128 + col;
                float ho = __uint_as_float((uint32)hold[idx] << 16);
                hb2[idx] = __bfloat16_as_ushort(__float2bfloat16(ng + zg * (ho - ng)));
            }
    }
}

// ======== FUSED q1 GEMM + q2 GEMM + alpha (q1/q2 never hit memory) ========
__global__ __launch_bounds__(256) void q2alpha_kernel(
    const bf16* __restrict__ A,      // hb2
    const bf16* __restrict__ W0,     // q2 weights [128][128] bf16
    const bf16* __restrict__ Wq1,    // q1 weights [128][128] bf16
    const int* __restrict__ rowmap, const float* __restrict__ att_w,
    const unsigned char* __restrict__ maskG, float* __restrict__ alG)
{
    __shared__ float red[4][128];
    __shared__ float q1s[16][128];
    const int tid = threadIdx.x;
    const int wv = tid >> 6, lane = tid & 63, quad = lane >> 4, lr = lane & 15;
    const int rbase = blockIdx.x * 128;
    const int ns0 = rbase / LP;
    int ns = ns0 + lr; if (ns > NSESS - 1) ns = NSESS - 1;
    const int qrow = rowmap[ns];
    f32x4 q1a[2];
    q1a[0] = (f32x4){0,0,0,0}; q1a[1] = (f32x4){0,0,0,0};
    f32x4 acc0[8][2];
#pragma unroll
    for (int mt = 0; mt < 8; ++mt) { acc0[mt][0] = (f32x4){0,0,0,0}; acc0[mt][1] = (f32x4){0,0,0,0}; }
#pragma unroll
    for (int ks = 0; ks < 4; ++ks) {
        short8 b00 = *(const short8*)&W0[(size_t)(wv * 32 + lr) * 128 + ks * 32 + quad * 8];
        short8 b01 = *(const short8*)&W0[(size_t)(wv * 32 + 16 + lr) * 128 + ks * 32 + quad * 8];
        short8 bq0 = *(const short8*)&Wq1[(size_t)(wv * 32 + lr) * 128 + ks * 32 + quad * 8];
        short8 bq1 = *(const short8*)&Wq1[(size_t)(wv * 32 + 16 + lr) * 128 + ks * 32 + quad * 8];
        short8 aq = *(const short8*)&A[(size_t)qrow * 128 + ks * 32 + quad * 8];
        q1a[0] = __builtin_amdgcn_mfma_f32_16x16x32_bf16(aq, bq0, q1a[0], 0, 0, 0);
        q1a[1] = __builtin_amdgcn_mfma_f32_16x16x32_bf16(aq, bq1, q1a[1], 0, 0, 0);
#pragma unroll
        for (int mt = 0; mt < 8; ++mt) {
            short8 a = *(const short8*)&A[(size_t)(rbase + mt * 16 + lr) * 128 + ks * 32 + quad * 8];
            acc0[mt][0] = __builtin_amdgcn_mfma_f32_16x16x32_bf16(a, b00, acc0[mt][0], 0, 0, 0);
            acc0[mt][1] = __builtin_amdgcn_mfma_f32_16x16x32_bf16(a, b01, acc0[mt][1], 0, 0, 0);
        }
    }
#pragma unroll
    for (int s = 0; s < 2; ++s)
#pragma unroll
        for (int reg = 0; reg < 4; ++reg)
            q1s[quad * 4 + reg][wv * 32 + s * 16 + lr] = q1a[s][reg];
    __syncthreads();
    const int colA = wv * 32 + lr, colB = colA + 16;
    const float awA = att_w[colA], awB = att_w[colB];
#pragma unroll
    for (int mt = 0; mt < 8; ++mt)
#pragma unroll
        for (int reg = 0; reg < 4; ++reg) {
            int row = rbase + mt * 16 + quad * 4 + reg;
            int n = row / LP;
            float q1A = q1s[n - ns0][colA];
            float q1B = q1s[n - ns0][colB];
            float p = awA / (1.f + expf(-(q1A + acc0[mt][0][reg])))
                    + awB / (1.f + expf(-(q1B + acc0[mt][1][reg])));
            p += __shfl_xor(p, 1, 64);
            p += __shfl_xor(p, 2, 64);
            p += __shfl_xor(p, 4, 64);
            p += __shfl_xor(p, 8, 64);
            if (lr == 0) red[wv][mt * 16 + quad * 4 + reg] = p;
        }
    __syncthreads();
    if (tid < 128) {
        int row = rbase + tid;
        float s = red[0][tid] + red[1][tid] + red[2][tid] + red[3][tid];
        alG[row] = (maskG[row] & 4) ? s : 0.f;
    }
}

// ------- attention readout + fuse layer -> reps (chist inlined from hab) -------
__global__ __launch_bounds__(128) void attn_fuse_kernel(
    const float* __restrict__ alG, const unsigned short* __restrict__ hu,
    const uint32* __restrict__ hab, const int* __restrict__ uid,
    const int* __restrict__ lens,
    const float* __restrict__ ftwf, const float* __restrict__ fuse_b,
    float* __restrict__ out)
{
    __shared__ float al[64], cv[256];
    const int n = blockIdx.x, tid = threadIdx.x;
    if (tid < 64) al[tid] = (tid < LP) ? alG[(size_t)n * LP + tid] : 0.f;
    __syncthreads();
    const int len = lens[n];
    float ssum = 0.f;
    for (int t = 0; t < len - 1; ++t) ssum += al[t];
    float inv = 1.f / (ssum + 1e-8f);
    float c = 0.f;
    for (int t = 0; t < len - 1; ++t) {
        float hv = __uint_as_float((uint32)hu[(size_t)(n * LP + t) * 128 + tid] << 16);
        c += al[t] * inv * hv;
    }
    cv[tid] = c;
    uint32 u = hab[(size_t)(N_ITEMS_C + uid[n & 255]) * 64 + (tid >> 1)];
    cv[128 + tid] = (tid & 1) ? bfhi(u) : bflo(u);
    __syncthreads();
    float s = fuse_b[tid];
    for (int kk = 0; kk < 256; ++kk)
        s += cv[kk] * ftwf[(size_t)kk * 128 + tid];
    out[(size_t)n * 128 + tid] = s;
}

// ============================================================================
extern "C" void kernel_launch(void* const* d_in, const int* in_sizes, int n_in,
                              void* d_out, int out_size, void* d_ws, size_t ws_size,
                              hipStream_t stream)
{
    const float* id_emb   = (const float*)d_in[0];
    const float* user_emb = (const float*)d_in[1];
    const float* lin_r_w  = (const float*)d_in[2];
    const float* upi_w    = (const float*)d_in[3];
    const float* upi_b    = (const float*)d_in[4];
    const float* upu_w    = (const float*)d_in[5];
    const float* upu_b    = (const float*)d_in[6];
    const float* w_ih     = (const float*)d_in[7];
    const float* w_hh     = (const float*)d_in[8];
    const float* b_ih     = (const float*)d_in[9];
    const float* b_hh     = (const float*)d_in[10];
    const float* b_iah    = (const float*)d_in[11];
    const float* b_oah    = (const float*)d_in[12];
    const float* ei_w     = (const float*)d_in[13];
    const float* ei_b     = (const float*)d_in[14];
    const float* eo_w     = (const float*)d_in[15];
    const float* eo_b     = (const float*)d_in[16];
    const float* q1_w     = (const float*)d_in[17];
    const float* q2_w     = (const float*)d_in[18];
    const float* att_w    = (const float*)d_in[19];
    const float* fuse_w   = (const float*)d_in[20];
    const float* fuse_b   = (const float*)d_in[21];
    const int*  rel_rows  = (const int*)d_in[22];
    const int*  rel_cols  = (const int*)d_in[23];
    const float* rel_vals = (const float*)d_in[24];
    const int*  ids       = (const int*)d_in[25];
    const int*  uid       = (const int*)d_in[26];
    const float* u_type   = (const float*)d_in[27];
    float* out = (float*)d_out;   // reps[131072] | target[1024] | u_type[1024]

    // ---- workspace layout (u32 units) ----
    uint32* W32    = (uint32*)d_ws;
    uint32* hab    = W32;                                 //  4,480,000 (bf16 nodes)
    uint32* T      = W32 + 4480000;                       // 13,440,000 (bf16, stride 192)
    uint32* edges  = W32 + 17920000;                      //  2,400,000 (4B records)
    int2*   tmp    = (int2*)(W32 + 20320000);             //  2,400,000 int2
    int*    offs   = (int*)(W32 + 25120000);              //  3 x 70001
    int*    bhist  = (int*)(W32 + 25330004);              //  3 x 137
    int*    cursor = (int*)(W32 + 25330415);              //  3 x 137
    int*    bbase  = (int*)(W32 + 25330826);              //  3 x 138
    int*    lens   = (int*)(W32 + 25658920);              //  1024
    int*    rowmap = (int*)(W32 + 25659944);              //  1024
    float*  alG    = (float*)(W32 + 25660968);            //  50,176
    uint32* Wcat   = W32 + 25711144;                      //  4 x 32768 (k,seg)
    unsigned char* maskG = (unsigned char*)(W32 + 25842216); // 50,176 B (12,544 u32) end 25,854,760
    // session overlays:
    uint32* sess_hb = W32 + 20320000;                     // over tmp (dead after refine)
    unsigned short* hb2 = (unsigned short*)(W32 + 10902528); // [NTOK][128] bf16 (in T region)
    uint32* wpk     = W32 + 17920000;                     // packed session wts (over edges)
    uint32* wihb = wpk;              // 49,152
    uint32* whhb = wpk + 49152;      // 24,576
    uint32* eiwb = wpk + 73728;      //  8,192
    uint32* eowb = wpk + 81920;      //  8,192
    uint32* q2wb = wpk + 90112;      //  8,192
    uint32* q1wb = wpk + 98304;      //  8,192
    float*  ftwf = (float*)(wpk + 106496); // 32,768 f32 (fuse_w transposed, k-major)
    if (ws_size < (size_t)27144192 * 4 + 4096) return;

    // ---- init + CSR build ----
    hipMemsetAsync(bhist, 0, (size_t)822 * 4, stream);    // bhist + cursor
    init_hist_kernel<<<9338, 256, 0, stream>>>((const float4*)id_emb, (const float4*)user_emb,
                                               hab, rel_rows, bhist);
    bucket_scan_kernel<<<1, 256, 0, stream>>>(bhist, bbase);
    bucket_scatter_kernel<<<dim3(196, 3), 256, 0, stream>>>(rel_rows, rel_cols, rel_vals,
                                                            bbase, cursor, tmp);
    bucket_refine_kernel<<<dim3(NBK, 3), 256, 0, stream>>>(tmp, bbase, offs, edges);

    // ---- weight prep for both HGNN layers (single fused launch) ----
    wprep_upack_kernel<<<152, 256, 0, stream>>>(upi_w, upu_w, lin_r_w, Wcat);

    // ---- HGNN: 2 layers ----
    for (int k = 0; k < 2; ++k) {
        gather_kernel<<<17500, 256, 0, stream>>>(hab, edges, offs, T);
        hgnn_update_mfma_kernel<<<548, 256, 0, stream>>>((const bf16*)T, hab,
            (const bf16*)Wcat, upi_b, upu_b, k);
    }

    // ---- session branch ----
    misc_prep_kernel<<<13092, 256, 0, stream>>>(ids, u_type, id_emb,
        w_ih, w_hh, ei_w, eo_w, q2_w, q1_w, fuse_w,
        lens, rowmap, out + 131072, out + 132096, wpk, sess_hb, maskG);
    gru_fused_kernel<<<1568, 256, 0, stream>>>(sess_hb, hb2,
        (const bf16*)eiwb, (const bf16*)eowb,
        (const bf16*)wihb, (const bf16*)whhb,
        ei_b, eo_b, b_iah, b_oah, b_ih, b_hh, maskG);
    q2alpha_kernel<<<392, 256, 0, stream>>>((const bf16*)hb2, (const bf16*)q2wb,
        (const bf16*)q1wb, rowmap, att_w, maskG, alG);
    attn_fuse_kernel<<<NSESS, 128, 0, stream>>>(alG, (const unsigned short*)hb2,
        hab, uid, lens, ftwf, fuse_b, out);
}